// Round 1
// baseline (6002.851 us; speedup 1.0000x reference)
//
#include <hip/hip_runtime.h>
#include <hip/hip_bf16.h>
#include <math.h>

// Problem constants (from reference)
#define BB 2
#define SS 2048
#define DD 2048
#define HH 16
#define GG 4
#define HDIM 128
#define DKV (GG * HDIM)      // 512
#define MS (BB * SS)         // 4096 rows

// ---------------- fp32 tiled GEMM: C[M,N] = A[M,K] @ B[K,N] ----------------
#define GBM 64
#define GBN 64
#define GBK 16
#define GPAD 68  // LDS row stride (floats): multiple of 4 (b128-aligned), breaks 64-alias

__global__ __launch_bounds__(256) void gemm_f32(const float* __restrict__ A,
                                                const float* __restrict__ Bm,
                                                float* __restrict__ C,
                                                int M, int N, int K) {
    __shared__ float As[GBK * GPAD];
    __shared__ float Bs[GBK * GPAD];
    const int t = threadIdx.x;
    const int bm = blockIdx.y * GBM;
    const int bn = blockIdx.x * GBN;
    const int tx = t & 15, ty = t >> 4;
    float acc[4][4] = {};
    for (int k0 = 0; k0 < K; k0 += GBK) {
#pragma unroll
        for (int l = 0; l < 4; ++l) {
            int idx = t + l * 256;
            int i = idx >> 4, j = idx & 15;
            As[j * GPAD + i] = A[(size_t)(bm + i) * K + k0 + j];
        }
#pragma unroll
        for (int l = 0; l < 4; ++l) {
            int idx = t + l * 256;
            int j = idx >> 6, i = idx & 63;
            Bs[j * GPAD + i] = Bm[(size_t)(k0 + j) * N + bn + i];
        }
        __syncthreads();
#pragma unroll
        for (int kk = 0; kk < GBK; ++kk) {
            float4 a = *(const float4*)&As[kk * GPAD + ty * 4];
            float4 b = *(const float4*)&Bs[kk * GPAD + tx * 4];
            float av[4] = {a.x, a.y, a.z, a.w};
            float bv[4] = {b.x, b.y, b.z, b.w};
#pragma unroll
            for (int r = 0; r < 4; ++r)
#pragma unroll
                for (int c = 0; c < 4; ++c)
                    acc[r][c] = fmaf(av[r], bv[c], acc[r][c]);
        }
        __syncthreads();
    }
#pragma unroll
    for (int r = 0; r < 4; ++r) {
        float4 o = make_float4(acc[r][0], acc[r][1], acc[r][2], acc[r][3]);
        *(float4*)&C[(size_t)(bm + ty * 4 + r) * N + bn + tx * 4] = o;
    }
}

// ---------------- RoPE (rotate_half, concat(freqs,freqs) layout) ----------------
// X: [B*S, nheads*128], position s = row % S. Pair (i, i+64) per head.
__global__ void rope_kernel(float* __restrict__ X, int nheads, int total) {
    int idx = blockIdx.x * blockDim.x + threadIdx.x;
    if (idx >= total) return;
    int i = idx & 63;
    int hh = (idx >> 6) % nheads;
    int row = idx / (64 * nheads);
    int s = row & (SS - 1);
    float inv = powf(10000.f, -(2.f * (float)i) / 128.f);
    float ang = (float)s * inv;
    float c, sn;
    __sincosf(ang, &sn, &c);
    float* p = X + (size_t)row * ((size_t)nheads * HDIM) + (size_t)hh * HDIM + i;
    float x1 = p[0], x2 = p[64];
    p[0]  = x1 * c - x2 * sn;
    p[64] = x2 * c + x1 * sn;
}

// ---------------- causal GQA flash attention ----------------
// one 128-thread block per (b, h, q_row). thread t owns out dim d=t.
__device__ __forceinline__ float blk_max128(float v, volatile float* red) {
#pragma unroll
    for (int off = 32; off; off >>= 1) v = fmaxf(v, __shfl_xor(v, off));
    if ((threadIdx.x & 63) == 0) red[threadIdx.x >> 6] = v;
    __syncthreads();
    v = fmaxf(red[0], red[1]);
    __syncthreads();
    return v;
}
__device__ __forceinline__ float blk_sum128(float v, volatile float* red) {
#pragma unroll
    for (int off = 32; off; off >>= 1) v += __shfl_xor(v, off);
    if ((threadIdx.x & 63) == 0) red[threadIdx.x >> 6] = v;
    __syncthreads();
    v = red[0] + red[1];
    __syncthreads();
    return v;
}

__global__ __launch_bounds__(128) void attn_kernel(const float* __restrict__ Q,
                                                   const float* __restrict__ K,
                                                   const float* __restrict__ V,
                                                   float* __restrict__ Ctx) {
    const int t = threadIdx.x;
    const int bid = blockIdx.x;
    const int q = bid & (SS - 1);
    const int h = (bid >> 11) & (HH - 1);
    const int b = bid >> 15;
    const int g = h >> 2;  // H/G = 4 (repeat_interleave)
    const float scale = 0.08838834764831845f;  // 1/sqrt(128)

    __shared__ float qs[HDIM];
    __shared__ float ps[128];
    __shared__ float red[2];

    const float* qrow = Q + (size_t)(b * SS + q) * DD + (size_t)h * HDIM;
    qs[t] = qrow[t];
    __syncthreads();

    float m = -INFINITY, l = 0.f, acc = 0.f;

    for (int kv0 = 0; kv0 <= q; kv0 += 128) {
        int j = kv0 + t;
        float s = -INFINITY;
        if (j <= q) {
            const float4* krow = (const float4*)(K + (size_t)(b * SS + j) * DKV + (size_t)g * HDIM);
            const float4* q4 = (const float4*)qs;
            float d0 = 0.f;
#pragma unroll
            for (int d4 = 0; d4 < 32; ++d4) {
                float4 kk = krow[d4];
                float4 qq = q4[d4];
                d0 = fmaf(kk.x, qq.x, d0);
                d0 = fmaf(kk.y, qq.y, d0);
                d0 = fmaf(kk.z, qq.z, d0);
                d0 = fmaf(kk.w, qq.w, d0);
            }
            s = d0 * scale;
        }
        float tmax = blk_max128(s, red);
        float m_new = fmaxf(m, tmax);
        float alpha = expf(m - m_new);       // m=-inf first tile -> 0
        float p = expf(s - m_new);           // s=-inf -> 0
        float psum = blk_sum128(p, red);
        l = l * alpha + psum;
        acc *= alpha;
        m = m_new;
        ps[t] = p;
        __syncthreads();
        int jmax = min(128, q + 1 - kv0);
        const float* vp = V + (size_t)(b * SS + kv0) * DKV + (size_t)g * HDIM + t;
#pragma unroll 8
        for (int jj = 0; jj < jmax; ++jj)
            acc = fmaf(ps[jj], vp[(size_t)jj * DKV], acc);
        __syncthreads();
    }
    Ctx[(size_t)(b * SS + q) * DD + (size_t)h * HDIM + t] = acc / l;
}

extern "C" void kernel_launch(void* const* d_in, const int* in_sizes, int n_in,
                              void* d_out, int out_size, void* d_ws, size_t ws_size,
                              hipStream_t stream) {
    const float* x  = (const float*)d_in[0];
    const float* Wq = (const float*)d_in[1];
    const float* Wk = (const float*)d_in[2];
    const float* Wv = (const float*)d_in[3];
    const float* Wo = (const float*)d_in[4];
    float* out = (float*)d_out;

    float* Qb  = (float*)d_ws;                         // [MS, D]
    float* Kb  = Qb + (size_t)MS * DD;                 // [MS, DKV]
    float* Vb  = Kb + (size_t)MS * DKV;                // [MS, DKV]
    float* Ctx = Vb + (size_t)MS * DKV;                // [MS, D]

    dim3 blk(256);
    // Q = x @ Wq ; K = x @ Wk ; V = x @ Wv
    gemm_f32<<<dim3(DD / GBN, MS / GBM), blk, 0, stream>>>(x, Wq, Qb, MS, DD, DD);
    gemm_f32<<<dim3(DKV / GBN, MS / GBM), blk, 0, stream>>>(x, Wk, Kb, MS, DKV, DD);
    gemm_f32<<<dim3(DKV / GBN, MS / GBM), blk, 0, stream>>>(x, Wv, Vb, MS, DKV, DD);

    int nq = MS * HH * 64;
    rope_kernel<<<(nq + 255) / 256, 256, 0, stream>>>(Qb, HH, nq);
    int nk = MS * GG * 64;
    rope_kernel<<<(nk + 255) / 256, 256, 0, stream>>>(Kb, GG, nk);

    attn_kernel<<<BB * HH * SS, 128, 0, stream>>>(Qb, Kb, Vb, Ctx);

    // out = ctx @ Wo
    gemm_f32<<<dim3(DD / GBN, MS / GBM), blk, 0, stream>>>(Ctx, Wo, out, MS, DD, DD);
}

// Round 3
// 1624.897 us; speedup vs baseline: 3.6943x; 3.6943x over previous
//
#include <hip/hip_runtime.h>
#include <hip/hip_bf16.h>
#include <math.h>

// Problem constants
#define BB 2
#define SS 2048
#define DD 2048
#define HH 16
#define GG 4
#define HDIM 128
#define DKV (GG * HDIM)      // 512
#define MS (BB * SS)         // 4096 rows

typedef __attribute__((ext_vector_type(8))) short bf16x8;
typedef __attribute__((ext_vector_type(4))) float f32x4;
typedef __attribute__((ext_vector_type(4))) unsigned int u32x4;

// ---------------- fp32 tiled GEMM: C[M,N] = A[M,K] @ B[K,N] ----------------
#define GBM 64
#define GBN 64
#define GBK 16
#define GPAD 68

__global__ __launch_bounds__(256) void gemm_f32(const float* __restrict__ A,
                                                const float* __restrict__ Bm,
                                                float* __restrict__ C,
                                                int M, int N, int K) {
    __shared__ float As[GBK * GPAD];
    __shared__ float Bs[GBK * GPAD];
    const int t = threadIdx.x;
    const int bm = blockIdx.y * GBM;
    const int bn = blockIdx.x * GBN;
    const int tx = t & 15, ty = t >> 4;
    float acc[4][4] = {};
    for (int k0 = 0; k0 < K; k0 += GBK) {
#pragma unroll
        for (int l = 0; l < 4; ++l) {
            int idx = t + l * 256;
            int i = idx >> 4, j = idx & 15;
            As[j * GPAD + i] = A[(size_t)(bm + i) * K + k0 + j];
        }
#pragma unroll
        for (int l = 0; l < 4; ++l) {
            int idx = t + l * 256;
            int j = idx >> 6, i = idx & 63;
            Bs[j * GPAD + i] = Bm[(size_t)(k0 + j) * N + bn + i];
        }
        __syncthreads();
#pragma unroll
        for (int kk = 0; kk < GBK; ++kk) {
            float4 a = *(const float4*)&As[kk * GPAD + ty * 4];
            float4 b = *(const float4*)&Bs[kk * GPAD + tx * 4];
            float av[4] = {a.x, a.y, a.z, a.w};
            float bv[4] = {b.x, b.y, b.z, b.w};
#pragma unroll
            for (int r = 0; r < 4; ++r)
#pragma unroll
                for (int c = 0; c < 4; ++c)
                    acc[r][c] = fmaf(av[r], bv[c], acc[r][c]);
        }
        __syncthreads();
    }
#pragma unroll
    for (int r = 0; r < 4; ++r) {
        float4 o = make_float4(acc[r][0], acc[r][1], acc[r][2], acc[r][3]);
        *(float4*)&C[(size_t)(bm + ty * 4 + r) * N + bn + tx * 4] = o;
    }
}

// ---------------- RoPE + cast to bf16 ----------------
__global__ void rope_cast(const float* __restrict__ X, ushort* __restrict__ O,
                          int nheads, int total) {
    int idx = blockIdx.x * blockDim.x + threadIdx.x;
    if (idx >= total) return;
    int i = idx & 63;
    int hh = (idx >> 6) % nheads;
    int row = idx / (64 * nheads);
    int s = row & (SS - 1);
    float inv = powf(10000.f, -(2.f * (float)i) / 128.f);
    float ang = (float)s * inv;
    float c, sn;
    __sincosf(ang, &sn, &c);
    size_t base = (size_t)row * ((size_t)nheads * HDIM) + (size_t)hh * HDIM + i;
    float x1 = X[base], x2 = X[base + 64];
    float o1 = x1 * c - x2 * sn;
    float o2 = x2 * c + x1 * sn;
    __hip_bfloat16 b1 = __float2bfloat16(o1);
    __hip_bfloat16 b2 = __float2bfloat16(o2);
    O[base] = *(ushort*)&b1;
    O[base + 64] = *(ushort*)&b2;
}

// ---------------- plain fp32 -> bf16 cast (for V), 8 elems/thread ----------------
__global__ void cast_bf16(const float* __restrict__ X, ushort* __restrict__ O, int total8) {
    int idx = blockIdx.x * blockDim.x + threadIdx.x;
    if (idx >= total8) return;
    const float4* p = (const float4*)X + (size_t)idx * 2;
    float4 a = p[0], b = p[1];
    float v[8] = {a.x, a.y, a.z, a.w, b.x, b.y, b.z, b.w};
    ushort r[8];
#pragma unroll
    for (int j = 0; j < 8; ++j) {
        __hip_bfloat16 t = __float2bfloat16(v[j]);
        r[j] = *(ushort*)&t;
    }
    *((u32x4*)O + idx) = *(u32x4*)r;
}

// ---------------- MFMA flash attention ----------------
// block = 256 thr (4 waves). Q-tile 64 (16 rows/wave). KV-tile 64.
// K in LDS row-major pad-136 (ushort). V staged TRANSPOSED: Vt[d][kv],
// row stride 72 ushorts (144 B, 16B-aligned) -> PV B-fragment is a plain
// contiguous ds_read_b128, same slot convention as the P operand (cancels).
#define KPAD 136
#define VTP 72
#define PSP 72

__global__ __launch_bounds__(256) void attn_mfma(const ushort* __restrict__ Qh,
                                                 const ushort* __restrict__ Kh,
                                                 const ushort* __restrict__ Vh,
                                                 float* __restrict__ Ctx) {
    __shared__ ushort Ks[64 * KPAD];    // 17408 B
    __shared__ ushort Vt[HDIM * VTP];   // 18432 B
    __shared__ ushort Ps[4][16 * PSP];  // 9216 B
    const int t = threadIdx.x;
    const int w = t >> 6;
    const int l = t & 63;
    const int lm = l & 15, lw = l >> 4;
    const int q0 = blockIdx.x * 64;
    const int h = blockIdx.y;
    const int b = blockIdx.z;
    const int g = h >> 2;
    const int qw = q0 + w * 16;
    const float scale = 0.08838834764831845f;  // 1/sqrt(128)

    // Q fragments: lane lm holds Q row (qw+lm), k = kk*32 + lw*8 + j
    bf16x8 qa[4];
    {
        const ushort* qp = Qh + (size_t)(b * SS + qw + lm) * DD + h * HDIM + lw * 8;
#pragma unroll
        for (int kk = 0; kk < 4; ++kk)
            qa[kk] = *(const bf16x8*)(qp + kk * 32);
    }

    f32x4 acc[8];
#pragma unroll
    for (int d = 0; d < 8; ++d) acc[d] = (f32x4){0.f, 0.f, 0.f, 0.f};
    float mrow[4] = {-INFINITY, -INFINITY, -INFINITY, -INFINITY};
    float lrow[4] = {0.f, 0.f, 0.f, 0.f};

    for (int kv0 = 0; kv0 < q0 + 64; kv0 += 64) {
        __syncthreads();
        // ---- stage K (row-major pad) and V (transposed) ----
        {
            const ushort* kg = Kh + (size_t)(b * SS + kv0) * DKV + g * HDIM;
            const ushort* vg = Vh + (size_t)(b * SS + kv0) * DKV + g * HDIM;
#pragma unroll
            for (int it = 0; it < 4; ++it) {
                int c = t + it * 256;
                int kv = c >> 4, c1 = c & 15;
                u32x4 kd = *(const u32x4*)(kg + (size_t)kv * DKV + c1 * 8);
                *(u32x4*)&Ks[kv * KPAD + c1 * 8] = kd;
                u32x4 vd = *(const u32x4*)(vg + (size_t)kv * DKV + c1 * 8);
                ushort vs[8];
                *(u32x4*)vs = vd;
#pragma unroll
                for (int dd = 0; dd < 8; ++dd)
                    Vt[(c1 * 8 + dd) * VTP + kv] = vs[dd];
            }
        }
        __syncthreads();

        if (kv0 <= qw + 15) {  // wave-uniform: skip fully-masked tiles
            // ---- QK^T ----
            f32x4 sf[4];
#pragma unroll
            for (int kvb = 0; kvb < 4; ++kvb) sf[kvb] = (f32x4){0.f, 0.f, 0.f, 0.f};
#pragma unroll
            for (int kvb = 0; kvb < 4; ++kvb)
#pragma unroll
                for (int kk = 0; kk < 4; ++kk) {
                    bf16x8 kb = *(const bf16x8*)&Ks[(kvb * 16 + lm) * KPAD + kk * 32 + lw * 8];
                    sf[kvb] = __builtin_amdgcn_mfma_f32_16x16x32_bf16(qa[kk], kb, sf[kvb], 0, 0, 0);
                }

            // ---- online softmax (C/D: row = lw*4+r, col = kvb*16+lm) ----
            float alpha[4];
#pragma unroll
            for (int r = 0; r < 4; ++r) {
                int qrow = qw + lw * 4 + r;
                float sv[4];
#pragma unroll
                for (int kvb = 0; kvb < 4; ++kvb) {
                    int kvcol = kv0 + kvb * 16 + lm;
                    float x = sf[kvb][r] * scale;
                    sv[kvb] = (kvcol <= qrow) ? x : -INFINITY;
                }
                float rm = fmaxf(fmaxf(sv[0], sv[1]), fmaxf(sv[2], sv[3]));
                rm = fmaxf(rm, __shfl_xor(rm, 1));
                rm = fmaxf(rm, __shfl_xor(rm, 2));
                rm = fmaxf(rm, __shfl_xor(rm, 4));
                rm = fmaxf(rm, __shfl_xor(rm, 8));
                float mn = fmaxf(mrow[r], rm);
                float a = __expf(mrow[r] - mn);
                mrow[r] = mn;
                alpha[r] = a;
                float rs = 0.f;
#pragma unroll
                for (int kvb = 0; kvb < 4; ++kvb) {
                    float pv = __expf(sv[kvb] - mn);
                    rs += pv;
                    __hip_bfloat16 pb = __float2bfloat16(pv);
                    Ps[w][(lw * 4 + r) * PSP + kvb * 16 + lm] = *(ushort*)&pb;
                }
                rs += __shfl_xor(rs, 1);
                rs += __shfl_xor(rs, 2);
                rs += __shfl_xor(rs, 4);
                rs += __shfl_xor(rs, 8);
                lrow[r] = lrow[r] * a + rs;
            }
#pragma unroll
            for (int d = 0; d < 8; ++d) {
                acc[d][0] *= alpha[0];
                acc[d][1] *= alpha[1];
                acc[d][2] *= alpha[2];
                acc[d][3] *= alpha[3];
            }

            // ---- PV: A = P rows (Ps), B = V via Vt (contiguous kv) ----
#pragma unroll
            for (int kks = 0; kks < 2; ++kks) {
                bf16x8 pa = *(const bf16x8*)&Ps[w][lm * PSP + kks * 32 + lw * 8];
#pragma unroll
                for (int dcol = 0; dcol < 8; ++dcol) {
                    bf16x8 vb = *(const bf16x8*)&Vt[(dcol * 16 + lm) * VTP + kks * 32 + lw * 8];
                    acc[dcol] = __builtin_amdgcn_mfma_f32_16x16x32_bf16(pa, vb, acc[dcol], 0, 0, 0);
                }
            }
        }
    }

    // ---- epilogue: Ctx[q][h*128 + d] = acc / l ----
    float rinv[4];
#pragma unroll
    for (int r = 0; r < 4; ++r) rinv[r] = 1.f / lrow[r];
    float* cp = Ctx + (size_t)(b * SS + qw) * DD + h * HDIM;
#pragma unroll
    for (int d = 0; d < 8; ++d)
#pragma unroll
        for (int r = 0; r < 4; ++r)
            cp[(size_t)(lw * 4 + r) * DD + d * 16 + lm] = acc[d][r] * rinv[r];
}

extern "C" void kernel_launch(void* const* d_in, const int* in_sizes, int n_in,
                              void* d_out, int out_size, void* d_ws, size_t ws_size,
                              hipStream_t stream) {
    const float* x  = (const float*)d_in[0];
    const float* Wq = (const float*)d_in[1];
    const float* Wk = (const float*)d_in[2];
    const float* Wv = (const float*)d_in[3];
    const float* Wo = (const float*)d_in[4];
    float* out = (float*)d_out;

    float* Qf = (float*)d_ws;                        // [MS, D] fp32
    float* Kf = Qf + (size_t)MS * DD;                // [MS, DKV]
    float* Vf = Kf + (size_t)MS * DKV;               // [MS, DKV]
    ushort* Qh = (ushort*)(Vf + (size_t)MS * DKV);   // [MS, D] bf16
    ushort* Kh = Qh + (size_t)MS * DD;               // [MS, DKV] bf16
    ushort* Vh = Kh + (size_t)MS * DKV;              // [MS, DKV] bf16
    float* Ctx = Qf;                                 // alias: Qf dead after rope_cast

    dim3 blk(256);
    gemm_f32<<<dim3(DD / GBN, MS / GBM), blk, 0, stream>>>(x, Wq, Qf, MS, DD, DD);
    gemm_f32<<<dim3(DKV / GBN, MS / GBM), blk, 0, stream>>>(x, Wk, Kf, MS, DKV, DD);
    gemm_f32<<<dim3(DKV / GBN, MS / GBM), blk, 0, stream>>>(x, Wv, Vf, MS, DKV, DD);

    int nq = MS * HH * 64;
    rope_cast<<<(nq + 255) / 256, 256, 0, stream>>>(Qf, Qh, HH, nq);
    int nk = MS * GG * 64;
    rope_cast<<<(nk + 255) / 256, 256, 0, stream>>>(Kf, Kh, GG, nk);
    int nv8 = MS * DKV / 8;
    cast_bf16<<<(nv8 + 255) / 256, 256, 0, stream>>>(Vf, Vh, nv8);

    attn_mfma<<<dim3(SS / 64, HH, BB), blk, 0, stream>>>(Qh, Kh, Vh, Ctx);

    gemm_f32<<<dim3(DD / GBN, MS / GBM), blk, 0, stream>>>(Ctx, Wo, out, MS, DD, DD);
}

// Round 4
// 635.207 us; speedup vs baseline: 9.4502x; 2.5581x over previous
//
#include <hip/hip_runtime.h>
#include <hip/hip_bf16.h>
#include <math.h>

// Problem constants
#define BB 2
#define SS 2048
#define DD 2048
#define HH 16
#define GG 4
#define HDIM 128
#define DKV (GG * HDIM)      // 512
#define MS (BB * SS)         // 4096 rows

typedef __attribute__((ext_vector_type(8))) short bf16x8;
typedef __attribute__((ext_vector_type(4))) float f32x4;
typedef __attribute__((ext_vector_type(4))) unsigned int u32x4;

__device__ __forceinline__ ushort f2bf(float x) {
    __hip_bfloat16 b = __float2bfloat16(x);
    return *(ushort*)&b;
}
__device__ __forceinline__ float bf2f(ushort u) {
    __hip_bfloat16 b;
    *(ushort*)&b = u;
    return __bfloat162float(b);
}

// ---------------- fp32 -> bf16 cast, 8 elems/thread ----------------
__global__ void cast_bf16(const float* __restrict__ X, ushort* __restrict__ O, int total8) {
    int idx = blockIdx.x * blockDim.x + threadIdx.x;
    if (idx >= total8) return;
    const float4* p = (const float4*)X + (size_t)idx * 2;
    float4 a = p[0], b = p[1];
    float v[8] = {a.x, a.y, a.z, a.w, b.x, b.y, b.z, b.w};
    ushort r[8];
#pragma unroll
    for (int j = 0; j < 8; ++j) r[j] = f2bf(v[j]);
    *((u32x4*)O + idx) = *(u32x4*)r;
}

// ---------------- transpose + cast: WT[n*K + k] = bf16(W[k*N + n]) ----------------
__global__ __launch_bounds__(256) void transpose_cast(const float* __restrict__ W,
                                                      ushort* __restrict__ WT,
                                                      int K, int N) {
    __shared__ ushort tile[32][33];
    const int tx = threadIdx.x & 31, ty = threadIdx.x >> 5;  // 32 x 8
    const int n0 = blockIdx.x * 32, k0 = blockIdx.y * 32;
#pragma unroll
    for (int i = 0; i < 4; ++i)
        tile[ty + i * 8][tx] = f2bf(W[(size_t)(k0 + ty + i * 8) * N + n0 + tx]);
    __syncthreads();
#pragma unroll
    for (int i = 0; i < 4; ++i)
        WT[(size_t)(n0 + ty + i * 8) * K + k0 + tx] = tile[tx][ty + i * 8];
}

// ---------------- bf16 MFMA GEMM (m97 structure): C = A[M,K] x BT[N,K]^T ----------
// 128x128 tile, BK=32, 4 waves of 64x64, linear LDS + global_load_lds(16B).
#define TBM 128
#define TBN 128
#define TBK 32

template <bool OUT_BF16>
__global__ __launch_bounds__(256) void gemm_bf16(const ushort* __restrict__ A,
                                                 const ushort* __restrict__ BT,
                                                 void* __restrict__ Cout,
                                                 int M, int N, int K) {
    __shared__ ushort As[TBM * TBK];  // 8 KB
    __shared__ ushort Bs[TBN * TBK];  // 8 KB
    const int t = threadIdx.x;
    const int w = t >> 6, l = t & 63;
    const int lm = l & 15, lw = l >> 4;
    const int bm = blockIdx.y * TBM, bn = blockIdx.x * TBN;
    const int wr = w >> 1, wc = w & 1;

    f32x4 acc[4][4];
#pragma unroll
    for (int m = 0; m < 4; ++m)
#pragma unroll
        for (int n = 0; n < 4; ++n) acc[m][n] = (f32x4){0.f, 0.f, 0.f, 0.f};

    for (int k0 = 0; k0 < K; k0 += TBK) {
        __syncthreads();
        // stage: 512 chunks of 16B per tile; chunk c -> row c>>2, colchunk c&3.
        // LDS dest = base + c*16: wave-uniform base + lane*16 (linear, required).
#pragma unroll
        for (int it = 0; it < 2; ++it) {
            int c = t + it * 256;
            const ushort* ga = A + (size_t)(bm + (c >> 2)) * K + k0 + (c & 3) * 8;
            const ushort* gb = BT + (size_t)(bn + (c >> 2)) * K + k0 + (c & 3) * 8;
            __builtin_amdgcn_global_load_lds(
                (const __attribute__((address_space(1))) unsigned int*)ga,
                (__attribute__((address_space(3))) unsigned int*)&As[c * 8], 16, 0, 0);
            __builtin_amdgcn_global_load_lds(
                (const __attribute__((address_space(1))) unsigned int*)gb,
                (__attribute__((address_space(3))) unsigned int*)&Bs[c * 8], 16, 0, 0);
        }
        asm volatile("s_waitcnt vmcnt(0)" ::: "memory");
        __syncthreads();

        bf16x8 af[4], bfr[4];
#pragma unroll
        for (int m = 0; m < 4; ++m)
            af[m] = *(const bf16x8*)&As[(wr * 64 + m * 16 + lm) * TBK + lw * 8];
#pragma unroll
        for (int n = 0; n < 4; ++n)
            bfr[n] = *(const bf16x8*)&Bs[(wc * 64 + n * 16 + lm) * TBK + lw * 8];
#pragma unroll
        for (int m = 0; m < 4; ++m)
#pragma unroll
            for (int n = 0; n < 4; ++n)
                acc[m][n] = __builtin_amdgcn_mfma_f32_16x16x32_bf16(af[m], bfr[n], acc[m][n], 0, 0, 0);
    }

    // epilogue: C/D layout col=lane&15, row=(lane>>4)*4+reg (verified)
#pragma unroll
    for (int m = 0; m < 4; ++m)
#pragma unroll
        for (int n = 0; n < 4; ++n)
#pragma unroll
            for (int r = 0; r < 4; ++r) {
                int row = bm + wr * 64 + m * 16 + lw * 4 + r;
                int col = bn + wc * 64 + n * 16 + lm;
                if (OUT_BF16)
                    ((ushort*)Cout)[(size_t)row * N + col] = f2bf(acc[m][n][r]);
                else
                    ((float*)Cout)[(size_t)row * N + col] = acc[m][n][r];
            }
}

// ---------------- RoPE in-place on bf16 ----------------
__global__ void rope_bf16(ushort* __restrict__ X, int nheads, int total) {
    int idx = blockIdx.x * blockDim.x + threadIdx.x;
    if (idx >= total) return;
    int i = idx & 63;
    int hh = (idx >> 6) % nheads;
    int row = idx / (64 * nheads);
    int s = row & (SS - 1);
    float inv = powf(10000.f, -(2.f * (float)i) / 128.f);
    float ang = (float)s * inv;
    float c, sn;
    __sincosf(ang, &sn, &c);
    size_t base = (size_t)row * ((size_t)nheads * HDIM) + (size_t)hh * HDIM + i;
    float x1 = bf2f(X[base]), x2 = bf2f(X[base + 64]);
    X[base] = f2bf(x1 * c - x2 * sn);
    X[base + 64] = f2bf(x2 * c + x1 * sn);
}

// ---------------- MFMA flash attention (round-3 verified), bf16 ctx out -------
#define KPAD 136
#define VTP 72
#define PSP 72

__global__ __launch_bounds__(256) void attn_mfma(const ushort* __restrict__ Qh,
                                                 const ushort* __restrict__ Kh,
                                                 const ushort* __restrict__ Vh,
                                                 ushort* __restrict__ Ctx) {
    __shared__ ushort Ks[64 * KPAD];
    __shared__ ushort Vt[HDIM * VTP];
    __shared__ ushort Ps[4][16 * PSP];
    const int t = threadIdx.x;
    const int w = t >> 6;
    const int l = t & 63;
    const int lm = l & 15, lw = l >> 4;
    const int q0 = blockIdx.x * 64;
    const int h = blockIdx.y;
    const int b = blockIdx.z;
    const int g = h >> 2;
    const int qw = q0 + w * 16;
    const float scale = 0.08838834764831845f;

    bf16x8 qa[4];
    {
        const ushort* qp = Qh + (size_t)(b * SS + qw + lm) * DD + h * HDIM + lw * 8;
#pragma unroll
        for (int kk = 0; kk < 4; ++kk)
            qa[kk] = *(const bf16x8*)(qp + kk * 32);
    }

    f32x4 acc[8];
#pragma unroll
    for (int d = 0; d < 8; ++d) acc[d] = (f32x4){0.f, 0.f, 0.f, 0.f};
    float mrow[4] = {-INFINITY, -INFINITY, -INFINITY, -INFINITY};
    float lrow[4] = {0.f, 0.f, 0.f, 0.f};

    for (int kv0 = 0; kv0 < q0 + 64; kv0 += 64) {
        __syncthreads();
        {
            const ushort* kg = Kh + (size_t)(b * SS + kv0) * DKV + g * HDIM;
            const ushort* vg = Vh + (size_t)(b * SS + kv0) * DKV + g * HDIM;
#pragma unroll
            for (int it = 0; it < 4; ++it) {
                int c = t + it * 256;
                int kv = c >> 4, c1 = c & 15;
                u32x4 kd = *(const u32x4*)(kg + (size_t)kv * DKV + c1 * 8);
                *(u32x4*)&Ks[kv * KPAD + c1 * 8] = kd;
                u32x4 vd = *(const u32x4*)(vg + (size_t)kv * DKV + c1 * 8);
                ushort vs[8];
                *(u32x4*)vs = vd;
#pragma unroll
                for (int dd = 0; dd < 8; ++dd)
                    Vt[(c1 * 8 + dd) * VTP + kv] = vs[dd];
            }
        }
        __syncthreads();

        if (kv0 <= qw + 15) {
            f32x4 sf[4];
#pragma unroll
            for (int kvb = 0; kvb < 4; ++kvb) sf[kvb] = (f32x4){0.f, 0.f, 0.f, 0.f};
#pragma unroll
            for (int kvb = 0; kvb < 4; ++kvb)
#pragma unroll
                for (int kk = 0; kk < 4; ++kk) {
                    bf16x8 kb = *(const bf16x8*)&Ks[(kvb * 16 + lm) * KPAD + kk * 32 + lw * 8];
                    sf[kvb] = __builtin_amdgcn_mfma_f32_16x16x32_bf16(qa[kk], kb, sf[kvb], 0, 0, 0);
                }

            float alpha[4];
#pragma unroll
            for (int r = 0; r < 4; ++r) {
                int qrow = qw + lw * 4 + r;
                float sv[4];
#pragma unroll
                for (int kvb = 0; kvb < 4; ++kvb) {
                    int kvcol = kv0 + kvb * 16 + lm;
                    float x = sf[kvb][r] * scale;
                    sv[kvb] = (kvcol <= qrow) ? x : -INFINITY;
                }
                float rm = fmaxf(fmaxf(sv[0], sv[1]), fmaxf(sv[2], sv[3]));
                rm = fmaxf(rm, __shfl_xor(rm, 1));
                rm = fmaxf(rm, __shfl_xor(rm, 2));
                rm = fmaxf(rm, __shfl_xor(rm, 4));
                rm = fmaxf(rm, __shfl_xor(rm, 8));
                float mn = fmaxf(mrow[r], rm);
                float a = __expf(mrow[r] - mn);
                mrow[r] = mn;
                alpha[r] = a;
                float rs = 0.f;
#pragma unroll
                for (int kvb = 0; kvb < 4; ++kvb) {
                    float pv = __expf(sv[kvb] - mn);
                    rs += pv;
                    Ps[w][(lw * 4 + r) * PSP + kvb * 16 + lm] = f2bf(pv);
                }
                rs += __shfl_xor(rs, 1);
                rs += __shfl_xor(rs, 2);
                rs += __shfl_xor(rs, 4);
                rs += __shfl_xor(rs, 8);
                lrow[r] = lrow[r] * a + rs;
            }
#pragma unroll
            for (int d = 0; d < 8; ++d) {
                acc[d][0] *= alpha[0];
                acc[d][1] *= alpha[1];
                acc[d][2] *= alpha[2];
                acc[d][3] *= alpha[3];
            }

#pragma unroll
            for (int kks = 0; kks < 2; ++kks) {
                bf16x8 pa = *(const bf16x8*)&Ps[w][lm * PSP + kks * 32 + lw * 8];
#pragma unroll
                for (int dcol = 0; dcol < 8; ++dcol) {
                    bf16x8 vb = *(const bf16x8*)&Vt[(dcol * 16 + lm) * VTP + kks * 32 + lw * 8];
                    acc[dcol] = __builtin_amdgcn_mfma_f32_16x16x32_bf16(pa, vb, acc[dcol], 0, 0, 0);
                }
            }
        }
    }

    float rinv[4];
#pragma unroll
    for (int r = 0; r < 4; ++r) rinv[r] = 1.f / lrow[r];
    ushort* cp = Ctx + (size_t)(b * SS + qw) * DD + h * HDIM;
#pragma unroll
    for (int d = 0; d < 8; ++d)
#pragma unroll
        for (int r = 0; r < 4; ++r)
            cp[(size_t)(lw * 4 + r) * DD + d * 16 + lm] = f2bf(acc[d][r] * rinv[r]);
}

extern "C" void kernel_launch(void* const* d_in, const int* in_sizes, int n_in,
                              void* d_out, int out_size, void* d_ws, size_t ws_size,
                              hipStream_t stream) {
    const float* x  = (const float*)d_in[0];
    const float* Wq = (const float*)d_in[1];
    const float* Wk = (const float*)d_in[2];
    const float* Wv = (const float*)d_in[3];
    const float* Wo = (const float*)d_in[4];
    float* out = (float*)d_out;

    // bf16 workspace: 71.4 MB total
    ushort* xh  = (ushort*)d_ws;                     // [MS, DD]
    ushort* Qh  = xh + (size_t)MS * DD;              // [MS, DD]
    ushort* Kh  = Qh + (size_t)MS * DD;              // [MS, DKV]
    ushort* Vh  = Kh + (size_t)MS * DKV;             // [MS, DKV]
    ushort* Ch  = Vh + (size_t)MS * DKV;             // [MS, DD] ctx bf16
    ushort* WT1 = Ch + (size_t)MS * DD;              // [DD, DD]  (WqT, later WoT)
    ushort* WkT = WT1 + (size_t)DD * DD;             // [DKV, DD]
    ushort* WvT = WkT + (size_t)DKV * DD;            // [DKV, DD]

    dim3 blk(256);
    int nx8 = MS * DD / 8;
    cast_bf16<<<(nx8 + 255) / 256, 256, 0, stream>>>(x, xh, nx8);

    transpose_cast<<<dim3(DD / 32, DD / 32), blk, 0, stream>>>(Wq, WT1, DD, DD);
    gemm_bf16<true><<<dim3(DD / TBN, MS / TBM), blk, 0, stream>>>(xh, WT1, Qh, MS, DD, DD);

    transpose_cast<<<dim3(DKV / 32, DD / 32), blk, 0, stream>>>(Wk, WkT, DD, DKV);
    gemm_bf16<true><<<dim3(DKV / TBN, MS / TBM), blk, 0, stream>>>(xh, WkT, Kh, MS, DKV, DD);

    transpose_cast<<<dim3(DKV / 32, DD / 32), blk, 0, stream>>>(Wv, WvT, DD, DKV);
    gemm_bf16<true><<<dim3(DKV / TBN, MS / TBM), blk, 0, stream>>>(xh, WvT, Vh, MS, DKV, DD);

    int nq = MS * HH * 64;
    rope_bf16<<<(nq + 255) / 256, 256, 0, stream>>>(Qh, HH, nq);
    int nk = MS * GG * 64;
    rope_bf16<<<(nk + 255) / 256, 256, 0, stream>>>(Kh, GG, nk);

    attn_mfma<<<dim3(SS / 64, HH, BB), blk, 0, stream>>>(Qh, Kh, Vh, Ch);

    transpose_cast<<<dim3(DD / 32, DD / 32), blk, 0, stream>>>(Wo, WT1, DD, DD);
    gemm_bf16<false><<<dim3(DD / TBN, MS / TBM), blk, 0, stream>>>(Ch, WT1, out, MS, DD, DD);
}

// Round 5
// 448.584 us; speedup vs baseline: 13.3818x; 1.4160x over previous
//
#include <hip/hip_runtime.h>
#include <hip/hip_bf16.h>
#include <math.h>

// Problem constants
#define BB 2
#define SS 2048
#define DD 2048
#define HH 16
#define GG 4
#define HDIM 128
#define DKV (GG * HDIM)      // 512
#define MS (BB * SS)         // 4096 rows

typedef __attribute__((ext_vector_type(8))) short bf16x8;
typedef __attribute__((ext_vector_type(4))) float f32x4;
typedef __attribute__((ext_vector_type(4))) unsigned int u32x4;

__device__ __forceinline__ ushort f2bf(float x) {
    __hip_bfloat16 b = __float2bfloat16(x);
    return *(ushort*)&b;
}
__device__ __forceinline__ float bf2f(ushort u) {
    __hip_bfloat16 b;
    *(ushort*)&b = u;
    return __bfloat162float(b);
}

// ---------------- fp32 -> bf16 cast, 8 elems/thread ----------------
__global__ void cast_bf16(const float* __restrict__ X, ushort* __restrict__ O, int total8) {
    int idx = blockIdx.x * blockDim.x + threadIdx.x;
    if (idx >= total8) return;
    const float4* p = (const float4*)X + (size_t)idx * 2;
    float4 a = p[0], b = p[1];
    float v[8] = {a.x, a.y, a.z, a.w, b.x, b.y, b.z, b.w};
    ushort r[8];
#pragma unroll
    for (int j = 0; j < 8; ++j) r[j] = f2bf(v[j]);
    *((u32x4*)O + idx) = *(u32x4*)r;
}

// ---------------- transpose + cast: WT[n*K + k] = bf16(W[k*N + n]) ----------------
__global__ __launch_bounds__(256) void transpose_cast(const float* __restrict__ W,
                                                      ushort* __restrict__ WT,
                                                      int K, int N) {
    __shared__ ushort tile[32][33];
    const int tx = threadIdx.x & 31, ty = threadIdx.x >> 5;  // 32 x 8
    const int n0 = blockIdx.x * 32, k0 = blockIdx.y * 32;
#pragma unroll
    for (int i = 0; i < 4; ++i)
        tile[ty + i * 8][tx] = f2bf(W[(size_t)(k0 + ty + i * 8) * N + n0 + tx]);
    __syncthreads();
#pragma unroll
    for (int i = 0; i < 4; ++i)
        WT[(size_t)(n0 + ty + i * 8) * K + k0 + tx] = tile[tx][ty + i * 8];
}

// ---------- per-batch V transpose: VT[b*DKV + dkv][kv] = Vh[b*SS + kv][dkv] ----------
__global__ __launch_bounds__(256) void transpose_v(const ushort* __restrict__ Vh,
                                                   ushort* __restrict__ VT) {
    __shared__ ushort tile[32][33];
    const int tx = threadIdx.x & 31, ty = threadIdx.x >> 5;  // 32 x 8
    const int d0 = blockIdx.x * 32;  // dkv
    const int k0 = blockIdx.y * 32;  // kv
    const int b = blockIdx.z;
#pragma unroll
    for (int i = 0; i < 4; ++i)
        tile[ty + i * 8][tx] = Vh[(size_t)(b * SS + k0 + ty + i * 8) * DKV + d0 + tx];
    __syncthreads();
#pragma unroll
    for (int i = 0; i < 4; ++i)
        VT[((size_t)b * DKV + d0 + ty + i * 8) * SS + k0 + tx] = tile[tx][ty + i * 8];
}

// ---------------- bf16 MFMA GEMM (m97 structure): C = A[M,K] x BT[N,K]^T ----------
#define TBM 128
#define TBN 128
#define TBK 32

template <bool OUT_BF16>
__global__ __launch_bounds__(256) void gemm_bf16(const ushort* __restrict__ A,
                                                 const ushort* __restrict__ BT,
                                                 void* __restrict__ Cout,
                                                 int M, int N, int K) {
    __shared__ ushort As[TBM * TBK];  // 8 KB
    __shared__ ushort Bs[TBN * TBK];  // 8 KB
    const int t = threadIdx.x;
    const int w = t >> 6, l = t & 63;
    const int lm = l & 15, lw = l >> 4;
    const int bm = blockIdx.y * TBM, bn = blockIdx.x * TBN;
    const int wr = w >> 1, wc = w & 1;

    f32x4 acc[4][4];
#pragma unroll
    for (int m = 0; m < 4; ++m)
#pragma unroll
        for (int n = 0; n < 4; ++n) acc[m][n] = (f32x4){0.f, 0.f, 0.f, 0.f};

    for (int k0 = 0; k0 < K; k0 += TBK) {
        __syncthreads();
#pragma unroll
        for (int it = 0; it < 2; ++it) {
            int c = t + it * 256;
            const ushort* ga = A + (size_t)(bm + (c >> 2)) * K + k0 + (c & 3) * 8;
            const ushort* gb = BT + (size_t)(bn + (c >> 2)) * K + k0 + (c & 3) * 8;
            __builtin_amdgcn_global_load_lds(
                (const __attribute__((address_space(1))) unsigned int*)ga,
                (__attribute__((address_space(3))) unsigned int*)&As[c * 8], 16, 0, 0);
            __builtin_amdgcn_global_load_lds(
                (const __attribute__((address_space(1))) unsigned int*)gb,
                (__attribute__((address_space(3))) unsigned int*)&Bs[c * 8], 16, 0, 0);
        }
        asm volatile("s_waitcnt vmcnt(0)" ::: "memory");
        __syncthreads();

        bf16x8 af[4], bfr[4];
#pragma unroll
        for (int m = 0; m < 4; ++m)
            af[m] = *(const bf16x8*)&As[(wr * 64 + m * 16 + lm) * TBK + lw * 8];
#pragma unroll
        for (int n = 0; n < 4; ++n)
            bfr[n] = *(const bf16x8*)&Bs[(wc * 64 + n * 16 + lm) * TBK + lw * 8];
#pragma unroll
        for (int m = 0; m < 4; ++m)
#pragma unroll
            for (int n = 0; n < 4; ++n)
                acc[m][n] = __builtin_amdgcn_mfma_f32_16x16x32_bf16(af[m], bfr[n], acc[m][n], 0, 0, 0);
    }

#pragma unroll
    for (int m = 0; m < 4; ++m)
#pragma unroll
        for (int n = 0; n < 4; ++n)
#pragma unroll
            for (int r = 0; r < 4; ++r) {
                int row = bm + wr * 64 + m * 16 + lw * 4 + r;
                int col = bn + wc * 64 + n * 16 + lm;
                if (OUT_BF16)
                    ((ushort*)Cout)[(size_t)row * N + col] = f2bf(acc[m][n][r]);
                else
                    ((float*)Cout)[(size_t)row * N + col] = acc[m][n][r];
            }
}

// ---------------- RoPE in-place on bf16 ----------------
__global__ void rope_bf16(ushort* __restrict__ X, int nheads, int total) {
    int idx = blockIdx.x * blockDim.x + threadIdx.x;
    if (idx >= total) return;
    int i = idx & 63;
    int hh = (idx >> 6) % nheads;
    int row = idx / (64 * nheads);
    int s = row & (SS - 1);
    float inv = powf(10000.f, -(2.f * (float)i) / 128.f);
    float ang = (float)s * inv;
    float c, sn;
    __sincosf(ang, &sn, &c);
    size_t base = (size_t)row * ((size_t)nheads * HDIM) + (size_t)hh * HDIM + i;
    float x1 = bf2f(X[base]), x2 = bf2f(X[base + 64]);
    X[base] = f2bf(x1 * c - x2 * sn);
    X[base + 64] = f2bf(x2 * c + x1 * sn);
}

// ---------------- MFMA flash attention, swizzled LDS (T2 / rule #21) -----------
// K tile [64 kv][128 d], V tile [128 d][64 kv] (from pre-transposed VT).
// Both staged with global_load_lds (linear LDS dest) + inverse-XOR'd global
// source; ds_read_b128 applies byte ^= ((row&7)<<4)  (ushort idx ^= (lm&7)<<3).
#define PSP 72

__global__ __launch_bounds__(256) void attn_mfma(const ushort* __restrict__ Qh,
                                                 const ushort* __restrict__ Kh,
                                                 const ushort* __restrict__ VT,
                                                 ushort* __restrict__ Ctx) {
    __shared__ ushort Ks[64 * 128];     // 16 KB
    __shared__ ushort Vs[128 * 64];     // 16 KB
    __shared__ ushort Ps[4][16 * PSP];  // 9 KB
    const int t = threadIdx.x;
    const int w = t >> 6;
    const int l = t & 63;
    const int lm = l & 15, lw = l >> 4;
    const int q0 = blockIdx.x * 64;
    const int h = blockIdx.y;
    const int b = blockIdx.z;
    const int g = h >> 2;
    const int qw = q0 + w * 16;
    const float scale = 0.08838834764831845f;
    const int swz = (lm & 7) << 3;  // ushort-index XOR for reads

    bf16x8 qa[4];
    {
        const ushort* qp = Qh + (size_t)(b * SS + qw + lm) * DD + h * HDIM + lw * 8;
#pragma unroll
        for (int kk = 0; kk < 4; ++kk)
            qa[kk] = *(const bf16x8*)(qp + kk * 32);
    }

    f32x4 acc[8];
#pragma unroll
    for (int d = 0; d < 8; ++d) acc[d] = (f32x4){0.f, 0.f, 0.f, 0.f};
    float mrow[4] = {-INFINITY, -INFINITY, -INFINITY, -INFINITY};
    float lrow[4] = {0.f, 0.f, 0.f, 0.f};

    const ushort* kbase = Kh + ((size_t)b * SS) * DKV + g * HDIM;
    const ushort* vbase = VT + ((size_t)b * DKV + g * HDIM) * SS;

    for (int kv0 = 0; kv0 < q0 + 64; kv0 += 64) {
        __syncthreads();
        // ---- stage K and V via global_load_lds, source pre-swizzled ----
#pragma unroll
        for (int it = 0; it < 4; ++it) {
            int c = t + it * 256;
            {  // K: 64 rows x 16 chunks
                int row = c >> 4, o = c & 15;
                const ushort* src = kbase + (size_t)(kv0 + row) * DKV + ((o ^ (row & 7)) * 8);
                __builtin_amdgcn_global_load_lds(
                    (const __attribute__((address_space(1))) unsigned int*)src,
                    (__attribute__((address_space(3))) unsigned int*)&Ks[c * 8], 16, 0, 0);
            }
            {  // V: 128 rows x 8 chunks
                int row = c >> 3, o = c & 7;
                const ushort* src = vbase + (size_t)row * SS + kv0 + ((o ^ (row & 7)) * 8);
                __builtin_amdgcn_global_load_lds(
                    (const __attribute__((address_space(1))) unsigned int*)src,
                    (__attribute__((address_space(3))) unsigned int*)&Vs[c * 8], 16, 0, 0);
            }
        }
        asm volatile("s_waitcnt vmcnt(0)" ::: "memory");
        __syncthreads();

        if (kv0 <= qw + 15) {
            // ---- QK^T ----
            f32x4 sf[4];
#pragma unroll
            for (int kvb = 0; kvb < 4; ++kvb) sf[kvb] = (f32x4){0.f, 0.f, 0.f, 0.f};
#pragma unroll
            for (int kvb = 0; kvb < 4; ++kvb)
#pragma unroll
                for (int kk = 0; kk < 4; ++kk) {
                    bf16x8 kb = *(const bf16x8*)&Ks[(kvb * 16 + lm) * 128 + ((kk * 32 + lw * 8) ^ swz)];
                    sf[kvb] = __builtin_amdgcn_mfma_f32_16x16x32_bf16(qa[kk], kb, sf[kvb], 0, 0, 0);
                }

            // ---- online softmax ----
            float alpha[4];
#pragma unroll
            for (int r = 0; r < 4; ++r) {
                int qrow = qw + lw * 4 + r;
                float sv[4];
#pragma unroll
                for (int kvb = 0; kvb < 4; ++kvb) {
                    int kvcol = kv0 + kvb * 16 + lm;
                    float x = sf[kvb][r] * scale;
                    sv[kvb] = (kvcol <= qrow) ? x : -INFINITY;
                }
                float rm = fmaxf(fmaxf(sv[0], sv[1]), fmaxf(sv[2], sv[3]));
                rm = fmaxf(rm, __shfl_xor(rm, 1));
                rm = fmaxf(rm, __shfl_xor(rm, 2));
                rm = fmaxf(rm, __shfl_xor(rm, 4));
                rm = fmaxf(rm, __shfl_xor(rm, 8));
                float mn = fmaxf(mrow[r], rm);
                float a = __expf(mrow[r] - mn);
                mrow[r] = mn;
                alpha[r] = a;
                float rs = 0.f;
#pragma unroll
                for (int kvb = 0; kvb < 4; ++kvb) {
                    float pv = __expf(sv[kvb] - mn);
                    rs += pv;
                    Ps[w][(lw * 4 + r) * PSP + kvb * 16 + lm] = f2bf(pv);
                }
                rs += __shfl_xor(rs, 1);
                rs += __shfl_xor(rs, 2);
                rs += __shfl_xor(rs, 4);
                rs += __shfl_xor(rs, 8);
                lrow[r] = lrow[r] * a + rs;
            }
#pragma unroll
            for (int d = 0; d < 8; ++d) {
                acc[d][0] *= alpha[0];
                acc[d][1] *= alpha[1];
                acc[d][2] *= alpha[2];
                acc[d][3] *= alpha[3];
            }

            // ---- PV ----
#pragma unroll
            for (int kks = 0; kks < 2; ++kks) {
                bf16x8 pa = *(const bf16x8*)&Ps[w][lm * PSP + kks * 32 + lw * 8];
#pragma unroll
                for (int dcol = 0; dcol < 8; ++dcol) {
                    bf16x8 vb = *(const bf16x8*)&Vs[(dcol * 16 + lm) * 64 + ((kks * 32 + lw * 8) ^ swz)];
                    acc[dcol] = __builtin_amdgcn_mfma_f32_16x16x32_bf16(pa, vb, acc[dcol], 0, 0, 0);
                }
            }
        }
    }

    float rinv[4];
#pragma unroll
    for (int r = 0; r < 4; ++r) rinv[r] = 1.f / lrow[r];
    ushort* cp = Ctx + (size_t)(b * SS + qw) * DD + h * HDIM;
#pragma unroll
    for (int d = 0; d < 8; ++d)
#pragma unroll
        for (int r = 0; r < 4; ++r)
            cp[(size_t)(lw * 4 + r) * DD + d * 16 + lm] = f2bf(acc[d][r] * rinv[r]);
}

extern "C" void kernel_launch(void* const* d_in, const int* in_sizes, int n_in,
                              void* d_out, int out_size, void* d_ws, size_t ws_size,
                              hipStream_t stream) {
    const float* x  = (const float*)d_in[0];
    const float* Wq = (const float*)d_in[1];
    const float* Wk = (const float*)d_in[2];
    const float* Wv = (const float*)d_in[3];
    const float* Wo = (const float*)d_in[4];
    float* out = (float*)d_out;

    // bf16 workspace (~58.8 MB): Ch aliases xh (dead after V GEMM)
    ushort* xh  = (ushort*)d_ws;                     // [MS, DD]
    ushort* Qh  = xh + (size_t)MS * DD;              // [MS, DD]
    ushort* Kh  = Qh + (size_t)MS * DD;              // [MS, DKV]
    ushort* Vh  = Kh + (size_t)MS * DKV;             // [MS, DKV]
    ushort* VTb = Vh + (size_t)MS * DKV;             // [BB*DKV, SS]
    ushort* WT1 = VTb + (size_t)MS * DKV;            // [DD, DD]  (WqT, later WoT)
    ushort* WkT = WT1 + (size_t)DD * DD;             // [DKV, DD]
    ushort* WvT = WkT + (size_t)DKV * DD;            // [DKV, DD]
    ushort* Ch  = xh;                                // ctx bf16 aliases xh

    dim3 blk(256);
    int nx8 = MS * DD / 8;
    cast_bf16<<<(nx8 + 255) / 256, 256, 0, stream>>>(x, xh, nx8);

    transpose_cast<<<dim3(DD / 32, DD / 32), blk, 0, stream>>>(Wq, WT1, DD, DD);
    gemm_bf16<true><<<dim3(DD / TBN, MS / TBM), blk, 0, stream>>>(xh, WT1, Qh, MS, DD, DD);

    transpose_cast<<<dim3(DKV / 32, DD / 32), blk, 0, stream>>>(Wk, WkT, DD, DKV);
    gemm_bf16<true><<<dim3(DKV / TBN, MS / TBM), blk, 0, stream>>>(xh, WkT, Kh, MS, DKV, DD);

    transpose_cast<<<dim3(DKV / 32, DD / 32), blk, 0, stream>>>(Wv, WvT, DD, DKV);
    gemm_bf16<true><<<dim3(DKV / TBN, MS / TBM), blk, 0, stream>>>(xh, WvT, Vh, MS, DKV, DD);

    int nq = MS * HH * 64;
    rope_bf16<<<(nq + 255) / 256, 256, 0, stream>>>(Qh, HH, nq);
    int nk = MS * GG * 64;
    rope_bf16<<<(nk + 255) / 256, 256, 0, stream>>>(Kh, GG, nk);

    transpose_v<<<dim3(DKV / 32, SS / 32, BB), blk, 0, stream>>>(Vh, VTb);

    attn_mfma<<<dim3(SS / 64, HH, BB), blk, 0, stream>>>(Qh, Kh, VTb, Ch);

    transpose_cast<<<dim3(DD / 32, DD / 32), blk, 0, stream>>>(Wo, WT1, DD, DD);
    gemm_bf16<false><<<dim3(DD / TBN, MS / TBM), blk, 0, stream>>>(Ch, WT1, out, MS, DD, DD);
}

// Round 6
// 276.481 us; speedup vs baseline: 21.7116x; 1.6225x over previous
//
#include <hip/hip_runtime.h>
#include <hip/hip_bf16.h>
#include <math.h>

// Problem constants
#define BB 2
#define SS 2048
#define DD 2048
#define HH 16
#define GG 4
#define HDIM 128
#define DKV (GG * HDIM)      // 512
#define MS (BB * SS)         // 4096 rows
#define QKVS 3072            // fused QKV row stride (2048 Q + 512 K + 512 V)

typedef __attribute__((ext_vector_type(8))) short bf16x8;
typedef __attribute__((ext_vector_type(4))) float f32x4;
typedef __attribute__((ext_vector_type(4))) unsigned int u32x4;

__device__ __forceinline__ ushort f2bf(float x) {
    __hip_bfloat16 b = __float2bfloat16(x);
    return *(ushort*)&b;
}
__device__ __forceinline__ float bf2f(ushort u) {
    __hip_bfloat16 b;
    *(ushort*)&b = u;
    return __bfloat162float(b);
}

// ---------------- fp32 -> bf16 cast, 8 elems/thread ----------------
__global__ void cast_bf16(const float* __restrict__ X, ushort* __restrict__ O, int total8) {
    int idx = blockIdx.x * blockDim.x + threadIdx.x;
    if (idx >= total8) return;
    const float4* p = (const float4*)X + (size_t)idx * 2;
    float4 a = p[0], b = p[1];
    float v[8] = {a.x, a.y, a.z, a.w, b.x, b.y, b.z, b.w};
    ushort r[8];
#pragma unroll
    for (int j = 0; j < 8; ++j) r[j] = f2bf(v[j]);
    *((u32x4*)O + idx) = *(u32x4*)r;
}

// ---------------- transpose + cast: WT[n*K + k] = bf16(W[k*N + n]) ----------------
__global__ __launch_bounds__(256) void transpose_cast(const float* __restrict__ W,
                                                      ushort* __restrict__ WT,
                                                      int K, int N) {
    __shared__ ushort tile[32][33];
    const int tx = threadIdx.x & 31, ty = threadIdx.x >> 5;  // 32 x 8
    const int n0 = blockIdx.x * 32, k0 = blockIdx.y * 32;
#pragma unroll
    for (int i = 0; i < 4; ++i)
        tile[ty + i * 8][tx] = f2bf(W[(size_t)(k0 + ty + i * 8) * N + n0 + tx]);
    __syncthreads();
#pragma unroll
    for (int i = 0; i < 4; ++i)
        WT[(size_t)(n0 + ty + i * 8) * K + k0 + tx] = tile[tx][ty + i * 8];
}

// ---- per-batch V transpose from fused QKV: VT[b*DKV + dkv][kv] = QKV[b*SS+kv][2560+dkv]
__global__ __launch_bounds__(256) void transpose_v(const ushort* __restrict__ QKV,
                                                   ushort* __restrict__ VT) {
    __shared__ ushort tile[32][33];
    const int tx = threadIdx.x & 31, ty = threadIdx.x >> 5;  // 32 x 8
    const int d0 = blockIdx.x * 32;  // dkv
    const int k0 = blockIdx.y * 32;  // kv
    const int b = blockIdx.z;
#pragma unroll
    for (int i = 0; i < 4; ++i)
        tile[ty + i * 8][tx] =
            QKV[(size_t)(b * SS + k0 + ty + i * 8) * QKVS + 2560 + d0 + tx];
    __syncthreads();
#pragma unroll
    for (int i = 0; i < 4; ++i)
        VT[((size_t)b * DKV + d0 + ty + i * 8) * SS + k0 + tx] = tile[tx][ty + i * 8];
}

// ---------------- bf16 MFMA GEMM (m97 structure): C = A[M,K] x BT[N,K]^T ----------
#define TBM 128
#define TBN 128
#define TBK 32

template <bool OUT_BF16>
__global__ __launch_bounds__(256) void gemm_bf16(const ushort* __restrict__ A,
                                                 const ushort* __restrict__ BT,
                                                 void* __restrict__ Cout,
                                                 int M, int N, int K) {
    __shared__ ushort As[TBM * TBK];  // 8 KB
    __shared__ ushort Bs[TBN * TBK];  // 8 KB
    const int t = threadIdx.x;
    const int w = t >> 6, l = t & 63;
    const int lm = l & 15, lw = l >> 4;
    const int bm = blockIdx.y * TBM, bn = blockIdx.x * TBN;
    const int wr = w >> 1, wc = w & 1;

    f32x4 acc[4][4];
#pragma unroll
    for (int m = 0; m < 4; ++m)
#pragma unroll
        for (int n = 0; n < 4; ++n) acc[m][n] = (f32x4){0.f, 0.f, 0.f, 0.f};

    for (int k0 = 0; k0 < K; k0 += TBK) {
        __syncthreads();
#pragma unroll
        for (int it = 0; it < 2; ++it) {
            int c = t + it * 256;
            const ushort* ga = A + (size_t)(bm + (c >> 2)) * K + k0 + (c & 3) * 8;
            const ushort* gb = BT + (size_t)(bn + (c >> 2)) * K + k0 + (c & 3) * 8;
            __builtin_amdgcn_global_load_lds(
                (const __attribute__((address_space(1))) unsigned int*)ga,
                (__attribute__((address_space(3))) unsigned int*)&As[c * 8], 16, 0, 0);
            __builtin_amdgcn_global_load_lds(
                (const __attribute__((address_space(1))) unsigned int*)gb,
                (__attribute__((address_space(3))) unsigned int*)&Bs[c * 8], 16, 0, 0);
        }
        asm volatile("s_waitcnt vmcnt(0)" ::: "memory");
        __syncthreads();

        bf16x8 af[4], bfr[4];
#pragma unroll
        for (int m = 0; m < 4; ++m)
            af[m] = *(const bf16x8*)&As[(wr * 64 + m * 16 + lm) * TBK + lw * 8];
#pragma unroll
        for (int n = 0; n < 4; ++n)
            bfr[n] = *(const bf16x8*)&Bs[(wc * 64 + n * 16 + lm) * TBK + lw * 8];
#pragma unroll
        for (int m = 0; m < 4; ++m)
#pragma unroll
            for (int n = 0; n < 4; ++n)
                acc[m][n] = __builtin_amdgcn_mfma_f32_16x16x32_bf16(af[m], bfr[n], acc[m][n], 0, 0, 0);
    }

#pragma unroll
    for (int m = 0; m < 4; ++m)
#pragma unroll
        for (int n = 0; n < 4; ++n)
#pragma unroll
            for (int r = 0; r < 4; ++r) {
                int row = bm + wr * 64 + m * 16 + lw * 4 + r;
                int col = bn + wc * 64 + n * 16 + lm;
                if (OUT_BF16)
                    ((ushort*)Cout)[(size_t)row * N + col] = f2bf(acc[m][n][r]);
                else
                    ((float*)Cout)[(size_t)row * N + col] = acc[m][n][r];
            }
}

// ---------------- RoPE in-place on bf16 (strided, fused-QKV aware) ----------------
__global__ void rope_bf16(ushort* __restrict__ X, int nheads, int colOff, int total) {
    int idx = blockIdx.x * blockDim.x + threadIdx.x;
    if (idx >= total) return;
    int i = idx & 63;
    int hh = (idx >> 6) % nheads;
    int row = idx / (64 * nheads);
    int s = row & (SS - 1);
    float inv = powf(10000.f, -(2.f * (float)i) / 128.f);
    float ang = (float)s * inv;
    float c, sn;
    __sincosf(ang, &sn, &c);
    size_t base = (size_t)row * QKVS + colOff + (size_t)hh * HDIM + i;
    float x1 = bf2f(X[base]), x2 = bf2f(X[base + 64]);
    X[base] = f2bf(x1 * c - x2 * sn);
    X[base + 64] = f2bf(x2 * c + x1 * sn);
}

// ---------------- MFMA flash attention: dbuf 2-phase pipeline + paired q-tiles ----
// Each block handles q-tiles {x, 31-x}: constant 33 KV-tiles of work per block.
// K tile [64 kv][128 d], V tile [128 d][64 kv]; both global_load_lds-staged with
// inverse-XOR'd source (rule #21), reads apply ushort-idx ^= (lm&7)<<3.
#define PSP 72

__global__ __launch_bounds__(256) void attn_mfma(const ushort* __restrict__ QKV,
                                                 const ushort* __restrict__ VT,
                                                 ushort* __restrict__ Ctx) {
    __shared__ ushort Ks[2][64 * 128];  // 2 x 16 KB
    __shared__ ushort Vs[2][128 * 64];  // 2 x 16 KB
    __shared__ ushort Ps[4][16 * PSP];  // 9 KB
    const int t = threadIdx.x;
    const int w = t >> 6;
    const int l = t & 63;
    const int lm = l & 15, lw = l >> 4;
    const int h = blockIdx.y;
    const int b = blockIdx.z;
    const int g = h >> 2;
    const float scale = 0.08838834764831845f;
    const int swz = (lm & 7) << 3;

    const ushort* kbase = QKV + (size_t)(b * SS) * QKVS + 2048 + g * HDIM;
    const ushort* vbase = VT + ((size_t)b * DKV + g * HDIM) * SS;

    auto stage = [&](int bufi, int tile) {
        int kv0 = tile * 64;
#pragma unroll
        for (int it = 0; it < 4; ++it) {
            int c = t + it * 256;
            {  // K: 64 rows x 16 chunks
                int row = c >> 4, o = c & 15;
                const ushort* src = kbase + (size_t)(kv0 + row) * QKVS + ((o ^ (row & 7)) * 8);
                __builtin_amdgcn_global_load_lds(
                    (const __attribute__((address_space(1))) unsigned int*)src,
                    (__attribute__((address_space(3))) unsigned int*)&Ks[bufi][c * 8], 16, 0, 0);
            }
            {  // V: 128 rows x 8 chunks
                int row = c >> 3, o = c & 7;
                const ushort* src = vbase + (size_t)row * SS + kv0 + ((o ^ (row & 7)) * 8);
                __builtin_amdgcn_global_load_lds(
                    (const __attribute__((address_space(1))) unsigned int*)src,
                    (__attribute__((address_space(3))) unsigned int*)&Vs[bufi][c * 8], 16, 0, 0);
            }
        }
    };

#pragma unroll 1
    for (int phase = 0; phase < 2; ++phase) {
        const int qt = (phase == 0) ? blockIdx.x : (SS / 64 - 1 - blockIdx.x);
        const int q0 = qt * 64;
        const int qw = q0 + w * 16;
        const int ntiles = qt + 1;

        // Q fragments: lane lm holds Q row (qw+lm), k = kk*32 + lw*8 + j
        bf16x8 qa[4];
        {
            const ushort* qp = QKV + (size_t)(b * SS + qw + lm) * QKVS + h * HDIM + lw * 8;
#pragma unroll
            for (int kk = 0; kk < 4; ++kk)
                qa[kk] = *(const bf16x8*)(qp + kk * 32);
        }

        f32x4 acc[8];
#pragma unroll
        for (int d = 0; d < 8; ++d) acc[d] = (f32x4){0.f, 0.f, 0.f, 0.f};
        float mrow[4] = {-INFINITY, -INFINITY, -INFINITY, -INFINITY};
        float lrow[4] = {0.f, 0.f, 0.f, 0.f};

        stage(0, 0);
        asm volatile("s_waitcnt vmcnt(0)" ::: "memory");
        __syncthreads();

#pragma unroll 1
        for (int tile = 0; tile < ntiles; ++tile) {
            const int cur = tile & 1;
            const int kv0 = tile * 64;
            if (tile + 1 < ntiles) stage(cur ^ 1, tile + 1);  // async prefetch

            // ---- QK^T ----
            f32x4 sf[4];
#pragma unroll
            for (int kvb = 0; kvb < 4; ++kvb) sf[kvb] = (f32x4){0.f, 0.f, 0.f, 0.f};
#pragma unroll
            for (int kvb = 0; kvb < 4; ++kvb)
#pragma unroll
                for (int kk = 0; kk < 4; ++kk) {
                    bf16x8 kb = *(const bf16x8*)&Ks[cur][(kvb * 16 + lm) * 128 + ((kk * 32 + lw * 8) ^ swz)];
                    sf[kvb] = __builtin_amdgcn_mfma_f32_16x16x32_bf16(qa[kk], kb, sf[kvb], 0, 0, 0);
                }

            // ---- online softmax (C/D: row = lw*4+r, col = kvb*16+lm) ----
            float alpha[4];
#pragma unroll
            for (int r = 0; r < 4; ++r) {
                int qrow = qw + lw * 4 + r;
                float sv[4];
#pragma unroll
                for (int kvb = 0; kvb < 4; ++kvb) {
                    int kvcol = kv0 + kvb * 16 + lm;
                    float x = sf[kvb][r] * scale;
                    sv[kvb] = (kvcol <= qrow) ? x : -INFINITY;
                }
                float rm = fmaxf(fmaxf(sv[0], sv[1]), fmaxf(sv[2], sv[3]));
                rm = fmaxf(rm, __shfl_xor(rm, 1));
                rm = fmaxf(rm, __shfl_xor(rm, 2));
                rm = fmaxf(rm, __shfl_xor(rm, 4));
                rm = fmaxf(rm, __shfl_xor(rm, 8));
                float mn = fmaxf(mrow[r], rm);
                float a = __expf(mrow[r] - mn);
                mrow[r] = mn;
                alpha[r] = a;
                float rs = 0.f;
#pragma unroll
                for (int kvb = 0; kvb < 4; ++kvb) {
                    float pv = __expf(sv[kvb] - mn);
                    rs += pv;
                    Ps[w][(lw * 4 + r) * PSP + kvb * 16 + lm] = f2bf(pv);
                }
                rs += __shfl_xor(rs, 1);
                rs += __shfl_xor(rs, 2);
                rs += __shfl_xor(rs, 4);
                rs += __shfl_xor(rs, 8);
                lrow[r] = lrow[r] * a + rs;
            }
#pragma unroll
            for (int d = 0; d < 8; ++d) {
                acc[d][0] *= alpha[0];
                acc[d][1] *= alpha[1];
                acc[d][2] *= alpha[2];
                acc[d][3] *= alpha[3];
            }

            // ---- PV ----
#pragma unroll
            for (int kks = 0; kks < 2; ++kks) {
                bf16x8 pa = *(const bf16x8*)&Ps[w][lm * PSP + kks * 32 + lw * 8];
#pragma unroll
                for (int dcol = 0; dcol < 8; ++dcol) {
                    bf16x8 vb = *(const bf16x8*)&Vs[cur][(dcol * 16 + lm) * 64 + ((kks * 32 + lw * 8) ^ swz)];
                    acc[dcol] = __builtin_amdgcn_mfma_f32_16x16x32_bf16(pa, vb, acc[dcol], 0, 0, 0);
                }
            }

            // drain prefetch, release buffers
            asm volatile("s_waitcnt vmcnt(0)" ::: "memory");
            __syncthreads();
        }

        // ---- epilogue ----
        float rinv[4];
#pragma unroll
        for (int r = 0; r < 4; ++r) rinv[r] = 1.f / lrow[r];
        ushort* cp = Ctx + (size_t)(b * SS + qw) * DD + h * HDIM;
#pragma unroll
        for (int d = 0; d < 8; ++d)
#pragma unroll
            for (int r = 0; r < 4; ++r)
                cp[(size_t)(lw * 4 + r) * DD + d * 16 + lm] = f2bf(acc[d][r] * rinv[r]);
    }
}

extern "C" void kernel_launch(void* const* d_in, const int* in_sizes, int n_in,
                              void* d_out, int out_size, void* d_ws, size_t ws_size,
                              hipStream_t stream) {
    const float* x  = (const float*)d_in[0];
    const float* Wq = (const float*)d_in[1];
    const float* Wk = (const float*)d_in[2];
    const float* Wv = (const float*)d_in[3];
    const float* Wo = (const float*)d_in[4];
    float* out = (float*)d_out;

    // bf16 workspace (~67 MB)
    ushort* xh    = (ushort*)d_ws;                    // [MS, DD]
    ushort* QKV   = xh + (size_t)MS * DD;             // [MS, QKVS]
    ushort* VTb   = QKV + (size_t)MS * QKVS;          // [BB*DKV, SS]
    ushort* WqkvT = VTb + (size_t)MS * DKV;           // [QKVS, DD]
    ushort* WoT   = WqkvT + (size_t)QKVS * DD;        // [DD, DD]
    ushort* Ch    = xh;                               // ctx bf16 aliases xh

    dim3 blk(256);
    int nx8 = MS * DD / 8;
    cast_bf16<<<(nx8 + 255) / 256, 256, 0, stream>>>(x, xh, nx8);

    // fused QKV weight transpose: rows 0..2047 = WqT, 2048..2559 = WkT, 2560..3071 = WvT
    transpose_cast<<<dim3(DD / 32, DD / 32), blk, 0, stream>>>(Wq, WqkvT, DD, DD);
    transpose_cast<<<dim3(DKV / 32, DD / 32), blk, 0, stream>>>(Wk, WqkvT + (size_t)DD * DD, DD, DKV);
    transpose_cast<<<dim3(DKV / 32, DD / 32), blk, 0, stream>>>(Wv, WqkvT + (size_t)(DD + DKV) * DD, DD, DKV);

    // one fused QKV GEMM: [MS, 3072]
    gemm_bf16<true><<<dim3(QKVS / TBN, MS / TBM), blk, 0, stream>>>(xh, WqkvT, QKV, MS, QKVS, DD);

    int nq = MS * HH * 64;
    rope_bf16<<<(nq + 255) / 256, 256, 0, stream>>>(QKV, HH, 0, nq);
    int nk = MS * GG * 64;
    rope_bf16<<<(nk + 255) / 256, 256, 0, stream>>>(QKV, GG, 2048, nk);

    transpose_v<<<dim3(DKV / 32, SS / 32, BB), blk, 0, stream>>>(QKV, VTb);

    attn_mfma<<<dim3(SS / 128, HH, BB), blk, 0, stream>>>(QKV, VTb, Ch);

    transpose_cast<<<dim3(DD / 32, DD / 32), blk, 0, stream>>>(Wo, WoT, DD, DD);
    gemm_bf16<false><<<dim3(DD / TBN, MS / TBM), blk, 0, stream>>>(Ch, WoT, out, MS, DD, DD);
}

// Round 7
// 270.375 us; speedup vs baseline: 22.2020x; 1.0226x over previous
//
#include <hip/hip_runtime.h>
#include <hip/hip_bf16.h>
#include <math.h>

// Problem constants
#define BB 2
#define SS 2048
#define DD 2048
#define HH 16
#define GG 4
#define HDIM 128
#define DKV (GG * HDIM)      // 512
#define MS (BB * SS)         // 4096 rows
#define QKVS 3072            // fused QKV row stride (2048 Q + 512 K + 512 V)

typedef __attribute__((ext_vector_type(8))) short bf16x8;
typedef __attribute__((ext_vector_type(4))) float f32x4;
typedef __attribute__((ext_vector_type(4))) unsigned int u32x4;

__device__ __forceinline__ ushort f2bf(float x) {
    __hip_bfloat16 b = __float2bfloat16(x);
    return *(ushort*)&b;
}
__device__ __forceinline__ float bf2f(ushort u) {
    __hip_bfloat16 b;
    *(ushort*)&b = u;
    return __bfloat162float(b);
}

// ---------------- fp32 -> bf16 cast, 8 elems/thread ----------------
__global__ void cast_bf16(const float* __restrict__ X, ushort* __restrict__ O, int total8) {
    int idx = blockIdx.x * blockDim.x + threadIdx.x;
    if (idx >= total8) return;
    const float4* p = (const float4*)X + (size_t)idx * 2;
    float4 a = p[0], b = p[1];
    float v[8] = {a.x, a.y, a.z, a.w, b.x, b.y, b.z, b.w};
    ushort r[8];
#pragma unroll
    for (int j = 0; j < 8; ++j) r[j] = f2bf(v[j]);
    *((u32x4*)O + idx) = *(u32x4*)r;
}

// ---------------- transpose + cast: WT[n*K + k] = bf16(W[k*N + n]) ----------------
__global__ __launch_bounds__(256) void transpose_cast(const float* __restrict__ W,
                                                      ushort* __restrict__ WT,
                                                      int K, int N) {
    __shared__ ushort tile[32][33];
    const int tx = threadIdx.x & 31, ty = threadIdx.x >> 5;  // 32 x 8
    const int n0 = blockIdx.x * 32, k0 = blockIdx.y * 32;
#pragma unroll
    for (int i = 0; i < 4; ++i)
        tile[ty + i * 8][tx] = f2bf(W[(size_t)(k0 + ty + i * 8) * N + n0 + tx]);
    __syncthreads();
#pragma unroll
    for (int i = 0; i < 4; ++i)
        WT[(size_t)(n0 + ty + i * 8) * K + k0 + tx] = tile[tx][ty + i * 8];
}

// ---- per-batch V transpose from fused QKV: VT[b*DKV + dkv][kv] = QKV[b*SS+kv][2560+dkv]
__global__ __launch_bounds__(256) void transpose_v(const ushort* __restrict__ QKV,
                                                   ushort* __restrict__ VT) {
    __shared__ ushort tile[32][33];
    const int tx = threadIdx.x & 31, ty = threadIdx.x >> 5;  // 32 x 8
    const int d0 = blockIdx.x * 32;  // dkv
    const int k0 = blockIdx.y * 32;  // kv
    const int b = blockIdx.z;
#pragma unroll
    for (int i = 0; i < 4; ++i)
        tile[ty + i * 8][tx] =
            QKV[(size_t)(b * SS + k0 + ty + i * 8) * QKVS + 2560 + d0 + tx];
    __syncthreads();
#pragma unroll
    for (int i = 0; i < 4; ++i)
        VT[((size_t)b * DKV + d0 + ty + i * 8) * SS + k0 + tx] = tile[tx][ty + i * 8];
}

// ---------------- bf16 MFMA GEMM (m97 structure + T1 XCD swizzle) ----------------
// C = A[M,K] x BT[N,K]^T.  Grid must have (gridDim.x*gridDim.y) % 8 == 0.
#define TBM 128
#define TBN 128
#define TBK 32

template <bool OUT_BF16>
__global__ __launch_bounds__(256) void gemm_bf16(const ushort* __restrict__ A,
                                                 const ushort* __restrict__ BT,
                                                 void* __restrict__ Cout,
                                                 int M, int N, int K) {
    __shared__ ushort As[TBM * TBK];  // 8 KB
    __shared__ ushort Bs[TBN * TBK];  // 8 KB
    const int t = threadIdx.x;
    const int w = t >> 6, l = t & 63;
    const int lm = l & 15, lw = l >> 4;
    // XCD-aware swizzle (T1): consecutive swizzled ids land on the same XCD
    const int nx = gridDim.x;
    const int bid = blockIdx.y * nx + blockIdx.x;
    const int cpx = (nx * gridDim.y) >> 3;
    const int swb = (bid & 7) * cpx + (bid >> 3);
    const int bm = (swb / nx) * TBM, bn = (swb % nx) * TBN;
    const int wr = w >> 1, wc = w & 1;

    f32x4 acc[4][4];
#pragma unroll
    for (int m = 0; m < 4; ++m)
#pragma unroll
        for (int n = 0; n < 4; ++n) acc[m][n] = (f32x4){0.f, 0.f, 0.f, 0.f};

    for (int k0 = 0; k0 < K; k0 += TBK) {
        __syncthreads();
#pragma unroll
        for (int it = 0; it < 2; ++it) {
            int c = t + it * 256;
            const ushort* ga = A + (size_t)(bm + (c >> 2)) * K + k0 + (c & 3) * 8;
            const ushort* gb = BT + (size_t)(bn + (c >> 2)) * K + k0 + (c & 3) * 8;
            __builtin_amdgcn_global_load_lds(
                (const __attribute__((address_space(1))) unsigned int*)ga,
                (__attribute__((address_space(3))) unsigned int*)&As[c * 8], 16, 0, 0);
            __builtin_amdgcn_global_load_lds(
                (const __attribute__((address_space(1))) unsigned int*)gb,
                (__attribute__((address_space(3))) unsigned int*)&Bs[c * 8], 16, 0, 0);
        }
        asm volatile("s_waitcnt vmcnt(0)" ::: "memory");
        __syncthreads();

        bf16x8 af[4], bfr[4];
#pragma unroll
        for (int m = 0; m < 4; ++m)
            af[m] = *(const bf16x8*)&As[(wr * 64 + m * 16 + lm) * TBK + lw * 8];
#pragma unroll
        for (int n = 0; n < 4; ++n)
            bfr[n] = *(const bf16x8*)&Bs[(wc * 64 + n * 16 + lm) * TBK + lw * 8];
#pragma unroll
        for (int m = 0; m < 4; ++m)
#pragma unroll
            for (int n = 0; n < 4; ++n)
                acc[m][n] = __builtin_amdgcn_mfma_f32_16x16x32_bf16(af[m], bfr[n], acc[m][n], 0, 0, 0);
    }

#pragma unroll
    for (int m = 0; m < 4; ++m)
#pragma unroll
        for (int n = 0; n < 4; ++n)
#pragma unroll
            for (int r = 0; r < 4; ++r) {
                int row = bm + wr * 64 + m * 16 + lw * 4 + r;
                int col = bn + wc * 64 + n * 16 + lm;
                if (OUT_BF16)
                    ((ushort*)Cout)[(size_t)row * N + col] = f2bf(acc[m][n][r]);
                else
                    ((float*)Cout)[(size_t)row * N + col] = acc[m][n][r];
            }
}

// ---------------- RoPE in-place on bf16 (strided, fused-QKV aware) ----------------
__global__ void rope_bf16(ushort* __restrict__ X, int nheads, int colOff, int total) {
    int idx = blockIdx.x * blockDim.x + threadIdx.x;
    if (idx >= total) return;
    int i = idx & 63;
    int hh = (idx >> 6) % nheads;
    int row = idx / (64 * nheads);
    int s = row & (SS - 1);
    float inv = powf(10000.f, -(2.f * (float)i) / 128.f);
    float ang = (float)s * inv;
    float c, sn;
    __sincosf(ang, &sn, &c);
    size_t base = (size_t)row * QKVS + colOff + (size_t)hh * HDIM + i;
    float x1 = bf2f(X[base]), x2 = bf2f(X[base + 64]);
    X[base] = f2bf(x1 * c - x2 * sn);
    X[base + 64] = f2bf(x2 * c + x1 * sn);
}

// ---------------- MFMA flash attention ----------------
// dbuf 2-phase pipeline, paired q-tiles {x, 31-x} (constant 33 KV-tiles/block).
// Softmax: raw scores; scale*log2e folded into exp2 FMA; mask only on the
// diagonal tile; l computed by ones-MFMA (inherits alpha rescale); defer-max
// (T13, THR=8 ln-units) skips rescale when the running max is stable.
#define PSP 72
#define SCL 0.08838834764831845f          // 1/sqrt(128)
#define CEXP 0.1275296340545927f          // SCL * log2(e)
#define THRRAW 90.50966799187809f         // 8 / SCL

__global__ __launch_bounds__(256) void attn_mfma(const ushort* __restrict__ QKV,
                                                 const ushort* __restrict__ VT,
                                                 ushort* __restrict__ Ctx) {
    __shared__ ushort Ks[2][64 * 128];  // 2 x 16 KB
    __shared__ ushort Vs[2][128 * 64];  // 2 x 16 KB
    __shared__ ushort Ps[4][16 * PSP];  // 9 KB
    const int t = threadIdx.x;
    const int w = t >> 6;
    const int l = t & 63;
    const int lm = l & 15, lw = l >> 4;
    const int h = blockIdx.y;
    const int b = blockIdx.z;
    const int g = h >> 2;
    const int swz = (lm & 7) << 3;

    const ushort* kbase = QKV + (size_t)(b * SS) * QKVS + 2048 + g * HDIM;
    const ushort* vbase = VT + ((size_t)b * DKV + g * HDIM) * SS;

    const short one_bf = (short)0x3F80;
    const bf16x8 ones = {one_bf, one_bf, one_bf, one_bf, one_bf, one_bf, one_bf, one_bf};

    auto stage = [&](int bufi, int tile) {
        int kv0 = tile * 64;
#pragma unroll
        for (int it = 0; it < 4; ++it) {
            int c = t + it * 256;
            {  // K: 64 rows x 16 chunks
                int row = c >> 4, o = c & 15;
                const ushort* src = kbase + (size_t)(kv0 + row) * QKVS + ((o ^ (row & 7)) * 8);
                __builtin_amdgcn_global_load_lds(
                    (const __attribute__((address_space(1))) unsigned int*)src,
                    (__attribute__((address_space(3))) unsigned int*)&Ks[bufi][c * 8], 16, 0, 0);
            }
            {  // V: 128 rows x 8 chunks
                int row = c >> 3, o = c & 7;
                const ushort* src = vbase + (size_t)row * SS + kv0 + ((o ^ (row & 7)) * 8);
                __builtin_amdgcn_global_load_lds(
                    (const __attribute__((address_space(1))) unsigned int*)src,
                    (__attribute__((address_space(3))) unsigned int*)&Vs[bufi][c * 8], 16, 0, 0);
            }
        }
    };

#pragma unroll 1
    for (int phase = 0; phase < 2; ++phase) {
        const int qt = (phase == 0) ? blockIdx.x : (SS / 64 - 1 - blockIdx.x);
        const int q0 = qt * 64;
        const int qw = q0 + w * 16;
        const int ntiles = qt + 1;

        bf16x8 qa[4];
        {
            const ushort* qp = QKV + (size_t)(b * SS + qw + lm) * QKVS + h * HDIM + lw * 8;
#pragma unroll
            for (int kk = 0; kk < 4; ++kk)
                qa[kk] = *(const bf16x8*)(qp + kk * 32);
        }

        f32x4 acc[8];
#pragma unroll
        for (int d = 0; d < 8; ++d) acc[d] = (f32x4){0.f, 0.f, 0.f, 0.f};
        f32x4 accl = (f32x4){0.f, 0.f, 0.f, 0.f};
        float mrow[4] = {-INFINITY, -INFINITY, -INFINITY, -INFINITY};

        stage(0, 0);
        asm volatile("s_waitcnt vmcnt(0)" ::: "memory");
        __syncthreads();

#pragma unroll 1
        for (int tile = 0; tile < ntiles; ++tile) {
            const int cur = tile & 1;
            const int kv0 = tile * 64;
            if (tile + 1 < ntiles) stage(cur ^ 1, tile + 1);  // async prefetch

            // ---- QK^T (raw scores) ----
            f32x4 sf[4];
#pragma unroll
            for (int kvb = 0; kvb < 4; ++kvb) sf[kvb] = (f32x4){0.f, 0.f, 0.f, 0.f};
            __builtin_amdgcn_s_setprio(1);
#pragma unroll
            for (int kvb = 0; kvb < 4; ++kvb)
#pragma unroll
                for (int kk = 0; kk < 4; ++kk) {
                    bf16x8 kb = *(const bf16x8*)&Ks[cur][(kvb * 16 + lm) * 128 + ((kk * 32 + lw * 8) ^ swz)];
                    sf[kvb] = __builtin_amdgcn_mfma_f32_16x16x32_bf16(qa[kk], kb, sf[kvb], 0, 0, 0);
                }
            __builtin_amdgcn_s_setprio(0);

            // ---- online softmax (mask only on diagonal tile) ----
            const bool diag = (tile == ntiles - 1);
            float sv[4][4];
            float rmax[4];
#pragma unroll
            for (int r = 0; r < 4; ++r) {
                int qrow = qw + lw * 4 + r;
#pragma unroll
                for (int kvb = 0; kvb < 4; ++kvb) {
                    float x = sf[kvb][r];
                    if (diag && (kv0 + kvb * 16 + lm > qrow)) x = -INFINITY;
                    sv[r][kvb] = x;
                }
                float rm = fmaxf(fmaxf(sv[r][0], sv[r][1]), fmaxf(sv[r][2], sv[r][3]));
                rm = fmaxf(rm, __shfl_xor(rm, 1));
                rm = fmaxf(rm, __shfl_xor(rm, 2));
                rm = fmaxf(rm, __shfl_xor(rm, 4));
                rm = fmaxf(rm, __shfl_xor(rm, 8));
                rmax[r] = rm;
            }
            // defer-max: skip rescale when max growth bounded (P <= e^8)
            bool stable = (rmax[0] - mrow[0] <= THRRAW) && (rmax[1] - mrow[1] <= THRRAW) &&
                          (rmax[2] - mrow[2] <= THRRAW) && (rmax[3] - mrow[3] <= THRRAW);
            if (!__all((int)stable)) {
                float alpha[4];
#pragma unroll
                for (int r = 0; r < 4; ++r) {
                    float mn = fmaxf(mrow[r], rmax[r]);
                    alpha[r] = exp2f((mrow[r] - mn) * CEXP);
                    mrow[r] = mn;
                }
#pragma unroll
                for (int d = 0; d < 8; ++d) {
                    acc[d][0] *= alpha[0];
                    acc[d][1] *= alpha[1];
                    acc[d][2] *= alpha[2];
                    acc[d][3] *= alpha[3];
                }
                accl[0] *= alpha[0];
                accl[1] *= alpha[1];
                accl[2] *= alpha[2];
                accl[3] *= alpha[3];
            }
            // P = exp2(s*C - m*C), bf16, to Ps
#pragma unroll
            for (int r = 0; r < 4; ++r) {
                float mnC = mrow[r] * CEXP;
#pragma unroll
                for (int kvb = 0; kvb < 4; ++kvb) {
                    float pv = exp2f(fmaf(sv[r][kvb], CEXP, -mnC));
                    Ps[w][(lw * 4 + r) * PSP + kvb * 16 + lm] = f2bf(pv);
                }
            }

            // ---- PV + l-accumulation via ones-MFMA ----
            __builtin_amdgcn_s_setprio(1);
#pragma unroll
            for (int kks = 0; kks < 2; ++kks) {
                bf16x8 pa = *(const bf16x8*)&Ps[w][lm * PSP + kks * 32 + lw * 8];
                accl = __builtin_amdgcn_mfma_f32_16x16x32_bf16(pa, ones, accl, 0, 0, 0);
#pragma unroll
                for (int dcol = 0; dcol < 8; ++dcol) {
                    bf16x8 vb = *(const bf16x8*)&Vs[cur][(dcol * 16 + lm) * 64 + ((kks * 32 + lw * 8) ^ swz)];
                    acc[dcol] = __builtin_amdgcn_mfma_f32_16x16x32_bf16(pa, vb, acc[dcol], 0, 0, 0);
                }
            }
            __builtin_amdgcn_s_setprio(0);

            // drain prefetch, release buffers
            asm volatile("s_waitcnt vmcnt(0)" ::: "memory");
            __syncthreads();
        }

        // ---- epilogue ----
        float rinv[4];
#pragma unroll
        for (int r = 0; r < 4; ++r) rinv[r] = 1.f / accl[r];
        ushort* cp = Ctx + (size_t)(b * SS + qw) * DD + h * HDIM;
#pragma unroll
        for (int d = 0; d < 8; ++d)
#pragma unroll
            for (int r = 0; r < 4; ++r)
                cp[(size_t)(lw * 4 + r) * DD + d * 16 + lm] = f2bf(acc[d][r] * rinv[r]);
    }
}

extern "C" void kernel_launch(void* const* d_in, const int* in_sizes, int n_in,
                              void* d_out, int out_size, void* d_ws, size_t ws_size,
                              hipStream_t stream) {
    const float* x  = (const float*)d_in[0];
    const float* Wq = (const float*)d_in[1];
    const float* Wk = (const float*)d_in[2];
    const float* Wv = (const float*)d_in[3];
    const float* Wo = (const float*)d_in[4];
    float* out = (float*)d_out;

    // bf16 workspace (~67 MB)
    ushort* xh    = (ushort*)d_ws;                    // [MS, DD]
    ushort* QKV   = xh + (size_t)MS * DD;             // [MS, QKVS]
    ushort* VTb   = QKV + (size_t)MS * QKVS;          // [BB*DKV, SS]
    ushort* WqkvT = VTb + (size_t)MS * DKV;           // [QKVS, DD]
    ushort* WoT   = WqkvT + (size_t)QKVS * DD;        // [DD, DD]
    ushort* Ch    = xh;                               // ctx bf16 aliases xh

    dim3 blk(256);
    int nx8 = MS * DD / 8;
    cast_bf16<<<(nx8 + 255) / 256, 256, 0, stream>>>(x, xh, nx8);

    // fused QKV weight transpose: rows 0..2047 = WqT, 2048..2559 = WkT, 2560..3071 = WvT
    transpose_cast<<<dim3(DD / 32, DD / 32), blk, 0, stream>>>(Wq, WqkvT, DD, DD);
    transpose_cast<<<dim3(DKV / 32, DD / 32), blk, 0, stream>>>(Wk, WqkvT + (size_t)DD * DD, DD, DKV);
    transpose_cast<<<dim3(DKV / 32, DD / 32), blk, 0, stream>>>(Wv, WqkvT + (size_t)(DD + DKV) * DD, DD, DKV);

    // one fused QKV GEMM: [MS, 3072]
    gemm_bf16<true><<<dim3(QKVS / TBN, MS / TBM), blk, 0, stream>>>(xh, WqkvT, QKV, MS, QKVS, DD);

    int nq = MS * HH * 64;
    rope_bf16<<<(nq + 255) / 256, 256, 0, stream>>>(QKV, HH, 0, nq);
    int nk = MS * GG * 64;
    rope_bf16<<<(nk + 255) / 256, 256, 0, stream>>>(QKV, GG, 2048, nk);

    transpose_v<<<dim3(DKV / 32, SS / 32, BB), blk, 0, stream>>>(QKV, VTb);

    attn_mfma<<<dim3(SS / 128, HH, BB), blk, 0, stream>>>(QKV, VTb, Ch);

    transpose_cast<<<dim3(DD / 32, DD / 32), blk, 0, stream>>>(Wo, WoT, DD, DD);
    gemm_bf16<false><<<dim3(DD / TBN, MS / TBM), blk, 0, stream>>>(Ch, WoT, out, MS, DD, DD);
}

// Round 8
// 253.582 us; speedup vs baseline: 23.6722x; 1.0662x over previous
//
#include <hip/hip_runtime.h>
#include <hip/hip_bf16.h>
#include <math.h>

// Problem constants
#define BB 2
#define SS 2048
#define DD 2048
#define HH 16
#define GG 4
#define HDIM 128
#define DKV (GG * HDIM)      // 512
#define MS (BB * SS)         // 4096 rows
#define QKVS 3072            // fused QKV row stride (2048 Q + 512 K + 512 V)

typedef __attribute__((ext_vector_type(8))) short bf16x8;
typedef __attribute__((ext_vector_type(4))) float f32x4;
typedef __attribute__((ext_vector_type(4))) unsigned int u32x4;

__device__ __forceinline__ ushort f2bf(float x) {
    __hip_bfloat16 b = __float2bfloat16(x);
    return *(ushort*)&b;
}
__device__ __forceinline__ float bf2f(ushort u) {
    __hip_bfloat16 b;
    *(ushort*)&b = u;
    return __bfloat162float(b);
}

#define GLOAD_LDS(src, dst)                                                        \
    __builtin_amdgcn_global_load_lds(                                              \
        (const __attribute__((address_space(1))) unsigned int*)(src),              \
        (__attribute__((address_space(3))) unsigned int*)(dst), 16, 0, 0)

// ---------------- fp32 -> bf16 cast, 8 elems/thread ----------------
__global__ void cast_bf16(const float* __restrict__ X, ushort* __restrict__ O, int total8) {
    int idx = blockIdx.x * blockDim.x + threadIdx.x;
    if (idx >= total8) return;
    const float4* p = (const float4*)X + (size_t)idx * 2;
    float4 a = p[0], b = p[1];
    float v[8] = {a.x, a.y, a.z, a.w, b.x, b.y, b.z, b.w};
    ushort r[8];
#pragma unroll
    for (int j = 0; j < 8; ++j) r[j] = f2bf(v[j]);
    *((u32x4*)O + idx) = *(u32x4*)r;
}

// ---------------- transpose + cast: WT[n*K + k] = bf16(W[k*N + n]) ----------------
__global__ __launch_bounds__(256) void transpose_cast(const float* __restrict__ W,
                                                      ushort* __restrict__ WT,
                                                      int K, int N) {
    __shared__ ushort tile[32][33];
    const int tx = threadIdx.x & 31, ty = threadIdx.x >> 5;  // 32 x 8
    const int n0 = blockIdx.x * 32, k0 = blockIdx.y * 32;
#pragma unroll
    for (int i = 0; i < 4; ++i)
        tile[ty + i * 8][tx] = f2bf(W[(size_t)(k0 + ty + i * 8) * N + n0 + tx]);
    __syncthreads();
#pragma unroll
    for (int i = 0; i < 4; ++i)
        WT[(size_t)(n0 + ty + i * 8) * K + k0 + tx] = tile[tx][ty + i * 8];
}

// ---- per-batch V transpose from fused QKV: VT[b*DKV + dkv][kv] = QKV[b*SS+kv][2560+dkv]
__global__ __launch_bounds__(256) void transpose_v(const ushort* __restrict__ QKV,
                                                   ushort* __restrict__ VT) {
    __shared__ ushort tile[32][33];
    const int tx = threadIdx.x & 31, ty = threadIdx.x >> 5;  // 32 x 8
    const int d0 = blockIdx.x * 32;  // dkv
    const int k0 = blockIdx.y * 32;  // kv
    const int b = blockIdx.z;
#pragma unroll
    for (int i = 0; i < 4; ++i)
        tile[ty + i * 8][tx] =
            QKV[(size_t)(b * SS + k0 + ty + i * 8) * QKVS + 2560 + d0 + tx];
    __syncthreads();
#pragma unroll
    for (int i = 0; i < 4; ++i)
        VT[((size_t)b * DKV + d0 + ty + i * 8) * SS + k0 + tx] = tile[tx][ty + i * 8];
}

// ---------------- bf16 MFMA GEMM (m97 structure + T1 XCD swizzle) ----------------
#define TBM 128
#define TBN 128
#define TBK 32

template <bool OUT_BF16>
__global__ __launch_bounds__(256) void gemm_bf16(const ushort* __restrict__ A,
                                                 const ushort* __restrict__ BT,
                                                 void* __restrict__ Cout,
                                                 int M, int N, int K) {
    __shared__ ushort As[TBM * TBK];  // 8 KB
    __shared__ ushort Bs[TBN * TBK];  // 8 KB
    const int t = threadIdx.x;
    const int w = t >> 6, l = t & 63;
    const int lm = l & 15, lw = l >> 4;
    const int nx = gridDim.x;
    const int bid = blockIdx.y * nx + blockIdx.x;
    const int cpx = (nx * gridDim.y) >> 3;
    const int swb = (bid & 7) * cpx + (bid >> 3);
    const int bm = (swb / nx) * TBM, bn = (swb % nx) * TBN;
    const int wr = w >> 1, wc = w & 1;

    f32x4 acc[4][4];
#pragma unroll
    for (int m = 0; m < 4; ++m)
#pragma unroll
        for (int n = 0; n < 4; ++n) acc[m][n] = (f32x4){0.f, 0.f, 0.f, 0.f};

    for (int k0 = 0; k0 < K; k0 += TBK) {
        __syncthreads();
#pragma unroll
        for (int it = 0; it < 2; ++it) {
            int c = t + it * 256;
            const ushort* ga = A + (size_t)(bm + (c >> 2)) * K + k0 + (c & 3) * 8;
            const ushort* gb = BT + (size_t)(bn + (c >> 2)) * K + k0 + (c & 3) * 8;
            GLOAD_LDS(ga, &As[c * 8]);
            GLOAD_LDS(gb, &Bs[c * 8]);
        }
        asm volatile("s_waitcnt vmcnt(0)" ::: "memory");
        __syncthreads();

        bf16x8 af[4], bfr[4];
#pragma unroll
        for (int m = 0; m < 4; ++m)
            af[m] = *(const bf16x8*)&As[(wr * 64 + m * 16 + lm) * TBK + lw * 8];
#pragma unroll
        for (int n = 0; n < 4; ++n)
            bfr[n] = *(const bf16x8*)&Bs[(wc * 64 + n * 16 + lm) * TBK + lw * 8];
#pragma unroll
        for (int m = 0; m < 4; ++m)
#pragma unroll
            for (int n = 0; n < 4; ++n)
                acc[m][n] = __builtin_amdgcn_mfma_f32_16x16x32_bf16(af[m], bfr[n], acc[m][n], 0, 0, 0);
    }

#pragma unroll
    for (int m = 0; m < 4; ++m)
#pragma unroll
        for (int n = 0; n < 4; ++n)
#pragma unroll
            for (int r = 0; r < 4; ++r) {
                int row = bm + wr * 64 + m * 16 + lw * 4 + r;
                int col = bn + wc * 64 + n * 16 + lm;
                if (OUT_BF16)
                    ((ushort*)Cout)[(size_t)row * N + col] = f2bf(acc[m][n][r]);
                else
                    ((float*)Cout)[(size_t)row * N + col] = acc[m][n][r];
            }
}

// ---------------- RoPE in-place on bf16 (strided, fused-QKV aware) ----------------
__global__ void rope_bf16(ushort* __restrict__ X, int nheads, int colOff, int total) {
    int idx = blockIdx.x * blockDim.x + threadIdx.x;
    if (idx >= total) return;
    int i = idx & 63;
    int hh = (idx >> 6) % nheads;
    int row = idx / (64 * nheads);
    int s = row & (SS - 1);
    float inv = exp2f((float)i * -0.2076205059304601f);  // 10000^(-2i/128)
    float ang = (float)s * inv;
    float c, sn;
    __sincosf(ang, &sn, &c);
    size_t base = (size_t)row * QKVS + colOff + (size_t)hh * HDIM + i;
    float x1 = bf2f(X[base]), x2 = bf2f(X[base + 64]);
    X[base] = f2bf(x1 * c - x2 * sn);
    X[base + 64] = f2bf(x2 * c + x1 * sn);
}

// ---------------- MFMA flash attention: 8 waves, Q-tile 128, counted-vmcnt ----
// Pairs q-tiles {x, 15-x} (34 KV-tiles/block constant). K double-buffered,
// V single-buffered; raw s_barrier + counted vmcnt(2) (never full drain in
// steady state). Per-tile: 3 barriers. Per-thread incremental source pointers.
#define PSP 72
#define SCL 0.08838834764831845f          // 1/sqrt(128)
#define CEXP 0.1275296340545927f          // SCL * log2(e)
#define THRRAW 90.50966799187809f         // 8 / SCL

__global__ __launch_bounds__(512) void attn_mfma(const ushort* __restrict__ QKV,
                                                 const ushort* __restrict__ VT,
                                                 ushort* __restrict__ Ctx) {
    __shared__ ushort Ks[2][64 * 128];  // 32 KB
    __shared__ ushort Vs[128 * 64];     // 16 KB
    __shared__ ushort Ps[8][16 * PSP];  // 18 KB
    const int t = threadIdx.x;          // 0..511
    const int w = t >> 6;               // wave 0..7
    const int l = t & 63;
    const int lm = l & 15, lw = l >> 4;
    const int h = blockIdx.y;
    const int b = blockIdx.z;
    const int g = h >> 2;
    const int swz = (lm & 7) << 3;

    const ushort* kbase = QKV + (size_t)(b * SS) * QKVS + 2048 + g * HDIM;
    const ushort* vbase = VT + ((size_t)b * DKV + g * HDIM) * SS;

    const short one_bf = (short)0x3F80;
    const bf16x8 ones = {one_bf, one_bf, one_bf, one_bf, one_bf, one_bf, one_bf, one_bf};

    // staging chunk assignment (512 threads, 1024 16B-chunks per tile)
    const int kr0 = t >> 4, ko0 = t & 15;
    const int kr1 = (t + 512) >> 4, ko1 = (t + 512) & 15;
    const int vr0 = t >> 3, vo0 = t & 7;
    const int vr1 = (t + 512) >> 3, vo1 = (t + 512) & 7;
    ushort* kd0a = &Ks[0][t * 8];
    ushort* kd0b = &Ks[1][t * 8];
    ushort* kd1a = &Ks[0][(t + 512) * 8];
    ushort* kd1b = &Ks[1][(t + 512) * 8];
    ushort* vd0 = &Vs[t * 8];
    ushort* vd1 = &Vs[(t + 512) * 8];

#pragma unroll 1
    for (int phase = 0; phase < 2; ++phase) {
        const int qt = (phase == 0) ? blockIdx.x : (15 - blockIdx.x);
        const int q0 = qt * 128;
        const int qw = q0 + w * 16;
        const int ntiles = 2 * qt + 2;
        const int lt = (w * 16 + 15 + q0) >> 6;  // last kv-tile this wave needs

        // per-thread incremental source pointers
        const ushort* ks0 = kbase + (size_t)kr0 * QKVS + ((ko0 ^ (kr0 & 7)) * 8);
        const ushort* ks1 = kbase + (size_t)kr1 * QKVS + ((ko1 ^ (kr1 & 7)) * 8);
        const ushort* vs0 = vbase + (size_t)vr0 * SS + ((vo0 ^ (vr0 & 7)) * 8);
        const ushort* vs1 = vbase + (size_t)vr1 * SS + ((vo1 ^ (vr1 & 7)) * 8);

        bf16x8 qa[4];
        {
            const ushort* qp = QKV + (size_t)(b * SS + qw + lm) * QKVS + h * HDIM + lw * 8;
#pragma unroll
            for (int kk = 0; kk < 4; ++kk)
                qa[kk] = *(const bf16x8*)(qp + kk * 32);
        }

        f32x4 acc[8];
#pragma unroll
        for (int d = 0; d < 8; ++d) acc[d] = (f32x4){0.f, 0.f, 0.f, 0.f};
        f32x4 accl = (f32x4){0.f, 0.f, 0.f, 0.f};
        float mrow[4] = {-INFINITY, -INFINITY, -INFINITY, -INFINITY};

        // prologue: stage K(0), V(0); full drain
        GLOAD_LDS(ks0, kd0a);
        GLOAD_LDS(ks1, kd1a);
        ks0 += 64 * QKVS;
        ks1 += 64 * QKVS;
        GLOAD_LDS(vs0, vd0);
        GLOAD_LDS(vs1, vd1);
        vs0 += 64;
        vs1 += 64;
        asm volatile("s_waitcnt vmcnt(0)" ::: "memory");
        __builtin_amdgcn_s_barrier();

#pragma unroll 1
        for (int tile = 0; tile < ntiles; ++tile) {
            const int cur = tile & 1;
            const int kv0 = tile * 64;
            const bool more = (tile + 1 < ntiles);
            if (more) {  // issue K(t+1) -> other buffer (+2 in flight)
                GLOAD_LDS(ks0, cur ? kd0a : kd0b);
                GLOAD_LDS(ks1, cur ? kd1a : kd1b);
                ks0 += 64 * QKVS;
                ks1 += 64 * QKVS;
            }

            const bool active = (tile <= lt);
            f32x4 sf[4];
            float sv[4][4], rmax[4];
            if (active) {
                // ---- QK^T ----
#pragma unroll
                for (int kvb = 0; kvb < 4; ++kvb) sf[kvb] = (f32x4){0.f, 0.f, 0.f, 0.f};
                __builtin_amdgcn_s_setprio(1);
#pragma unroll
                for (int kvb = 0; kvb < 4; ++kvb)
#pragma unroll
                    for (int kk = 0; kk < 4; ++kk) {
                        bf16x8 kb = *(const bf16x8*)&Ks[cur][(kvb * 16 + lm) * 128 + ((kk * 32 + lw * 8) ^ swz)];
                        sf[kvb] = __builtin_amdgcn_mfma_f32_16x16x32_bf16(qa[kk], kb, sf[kvb], 0, 0, 0);
                    }
                __builtin_amdgcn_s_setprio(0);

                // ---- online softmax (mask only on this wave's diagonal tile) ----
                const bool diag = (tile == lt);
#pragma unroll
                for (int r = 0; r < 4; ++r) {
                    int qrow = qw + lw * 4 + r;
#pragma unroll
                    for (int kvb = 0; kvb < 4; ++kvb) {
                        float x = sf[kvb][r];
                        if (diag && (kv0 + kvb * 16 + lm > qrow)) x = -INFINITY;
                        sv[r][kvb] = x;
                    }
                    float rm = fmaxf(fmaxf(sv[r][0], sv[r][1]), fmaxf(sv[r][2], sv[r][3]));
                    rm = fmaxf(rm, __shfl_xor(rm, 1));
                    rm = fmaxf(rm, __shfl_xor(rm, 2));
                    rm = fmaxf(rm, __shfl_xor(rm, 4));
                    rm = fmaxf(rm, __shfl_xor(rm, 8));
                    rmax[r] = rm;
                }
                bool stable = (rmax[0] - mrow[0] <= THRRAW) && (rmax[1] - mrow[1] <= THRRAW) &&
                              (rmax[2] - mrow[2] <= THRRAW) && (rmax[3] - mrow[3] <= THRRAW);
                if (!__all((int)stable)) {
                    float alpha[4];
#pragma unroll
                    for (int r = 0; r < 4; ++r) {
                        float mn = fmaxf(mrow[r], rmax[r]);
                        alpha[r] = exp2f((mrow[r] - mn) * CEXP);
                        mrow[r] = mn;
                    }
#pragma unroll
                    for (int d = 0; d < 8; ++d) {
                        acc[d][0] *= alpha[0];
                        acc[d][1] *= alpha[1];
                        acc[d][2] *= alpha[2];
                        acc[d][3] *= alpha[3];
                    }
                    accl[0] *= alpha[0];
                    accl[1] *= alpha[1];
                    accl[2] *= alpha[2];
                    accl[3] *= alpha[3];
                }
#pragma unroll
                for (int r = 0; r < 4; ++r) {
                    float mnC = mrow[r] * CEXP;
#pragma unroll
                    for (int kvb = 0; kvb < 4; ++kvb) {
                        float pv = exp2f(fmaf(sv[r][kvb], CEXP, -mnC));
                        Ps[w][(lw * 4 + r) * PSP + kvb * 16 + lm] = f2bf(pv);
                    }
                }
            }

            // V(t) visible: drain all but K(t+1)'s 2 loads, then sync
            if (more)
                asm volatile("s_waitcnt vmcnt(2)" ::: "memory");
            else
                asm volatile("s_waitcnt vmcnt(0)" ::: "memory");
            __builtin_amdgcn_s_barrier();

            if (active) {
                // ---- PV + l via ones-MFMA ----
                __builtin_amdgcn_s_setprio(1);
#pragma unroll
                for (int kks = 0; kks < 2; ++kks) {
                    bf16x8 pa = *(const bf16x8*)&Ps[w][lm * PSP + kks * 32 + lw * 8];
                    accl = __builtin_amdgcn_mfma_f32_16x16x32_bf16(pa, ones, accl, 0, 0, 0);
#pragma unroll
                    for (int dcol = 0; dcol < 8; ++dcol) {
                        bf16x8 vb = *(const bf16x8*)&Vs[(dcol * 16 + lm) * 64 + ((kks * 32 + lw * 8) ^ swz)];
                        acc[dcol] = __builtin_amdgcn_mfma_f32_16x16x32_bf16(pa, vb, acc[dcol], 0, 0, 0);
                    }
                }
                __builtin_amdgcn_s_setprio(0);
            }
            __builtin_amdgcn_s_barrier();  // all done reading Vs

            if (more) {  // issue V(t+1) into the (now free) single buffer
                GLOAD_LDS(vs0, vd0);
                GLOAD_LDS(vs1, vd1);
                vs0 += 64;
                vs1 += 64;
                // K(t+1) visible: drain all but V(t+1)'s 2 loads, then sync
                asm volatile("s_waitcnt vmcnt(2)" ::: "memory");
                __builtin_amdgcn_s_barrier();
            }
        }

        // ---- epilogue ----
        float rinv[4];
#pragma unroll
        for (int r = 0; r < 4; ++r) rinv[r] = 1.f / accl[r];
        ushort* cp = Ctx + (size_t)(b * SS + qw) * DD + h * HDIM;
#pragma unroll
        for (int d = 0; d < 8; ++d)
#pragma unroll
            for (int r = 0; r < 4; ++r)
                cp[(size_t)(lw * 4 + r) * DD + d * 16 + lm] = f2bf(acc[d][r] * rinv[r]);
    }
}

extern "C" void kernel_launch(void* const* d_in, const int* in_sizes, int n_in,
                              void* d_out, int out_size, void* d_ws, size_t ws_size,
                              hipStream_t stream) {
    const float* x  = (const float*)d_in[0];
    const float* Wq = (const float*)d_in[1];
    const float* Wk = (const float*)d_in[2];
    const float* Wv = (const float*)d_in[3];
    const float* Wo = (const float*)d_in[4];
    float* out = (float*)d_out;

    // bf16 workspace (~67 MB)
    ushort* xh    = (ushort*)d_ws;                    // [MS, DD]
    ushort* QKV   = xh + (size_t)MS * DD;             // [MS, QKVS]
    ushort* VTb   = QKV + (size_t)MS * QKVS;          // [BB*DKV, SS]
    ushort* WqkvT = VTb + (size_t)MS * DKV;           // [QKVS, DD]
    ushort* WoT   = WqkvT + (size_t)QKVS * DD;        // [DD, DD]
    ushort* Ch    = xh;                               // ctx bf16 aliases xh

    dim3 blk(256);
    int nx8 = MS * DD / 8;
    cast_bf16<<<(nx8 + 255) / 256, 256, 0, stream>>>(x, xh, nx8);

    transpose_cast<<<dim3(DD / 32, DD / 32), blk, 0, stream>>>(Wq, WqkvT, DD, DD);
    transpose_cast<<<dim3(DKV / 32, DD / 32), blk, 0, stream>>>(Wk, WqkvT + (size_t)DD * DD, DD, DKV);
    transpose_cast<<<dim3(DKV / 32, DD / 32), blk, 0, stream>>>(Wv, WqkvT + (size_t)(DD + DKV) * DD, DD, DKV);

    gemm_bf16<true><<<dim3(QKVS / TBN, MS / TBM), blk, 0, stream>>>(xh, WqkvT, QKV, MS, QKVS, DD);

    int nq = MS * HH * 64;
    rope_bf16<<<(nq + 255) / 256, 256, 0, stream>>>(QKV, HH, 0, nq);
    int nk = MS * GG * 64;
    rope_bf16<<<(nk + 255) / 256, 256, 0, stream>>>(QKV, GG, 2048, nk);

    transpose_v<<<dim3(DKV / 32, SS / 32, BB), blk, 0, stream>>>(QKV, VTb);

    attn_mfma<<<dim3(8, HH, BB), dim3(512), 0, stream>>>(QKV, VTb, Ch);

    transpose_cast<<<dim3(DD / 32, DD / 32), blk, 0, stream>>>(Wo, WoT, DD, DD);
    gemm_bf16<false><<<dim3(DD / TBN, MS / TBM), blk, 0, stream>>>(Ch, WoT, out, MS, DD, DD);
}

// Round 9
// 231.445 us; speedup vs baseline: 25.9364x; 1.0956x over previous
//
#include <hip/hip_runtime.h>
#include <hip/hip_bf16.h>
#include <math.h>

// Problem constants
#define BB 2
#define SS 2048
#define DD 2048
#define HH 16
#define GG 4
#define HDIM 128
#define DKV (GG * HDIM)      // 512
#define MS (BB * SS)         // 4096 rows
#define QKVS 3072            // fused QKV row stride (2048 Q + 512 K + 512 V)

typedef __attribute__((ext_vector_type(8))) short bf16x8;
typedef __attribute__((ext_vector_type(4))) float f32x4;
typedef __attribute__((ext_vector_type(4))) unsigned int u32x4;

__device__ __forceinline__ ushort f2bf(float x) {
    __hip_bfloat16 b = __float2bfloat16(x);
    return *(ushort*)&b;
}
__device__ __forceinline__ float bf2f(ushort u) {
    __hip_bfloat16 b;
    *(ushort*)&b = u;
    return __bfloat162float(b);
}

#define GLOAD_LDS(src, dst)                                                        \
    __builtin_amdgcn_global_load_lds(                                              \
        (const __attribute__((address_space(1))) unsigned int*)(src),              \
        (__attribute__((address_space(3))) unsigned int*)(dst), 16, 0, 0)

// ---------------- fp32 -> bf16 cast, 8 elems/thread ----------------
__global__ void cast_bf16(const float* __restrict__ X, ushort* __restrict__ O, int total8) {
    int idx = blockIdx.x * blockDim.x + threadIdx.x;
    if (idx >= total8) return;
    const float4* p = (const float4*)X + (size_t)idx * 2;
    float4 a = p[0], b = p[1];
    float v[8] = {a.x, a.y, a.z, a.w, b.x, b.y, b.z, b.w};
    ushort r[8];
#pragma unroll
    for (int j = 0; j < 8; ++j) r[j] = f2bf(v[j]);
    *((u32x4*)O + idx) = *(u32x4*)r;
}

// ---------------- transpose + cast: WT[n*K + k] = bf16(W[k*N + n]) ----------------
__global__ __launch_bounds__(256) void transpose_cast(const float* __restrict__ W,
                                                      ushort* __restrict__ WT,
                                                      int K, int N) {
    __shared__ ushort tile[32][33];
    const int tx = threadIdx.x & 31, ty = threadIdx.x >> 5;  // 32 x 8
    const int n0 = blockIdx.x * 32, k0 = blockIdx.y * 32;
#pragma unroll
    for (int i = 0; i < 4; ++i)
        tile[ty + i * 8][tx] = f2bf(W[(size_t)(k0 + ty + i * 8) * N + n0 + tx]);
    __syncthreads();
#pragma unroll
    for (int i = 0; i < 4; ++i)
        WT[(size_t)(n0 + ty + i * 8) * K + k0 + tx] = tile[tx][ty + i * 8];
}

// ---- per-batch V transpose from fused QKV, with PV-slot column permutation ----
// VT'[b*DKV + dkv][tau(kv)] = QKV[b*SS+kv][2560+dkv]
// tau: kv = 32a+16m+4w+r  ->  pos = 32a+8w+4m+r  (so PV A-fragment needs no shuffles)
__global__ __launch_bounds__(256) void transpose_v(const ushort* __restrict__ QKV,
                                                   ushort* __restrict__ VT) {
    __shared__ ushort tile[32][33];
    const int tx = threadIdx.x & 31, ty = threadIdx.x >> 5;  // 32 x 8
    const int d0 = blockIdx.x * 32;  // dkv
    const int k0 = blockIdx.y * 32;  // kv (32-aligned)
    const int b = blockIdx.z;
#pragma unroll
    for (int i = 0; i < 4; ++i)
        tile[ty + i * 8][tx] =
            QKV[(size_t)(b * SS + k0 + ty + i * 8) * QKVS + 2560 + d0 + tx];
    __syncthreads();
    const int posl = ((tx & 12) << 1) | ((tx & 16) >> 2) | (tx & 3);
#pragma unroll
    for (int i = 0; i < 4; ++i)
        VT[((size_t)b * DKV + d0 + ty + i * 8) * SS + k0 + posl] = tile[tx][ty + i * 8];
}

// ---------------- bf16 MFMA GEMM (m97 structure + T1 XCD swizzle) ----------------
#define TBM 128
#define TBN 128
#define TBK 32

template <bool OUT_BF16>
__global__ __launch_bounds__(256) void gemm_bf16(const ushort* __restrict__ A,
                                                 const ushort* __restrict__ BT,
                                                 void* __restrict__ Cout,
                                                 int M, int N, int K) {
    __shared__ ushort As[TBM * TBK];  // 8 KB
    __shared__ ushort Bs[TBN * TBK];  // 8 KB
    const int t = threadIdx.x;
    const int w = t >> 6, l = t & 63;
    const int lm = l & 15, lw = l >> 4;
    const int nx = gridDim.x;
    const int bid = blockIdx.y * nx + blockIdx.x;
    const int cpx = (nx * gridDim.y) >> 3;
    const int swb = (bid & 7) * cpx + (bid >> 3);
    const int bm = (swb / nx) * TBM, bn = (swb % nx) * TBN;
    const int wr = w >> 1, wc = w & 1;

    f32x4 acc[4][4];
#pragma unroll
    for (int m = 0; m < 4; ++m)
#pragma unroll
        for (int n = 0; n < 4; ++n) acc[m][n] = (f32x4){0.f, 0.f, 0.f, 0.f};

    for (int k0 = 0; k0 < K; k0 += TBK) {
        __syncthreads();
#pragma unroll
        for (int it = 0; it < 2; ++it) {
            int c = t + it * 256;
            const ushort* ga = A + (size_t)(bm + (c >> 2)) * K + k0 + (c & 3) * 8;
            const ushort* gb = BT + (size_t)(bn + (c >> 2)) * K + k0 + (c & 3) * 8;
            GLOAD_LDS(ga, &As[c * 8]);
            GLOAD_LDS(gb, &Bs[c * 8]);
        }
        asm volatile("s_waitcnt vmcnt(0)" ::: "memory");
        __syncthreads();

        bf16x8 af[4], bfr[4];
#pragma unroll
        for (int m = 0; m < 4; ++m)
            af[m] = *(const bf16x8*)&As[(wr * 64 + m * 16 + lm) * TBK + lw * 8];
#pragma unroll
        for (int n = 0; n < 4; ++n)
            bfr[n] = *(const bf16x8*)&Bs[(wc * 64 + n * 16 + lm) * TBK + lw * 8];
#pragma unroll
        for (int m = 0; m < 4; ++m)
#pragma unroll
            for (int n = 0; n < 4; ++n)
                acc[m][n] = __builtin_amdgcn_mfma_f32_16x16x32_bf16(af[m], bfr[n], acc[m][n], 0, 0, 0);
    }

#pragma unroll
    for (int m = 0; m < 4; ++m)
#pragma unroll
        for (int n = 0; n < 4; ++n)
#pragma unroll
            for (int r = 0; r < 4; ++r) {
                int row = bm + wr * 64 + m * 16 + lw * 4 + r;
                int col = bn + wc * 64 + n * 16 + lm;
                if (OUT_BF16)
                    ((ushort*)Cout)[(size_t)row * N + col] = f2bf(acc[m][n][r]);
                else
                    ((float*)Cout)[(size_t)row * N + col] = acc[m][n][r];
            }
}

// ---------------- RoPE in-place on bf16 (strided, fused-QKV aware) ----------------
__global__ void rope_bf16(ushort* __restrict__ X, int nheads, int colOff, int total) {
    int idx = blockIdx.x * blockDim.x + threadIdx.x;
    if (idx >= total) return;
    int i = idx & 63;
    int hh = (idx >> 6) % nheads;
    int row = idx / (64 * nheads);
    int s = row & (SS - 1);
    float inv = exp2f((float)i * -0.2076205059304601f);  // 10000^(-2i/128)
    float ang = (float)s * inv;
    float c, sn;
    __sincosf(ang, &sn, &c);
    size_t base = (size_t)row * QKVS + colOff + (size_t)hh * HDIM + i;
    float x1 = bf2f(X[base]), x2 = bf2f(X[base + 64]);
    X[base] = f2bf(x1 * c - x2 * sn);
    X[base + 64] = f2bf(x2 * c + x1 * sn);
}

// ---------------- MFMA flash attention v9 ----------------
// Swapped QK^T (S^T = mfma(K,Q)): lane lm owns q-row lm -> in-lane softmax,
// P feeds PV A-operand directly (V columns pre-permuted by tau in transpose_v).
// K,V both double-buffered; ONE barrier per tile (counted: stage(t+1) issued at
// tile top, vmcnt(0)+s_barrier at tile end). Flat 256-block grid decoded so
// each XCD owns one (b,g) -> K/V L2-resident per XCD.
#define SCL 0.08838834764831845f          // 1/sqrt(128)
#define CEXP 0.1275296340545927f          // SCL * log2(e)
#define THRRAW 90.50966799187809f         // 8 / SCL

__global__ __launch_bounds__(512) void attn_mfma(const ushort* __restrict__ QKV,
                                                 const ushort* __restrict__ VT,
                                                 ushort* __restrict__ Ctx) {
    __shared__ ushort Ks[2][64 * 128];  // 32 KB
    __shared__ ushort Vs[2][128 * 64];  // 32 KB
    const int t = threadIdx.x;          // 0..511
    const int w = t >> 6;               // wave 0..7
    const int l = t & 63;
    const int lm = l & 15, lw = l >> 4;
    // XCD decode: bid&7 = (g + 4b)  -> one (b,g) per XCD (assumes bid%8 -> XCD)
    const int bid = blockIdx.x;
    const int g = bid & 3;
    const int b = (bid >> 2) & 1;
    const int within = bid >> 3;
    const int xq = within & 7;
    const int h = g * 4 + (within >> 3);
    const int swz = (lm & 7) << 3;

    const ushort* kbase = QKV + (size_t)(b * SS) * QKVS + 2048 + g * HDIM;
    const ushort* vbase = VT + ((size_t)b * DKV + g * HDIM) * SS;

    const short one_bf = (short)0x3F80;
    const bf16x8 ones = {one_bf, one_bf, one_bf, one_bf, one_bf, one_bf, one_bf, one_bf};

    // staging chunk assignment (512 threads, 1024 16B-chunks per K/V tile)
    const int kr0 = t >> 4, ko0 = t & 15;
    const int kr1 = (t + 512) >> 4, ko1 = (t + 512) & 15;
    const int vr0 = t >> 3, vo0 = t & 7;
    const int vr1 = (t + 512) >> 3, vo1 = (t + 512) & 7;
    ushort* kd0a = &Ks[0][t * 8];
    ushort* kd0b = &Ks[1][t * 8];
    ushort* kd1a = &Ks[0][(t + 512) * 8];
    ushort* kd1b = &Ks[1][(t + 512) * 8];
    ushort* vd0a = &Vs[0][t * 8];
    ushort* vd0b = &Vs[1][t * 8];
    ushort* vd1a = &Vs[0][(t + 512) * 8];
    ushort* vd1b = &Vs[1][(t + 512) * 8];

#pragma unroll 1
    for (int phase = 0; phase < 2; ++phase) {
        const int qt = (phase == 0) ? xq : (15 - xq);
        const int q0 = qt * 128;
        const int qw = q0 + w * 16;
        const int q = qw + lm;                   // this lane's q-row
        const int ntiles = 2 * qt + 2;
        const int lt = (qw + 15) >> 6;           // last kv-tile this wave needs

        const ushort* ks0 = kbase + (size_t)kr0 * QKVS + ((ko0 ^ (kr0 & 7)) * 8);
        const ushort* ks1 = kbase + (size_t)kr1 * QKVS + ((ko1 ^ (kr1 & 7)) * 8);
        const ushort* vs0 = vbase + (size_t)vr0 * SS + ((vo0 ^ (vr0 & 7)) * 8);
        const ushort* vs1 = vbase + (size_t)vr1 * SS + ((vo1 ^ (vr1 & 7)) * 8);

        bf16x8 qa[4];
        {
            const ushort* qp = QKV + (size_t)(b * SS + qw + lm) * QKVS + h * HDIM + lw * 8;
#pragma unroll
            for (int kk = 0; kk < 4; ++kk)
                qa[kk] = *(const bf16x8*)(qp + kk * 32);
        }

        f32x4 acc[8];
#pragma unroll
        for (int d = 0; d < 8; ++d) acc[d] = (f32x4){0.f, 0.f, 0.f, 0.f};
        f32x4 accl = (f32x4){0.f, 0.f, 0.f, 0.f};
        float m = -INFINITY;                      // per-lane running max (q-row lm)

        // prologue: stage tile 0 into buffer 0
        GLOAD_LDS(ks0, kd0a);
        GLOAD_LDS(ks1, kd1a);
        ks0 += 64 * QKVS;
        ks1 += 64 * QKVS;
        GLOAD_LDS(vs0, vd0a);
        GLOAD_LDS(vs1, vd1a);
        vs0 += 64;
        vs1 += 64;
        asm volatile("s_waitcnt vmcnt(0)" ::: "memory");
        __builtin_amdgcn_s_barrier();

#pragma unroll 1
        for (int tile = 0; tile < ntiles; ++tile) {
            const int cur = tile & 1;
            const int kv0 = tile * 64;
            const bool more = (tile + 1 < ntiles);
            if (more) {  // issue next tile into other buffer (4 loads in flight)
                GLOAD_LDS(ks0, cur ? kd0a : kd0b);
                GLOAD_LDS(ks1, cur ? kd1a : kd1b);
                ks0 += 64 * QKVS;
                ks1 += 64 * QKVS;
                GLOAD_LDS(vs0, cur ? vd0a : vd0b);
                GLOAD_LDS(vs1, cur ? vd1a : vd1b);
                vs0 += 64;
                vs1 += 64;
            }

            if (tile <= lt) {
                // ---- S^T = mfma(K, Q): lane holds S[q=lm][kv=kv0+16kvb+4lw+r] ----
                f32x4 sfT[4];
#pragma unroll
                for (int kvb = 0; kvb < 4; ++kvb) sfT[kvb] = (f32x4){0.f, 0.f, 0.f, 0.f};
                __builtin_amdgcn_s_setprio(1);
#pragma unroll
                for (int kvb = 0; kvb < 4; ++kvb)
#pragma unroll
                    for (int kk = 0; kk < 4; ++kk) {
                        bf16x8 kb = *(const bf16x8*)&Ks[cur][(kvb * 16 + lm) * 128 + ((kk * 32 + lw * 8) ^ swz)];
                        sfT[kvb] = __builtin_amdgcn_mfma_f32_16x16x32_bf16(kb, qa[kk], sfT[kvb], 0, 0, 0);
                    }
                __builtin_amdgcn_s_setprio(0);

                // ---- mask (diagonal tile only) ----
                if (tile == lt) {
#pragma unroll
                    for (int kvb = 0; kvb < 4; ++kvb)
#pragma unroll
                        for (int r = 0; r < 4; ++r) {
                            int kv = kv0 + kvb * 16 + lw * 4 + r;
                            if (kv > q) sfT[kvb][r] = -INFINITY;
                        }
                }

                // ---- in-lane row max + cross-lw reduce (2 shfl) ----
                float rm = fmaxf(fmaxf(sfT[0][0], sfT[0][1]), fmaxf(sfT[0][2], sfT[0][3]));
#pragma unroll
                for (int kvb = 1; kvb < 4; ++kvb) {
                    rm = fmaxf(rm, fmaxf(fmaxf(sfT[kvb][0], sfT[kvb][1]),
                                         fmaxf(sfT[kvb][2], sfT[kvb][3])));
                }
                rm = fmaxf(rm, __shfl_xor(rm, 16));
                rm = fmaxf(rm, __shfl_xor(rm, 32));

                // ---- defer-max rescale ----
                bool stable = (rm - m <= THRRAW);
                if (!__all((int)stable)) {
                    float mn = fmaxf(m, rm);
                    float alpha_l = exp2f((m - mn) * CEXP);
                    m = mn;
                    float ar[4];
#pragma unroll
                    for (int r = 0; r < 4; ++r)
                        ar[r] = __shfl(alpha_l, (l & 48) | (lw * 4 + r));
#pragma unroll
                    for (int d = 0; d < 8; ++d) {
                        acc[d][0] *= ar[0];
                        acc[d][1] *= ar[1];
                        acc[d][2] *= ar[2];
                        acc[d][3] *= ar[3];
                    }
                    accl[0] *= ar[0];
                    accl[1] *= ar[1];
                    accl[2] *= ar[2];
                    accl[3] *= ar[3];
                }

                // ---- P = exp2((s-m)*CEXP), packed straight into A-fragments ----
                bf16x8 pa[2];
                float mC = m * CEXP;
#pragma unroll
                for (int kvb = 0; kvb < 4; ++kvb)
#pragma unroll
                    for (int r = 0; r < 4; ++r) {
                        float pv = exp2f(fmaf(sfT[kvb][r], CEXP, -mC));
                        pa[kvb >> 1][(kvb & 1) * 4 + r] = (short)f2bf(pv);
                    }

                // ---- PV + l via ones-MFMA (V columns tau-permuted: direct reads) ----
                __builtin_amdgcn_s_setprio(1);
#pragma unroll
                for (int kks = 0; kks < 2; ++kks) {
                    accl = __builtin_amdgcn_mfma_f32_16x16x32_bf16(pa[kks], ones, accl, 0, 0, 0);
#pragma unroll
                    for (int dcol = 0; dcol < 8; ++dcol) {
                        bf16x8 vb = *(const bf16x8*)&Vs[cur][(dcol * 16 + lm) * 64 + ((kks * 32 + lw * 8) ^ swz)];
                        acc[dcol] = __builtin_amdgcn_mfma_f32_16x16x32_bf16(pa[kks], vb, acc[dcol], 0, 0, 0);
                    }
                }
                __builtin_amdgcn_s_setprio(0);
            }

            if (more) {  // single barrier per tile; prefetch had full tile to land
                asm volatile("s_waitcnt vmcnt(0)" ::: "memory");
                __builtin_amdgcn_s_barrier();
            }
        }

        // ---- epilogue: O[q=qw+lw*4+r][d=dcol*16+lm] = acc/l ----
        float rinv[4];
#pragma unroll
        for (int r = 0; r < 4; ++r) rinv[r] = 1.f / accl[r];
        ushort* cp = Ctx + (size_t)(b * SS + qw) * DD + h * HDIM;
#pragma unroll
        for (int d = 0; d < 8; ++d)
#pragma unroll
            for (int r = 0; r < 4; ++r)
                cp[(size_t)(lw * 4 + r) * DD + d * 16 + lm] = f2bf(acc[d][r] * rinv[r]);
        __builtin_amdgcn_s_barrier();  // protect LDS before next phase's prologue
    }
}

extern "C" void kernel_launch(void* const* d_in, const int* in_sizes, int n_in,
                              void* d_out, int out_size, void* d_ws, size_t ws_size,
                              hipStream_t stream) {
    const float* x  = (const float*)d_in[0];
    const float* Wq = (const float*)d_in[1];
    const float* Wk = (const float*)d_in[2];
    const float* Wv = (const float*)d_in[3];
    const float* Wo = (const float*)d_in[4];
    float* out = (float*)d_out;

    // bf16 workspace (~67 MB)
    ushort* xh    = (ushort*)d_ws;                    // [MS, DD]
    ushort* QKV   = xh + (size_t)MS * DD;             // [MS, QKVS]
    ushort* VTb   = QKV + (size_t)MS * QKVS;          // [BB*DKV, SS]
    ushort* WqkvT = VTb + (size_t)MS * DKV;           // [QKVS, DD]
    ushort* WoT   = WqkvT + (size_t)QKVS * DD;        // [DD, DD]
    ushort* Ch    = xh;                               // ctx bf16 aliases xh

    dim3 blk(256);
    int nx8 = MS * DD / 8;
    cast_bf16<<<(nx8 + 255) / 256, 256, 0, stream>>>(x, xh, nx8);

    transpose_cast<<<dim3(DD / 32, DD / 32), blk, 0, stream>>>(Wq, WqkvT, DD, DD);
    transpose_cast<<<dim3(DKV / 32, DD / 32), blk, 0, stream>>>(Wk, WqkvT + (size_t)DD * DD, DD, DKV);
    transpose_cast<<<dim3(DKV / 32, DD / 32), blk, 0, stream>>>(Wv, WqkvT + (size_t)(DD + DKV) * DD, DD, DKV);

    gemm_bf16<true><<<dim3(QKVS / TBN, MS / TBM), blk, 0, stream>>>(xh, WqkvT, QKV, MS, QKVS, DD);

    int nq = MS * HH * 64;
    rope_bf16<<<(nq + 255) / 256, 256, 0, stream>>>(QKV, HH, 0, nq);
    int nk = MS * GG * 64;
    rope_bf16<<<(nk + 255) / 256, 256, 0, stream>>>(QKV, GG, 2048, nk);

    transpose_v<<<dim3(DKV / 32, SS / 32, BB), blk, 0, stream>>>(QKV, VTb);

    attn_mfma<<<dim3(256), dim3(512), 0, stream>>>(QKV, VTb, Ch);

    transpose_cast<<<dim3(DD / 32, DD / 32), blk, 0, stream>>>(Wo, WoT, DD, DD);
    gemm_bf16<false><<<dim3(DD / TBN, MS / TBM), blk, 0, stream>>>(Ch, WoT, out, MS, DD, DD);
}

// Round 10
// 216.623 us; speedup vs baseline: 27.7110x; 1.0684x over previous
//
#include <hip/hip_runtime.h>
#include <hip/hip_bf16.h>
#include <math.h>

// Problem constants
#define BB 2
#define SS 2048
#define DD 2048
#define HH 16
#define GG 4
#define HDIM 128
#define DKV (GG * HDIM)      // 512
#define MS (BB * SS)         // 4096 rows
#define QKVS 3072            // fused QKV row stride (2048 Q + 512 K + 512 V)

typedef __attribute__((ext_vector_type(8))) short bf16x8;
typedef __attribute__((ext_vector_type(4))) float f32x4;
typedef __attribute__((ext_vector_type(4))) unsigned int u32x4;

__device__ __forceinline__ ushort f2bf(float x) {
    __hip_bfloat16 b = __float2bfloat16(x);
    return *(ushort*)&b;
}
__device__ __forceinline__ float bf2f(ushort u) {
    __hip_bfloat16 b;
    *(ushort*)&b = u;
    return __bfloat162float(b);
}

#define GLOAD_LDS(src, dst)                                                        \
    __builtin_amdgcn_global_load_lds(                                              \
        (const __attribute__((address_space(1))) unsigned int*)(src),              \
        (__attribute__((address_space(3))) unsigned int*)(dst), 16, 0, 0)

#define WAITV(n) asm volatile("s_waitcnt vmcnt(" #n ")" ::: "memory")

// ---------------- fp32 -> bf16 cast, 8 elems/thread ----------------
__global__ void cast_bf16(const float* __restrict__ X, ushort* __restrict__ O, int total8) {
    int idx = blockIdx.x * blockDim.x + threadIdx.x;
    if (idx >= total8) return;
    const float4* p = (const float4*)X + (size_t)idx * 2;
    float4 a = p[0], b = p[1];
    float v[8] = {a.x, a.y, a.z, a.w, b.x, b.y, b.z, b.w};
    ushort r[8];
#pragma unroll
    for (int j = 0; j < 8; ++j) r[j] = f2bf(v[j]);
    *((u32x4*)O + idx) = *(u32x4*)r;
}

// ---------------- transpose + cast: WT[n*K + k] = bf16(W[k*N + n]) ----------------
__global__ __launch_bounds__(256) void transpose_cast(const float* __restrict__ W,
                                                      ushort* __restrict__ WT,
                                                      int K, int N) {
    __shared__ ushort tile[32][33];
    const int tx = threadIdx.x & 31, ty = threadIdx.x >> 5;  // 32 x 8
    const int n0 = blockIdx.x * 32, k0 = blockIdx.y * 32;
#pragma unroll
    for (int i = 0; i < 4; ++i)
        tile[ty + i * 8][tx] = f2bf(W[(size_t)(k0 + ty + i * 8) * N + n0 + tx]);
    __syncthreads();
#pragma unroll
    for (int i = 0; i < 4; ++i)
        WT[(size_t)(n0 + ty + i * 8) * K + k0 + tx] = tile[tx][ty + i * 8];
}

// ---- per-batch V transpose from fused QKV, with PV-slot column permutation ----
// VT'[b*DKV + dkv][tau(kv)] = QKV[b*SS+kv][2560+dkv]
// tau: kv = 32a+16m+4w+r  ->  pos = 32a+8w+4m+r
__global__ __launch_bounds__(256) void transpose_v(const ushort* __restrict__ QKV,
                                                   ushort* __restrict__ VT) {
    __shared__ ushort tile[32][33];
    const int tx = threadIdx.x & 31, ty = threadIdx.x >> 5;  // 32 x 8
    const int d0 = blockIdx.x * 32;  // dkv
    const int k0 = blockIdx.y * 32;  // kv (32-aligned)
    const int b = blockIdx.z;
#pragma unroll
    for (int i = 0; i < 4; ++i)
        tile[ty + i * 8][tx] =
            QKV[(size_t)(b * SS + k0 + ty + i * 8) * QKVS + 2560 + d0 + tx];
    __syncthreads();
    const int posl = ((tx & 12) << 1) | ((tx & 16) >> 2) | (tx & 3);
#pragma unroll
    for (int i = 0; i < 4; ++i)
        VT[((size_t)b * DKV + d0 + ty + i * 8) * SS + k0 + posl] = tile[tx][ty + i * 8];
}

// ---------------- bf16 MFMA GEMM v2: ring-4 K-tile pipeline (T2+T3+T4+T5) ------
// C[M,N] = A[M,K] x BT[N,K]^T.  BN=256 fixed, BM templated (256 or 128).
// BK=32; 4-deep LDS ring; stage(kt+2) issued at top of kt; counted vmcnt;
// ONE s_barrier per K-tile. XOR swizzle chunk^=(row>>1)&3 on both sides.
// 512 threads = 8 waves (2M x 4N). Per-wave output (BM/2) x 64.
template <int BM, bool OUT_BF16>
__global__ __launch_bounds__(512) void gemm8(const ushort* __restrict__ A,
                                             const ushort* __restrict__ BT,
                                             void* __restrict__ Cout,
                                             int M, int N, int K) {
    constexpr int ABUF = BM * 32;       // ushorts per A K-tile buffer
    constexpr int BBUF = 256 * 32;      // 8192
    constexpr int MFR = BM / 32;        // M fragments per wave (8 or 4)
    constexpr int NPH = MFR / 4;        // phases per K-tile (2 or 1)
    __shared__ ushort As[4 * ABUF];
    __shared__ ushort Bs[4 * BBUF];

    const int t = threadIdx.x;
    const int w = t >> 6, l = t & 63;
    const int lm = l & 15, lw = l >> 4;
    const int wr = w >> 2, wc = w & 3;
    // XCD swizzle (grid size % 8 == 0)
    const int nx = gridDim.x;
    const int bid = blockIdx.y * nx + blockIdx.x;
    const int cpx = (nx * gridDim.y) >> 3;
    const int swb = (bid & 7) * cpx + (bid >> 3);
    const int bm = (swb / nx) * BM, bn = (swb % nx) * 256;

    const int NT = K >> 5;  // K-tiles of 32
    const int swzc = (lw ^ ((lm >> 1) & 3)) * 8;  // swizzled read column (ushorts)

    // staging source pointers (inverse-swizzled chunk within each 64B row)
    const int ar0 = t >> 2, ac0 = ((t & 3) ^ ((ar0 >> 1) & 3));
    const ushort* a0 = A + (size_t)(bm + ar0) * K + ac0 * 8;
    const int ar1 = (t + 512) >> 2, ac1 = (((t + 512) & 3) ^ ((ar1 >> 1) & 3));
    const ushort* a1 = A + (size_t)(bm + ar1) * K + ac1 * 8;  // BM==256 only
    const int br0 = t >> 2, bc0 = ((t & 3) ^ ((br0 >> 1) & 3));
    const ushort* b0 = BT + (size_t)(bn + br0) * K + bc0 * 8;
    const int br1 = (t + 512) >> 2, bc1 = (((t + 512) & 3) ^ ((br1 >> 1) & 3));
    const ushort* b1 = BT + (size_t)(bn + br1) * K + bc1 * 8;

    auto STAGE = [&](int kt) {
        const int buf = kt & 3;
        GLOAD_LDS(a0, &As[buf * ABUF + t * 8]);
        a0 += 32;
        if constexpr (BM == 256) {
            GLOAD_LDS(a1, &As[buf * ABUF + (t + 512) * 8]);
            a1 += 32;
        }
        GLOAD_LDS(b0, &Bs[buf * BBUF + t * 8]);
        b0 += 32;
        GLOAD_LDS(b1, &Bs[buf * BBUF + (t + 512) * 8]);
        b1 += 32;
    };

    f32x4 acc[MFR][4];
#pragma unroll
    for (int m = 0; m < MFR; ++m)
#pragma unroll
        for (int n = 0; n < 4; ++n) acc[m][n] = (f32x4){0.f, 0.f, 0.f, 0.f};

    STAGE(0);
    STAGE(1);

#pragma unroll 1
    for (int kt = 0; kt < NT; ++kt) {
        if (kt + 2 < NT) {
            STAGE(kt + 2);
            if constexpr (BM == 256) WAITV(8); else WAITV(6);
        } else if (kt + 1 < NT) {
            if constexpr (BM == 256) WAITV(4); else WAITV(3);
        } else {
            WAITV(0);
        }
        __builtin_amdgcn_s_barrier();

        const ushort* Ab = &As[(kt & 3) * ABUF];
        const ushort* Bb = &Bs[(kt & 3) * BBUF];
        bf16x8 bfr[4];
#pragma unroll
        for (int n = 0; n < 4; ++n)
            bfr[n] = *(const bf16x8*)&Bb[(wc * 64 + n * 16 + lm) * 32 + swzc];
#pragma unroll
        for (int ph = 0; ph < NPH; ++ph) {
            bf16x8 af[4];
#pragma unroll
            for (int i = 0; i < 4; ++i)
                af[i] = *(const bf16x8*)&Ab[(wr * (BM / 2) + (ph * 4 + i) * 16 + lm) * 32 + swzc];
            __builtin_amdgcn_s_setprio(1);
#pragma unroll
            for (int i = 0; i < 4; ++i)
#pragma unroll
                for (int n = 0; n < 4; ++n)
                    acc[ph * 4 + i][n] =
                        __builtin_amdgcn_mfma_f32_16x16x32_bf16(af[i], bfr[n], acc[ph * 4 + i][n], 0, 0, 0);
            __builtin_amdgcn_s_setprio(0);
        }
    }

    // epilogue: C/D layout col=lm, row=lw*4+reg (verified)
#pragma unroll
    for (int m = 0; m < MFR; ++m)
#pragma unroll
        for (int n = 0; n < 4; ++n)
#pragma unroll
            for (int r = 0; r < 4; ++r) {
                int row = bm + wr * (BM / 2) + m * 16 + lw * 4 + r;
                int col = bn + wc * 64 + n * 16 + lm;
                if (OUT_BF16)
                    ((ushort*)Cout)[(size_t)row * N + col] = f2bf(acc[m][n][r]);
                else
                    ((float*)Cout)[(size_t)row * N + col] = acc[m][n][r];
            }
}

// ---------------- RoPE in-place on bf16 (strided, fused-QKV aware) ----------------
__global__ void rope_bf16(ushort* __restrict__ X, int nheads, int colOff, int total) {
    int idx = blockIdx.x * blockDim.x + threadIdx.x;
    if (idx >= total) return;
    int i = idx & 63;
    int hh = (idx >> 6) % nheads;
    int row = idx / (64 * nheads);
    int s = row & (SS - 1);
    float inv = exp2f((float)i * -0.2076205059304601f);  // 10000^(-2i/128)
    float ang = (float)s * inv;
    float c, sn;
    __sincosf(ang, &sn, &c);
    size_t base = (size_t)row * QKVS + colOff + (size_t)hh * HDIM + i;
    float x1 = bf2f(X[base]), x2 = bf2f(X[base + 64]);
    X[base] = f2bf(x1 * c - x2 * sn);
    X[base + 64] = f2bf(x2 * c + x1 * sn);
}

// ---------------- MFMA flash attention v9 (round-9 verified) ----------------
#define SCL 0.08838834764831845f          // 1/sqrt(128)
#define CEXP 0.1275296340545927f          // SCL * log2(e)
#define THRRAW 90.50966799187809f         // 8 / SCL

__global__ __launch_bounds__(512) void attn_mfma(const ushort* __restrict__ QKV,
                                                 const ushort* __restrict__ VT,
                                                 ushort* __restrict__ Ctx) {
    __shared__ ushort Ks[2][64 * 128];  // 32 KB
    __shared__ ushort Vs[2][128 * 64];  // 32 KB
    const int t = threadIdx.x;          // 0..511
    const int w = t >> 6;               // wave 0..7
    const int l = t & 63;
    const int lm = l & 15, lw = l >> 4;
    const int bid = blockIdx.x;
    const int g = bid & 3;
    const int b = (bid >> 2) & 1;
    const int within = bid >> 3;
    const int xq = within & 7;
    const int h = g * 4 + (within >> 3);
    const int swz = (lm & 7) << 3;

    const ushort* kbase = QKV + (size_t)(b * SS) * QKVS + 2048 + g * HDIM;
    const ushort* vbase = VT + ((size_t)b * DKV + g * HDIM) * SS;

    const short one_bf = (short)0x3F80;
    const bf16x8 ones = {one_bf, one_bf, one_bf, one_bf, one_bf, one_bf, one_bf, one_bf};

    const int kr0 = t >> 4, ko0 = t & 15;
    const int kr1 = (t + 512) >> 4, ko1 = (t + 512) & 15;
    const int vr0 = t >> 3, vo0 = t & 7;
    const int vr1 = (t + 512) >> 3, vo1 = (t + 512) & 7;
    ushort* kd0a = &Ks[0][t * 8];
    ushort* kd0b = &Ks[1][t * 8];
    ushort* kd1a = &Ks[0][(t + 512) * 8];
    ushort* kd1b = &Ks[1][(t + 512) * 8];
    ushort* vd0a = &Vs[0][t * 8];
    ushort* vd0b = &Vs[1][t * 8];
    ushort* vd1a = &Vs[0][(t + 512) * 8];
    ushort* vd1b = &Vs[1][(t + 512) * 8];

#pragma unroll 1
    for (int phase = 0; phase < 2; ++phase) {
        const int qt = (phase == 0) ? xq : (15 - xq);
        const int q0 = qt * 128;
        const int qw = q0 + w * 16;
        const int q = qw + lm;
        const int ntiles = 2 * qt + 2;
        const int lt = (qw + 15) >> 6;

        const ushort* ks0 = kbase + (size_t)kr0 * QKVS + ((ko0 ^ (kr0 & 7)) * 8);
        const ushort* ks1 = kbase + (size_t)kr1 * QKVS + ((ko1 ^ (kr1 & 7)) * 8);
        const ushort* vs0 = vbase + (size_t)vr0 * SS + ((vo0 ^ (vr0 & 7)) * 8);
        const ushort* vs1 = vbase + (size_t)vr1 * SS + ((vo1 ^ (vr1 & 7)) * 8);

        bf16x8 qa[4];
        {
            const ushort* qp = QKV + (size_t)(b * SS + qw + lm) * QKVS + h * HDIM + lw * 8;
#pragma unroll
            for (int kk = 0; kk < 4; ++kk)
                qa[kk] = *(const bf16x8*)(qp + kk * 32);
        }

        f32x4 acc[8];
#pragma unroll
        for (int d = 0; d < 8; ++d) acc[d] = (f32x4){0.f, 0.f, 0.f, 0.f};
        f32x4 accl = (f32x4){0.f, 0.f, 0.f, 0.f};
        float m = -INFINITY;

        GLOAD_LDS(ks0, kd0a);
        GLOAD_LDS(ks1, kd1a);
        ks0 += 64 * QKVS;
        ks1 += 64 * QKVS;
        GLOAD_LDS(vs0, vd0a);
        GLOAD_LDS(vs1, vd1a);
        vs0 += 64;
        vs1 += 64;
        asm volatile("s_waitcnt vmcnt(0)" ::: "memory");
        __builtin_amdgcn_s_barrier();

#pragma unroll 1
        for (int tile = 0; tile < ntiles; ++tile) {
            const int cur = tile & 1;
            const int kv0 = tile * 64;
            const bool more = (tile + 1 < ntiles);
            if (more) {
                GLOAD_LDS(ks0, cur ? kd0a : kd0b);
                GLOAD_LDS(ks1, cur ? kd1a : kd1b);
                ks0 += 64 * QKVS;
                ks1 += 64 * QKVS;
                GLOAD_LDS(vs0, cur ? vd0a : vd0b);
                GLOAD_LDS(vs1, cur ? vd1a : vd1b);
                vs0 += 64;
                vs1 += 64;
            }

            if (tile <= lt) {
                f32x4 sfT[4];
#pragma unroll
                for (int kvb = 0; kvb < 4; ++kvb) sfT[kvb] = (f32x4){0.f, 0.f, 0.f, 0.f};
                __builtin_amdgcn_s_setprio(1);
#pragma unroll
                for (int kvb = 0; kvb < 4; ++kvb)
#pragma unroll
                    for (int kk = 0; kk < 4; ++kk) {
                        bf16x8 kb = *(const bf16x8*)&Ks[cur][(kvb * 16 + lm) * 128 + ((kk * 32 + lw * 8) ^ swz)];
                        sfT[kvb] = __builtin_amdgcn_mfma_f32_16x16x32_bf16(kb, qa[kk], sfT[kvb], 0, 0, 0);
                    }
                __builtin_amdgcn_s_setprio(0);

                if (tile == lt) {
#pragma unroll
                    for (int kvb = 0; kvb < 4; ++kvb)
#pragma unroll
                        for (int r = 0; r < 4; ++r) {
                            int kv = kv0 + kvb * 16 + lw * 4 + r;
                            if (kv > q) sfT[kvb][r] = -INFINITY;
                        }
                }

                float rm = fmaxf(fmaxf(sfT[0][0], sfT[0][1]), fmaxf(sfT[0][2], sfT[0][3]));
#pragma unroll
                for (int kvb = 1; kvb < 4; ++kvb) {
                    rm = fmaxf(rm, fmaxf(fmaxf(sfT[kvb][0], sfT[kvb][1]),
                                         fmaxf(sfT[kvb][2], sfT[kvb][3])));
                }
                rm = fmaxf(rm, __shfl_xor(rm, 16));
                rm = fmaxf(rm, __shfl_xor(rm, 32));

                bool stable = (rm - m <= THRRAW);
                if (!__all((int)stable)) {
                    float mn = fmaxf(m, rm);
                    float alpha_l = exp2f((m - mn) * CEXP);
                    m = mn;
                    float ar[4];
#pragma unroll
                    for (int r = 0; r < 4; ++r)
                        ar[r] = __shfl(alpha_l, (l & 48) | (lw * 4 + r));
#pragma unroll
                    for (int d = 0; d < 8; ++d) {
                        acc[d][0] *= ar[0];
                        acc[d][1] *= ar[1];
                        acc[d][2] *= ar[2];
                        acc[d][3] *= ar[3];
                    }
                    accl[0] *= ar[0];
                    accl[1] *= ar[1];
                    accl[2] *= ar[2];
                    accl[3] *= ar[3];
                }

                bf16x8 pa[2];
                float mC = m * CEXP;
#pragma unroll
                for (int kvb = 0; kvb < 4; ++kvb)
#pragma unroll
                    for (int r = 0; r < 4; ++r) {
                        float pv = exp2f(fmaf(sfT[kvb][r], CEXP, -mC));
                        pa[kvb >> 1][(kvb & 1) * 4 + r] = (short)f2bf(pv);
                    }

                __builtin_amdgcn_s_setprio(1);
#pragma unroll
                for (int kks = 0; kks < 2; ++kks) {
                    accl = __builtin_amdgcn_mfma_f32_16x16x32_bf16(pa[kks], ones, accl, 0, 0, 0);
#pragma unroll
                    for (int dcol = 0; dcol < 8; ++dcol) {
                        bf16x8 vb = *(const bf16x8*)&Vs[cur][(dcol * 16 + lm) * 64 + ((kks * 32 + lw * 8) ^ swz)];
                        acc[dcol] = __builtin_amdgcn_mfma_f32_16x16x32_bf16(pa[kks], vb, acc[dcol], 0, 0, 0);
                    }
                }
                __builtin_amdgcn_s_setprio(0);
            }

            if (more) {
                asm volatile("s_waitcnt vmcnt(0)" ::: "memory");
                __builtin_amdgcn_s_barrier();
            }
        }

        float rinv[4];
#pragma unroll
        for (int r = 0; r < 4; ++r) rinv[r] = 1.f / accl[r];
        ushort* cp = Ctx + (size_t)(b * SS + qw) * DD + h * HDIM;
#pragma unroll
        for (int d = 0; d < 8; ++d)
#pragma unroll
            for (int r = 0; r < 4; ++r)
                cp[(size_t)(lw * 4 + r) * DD + d * 16 + lm] = f2bf(acc[d][r] * rinv[r]);
        __builtin_amdgcn_s_barrier();
    }
}

extern "C" void kernel_launch(void* const* d_in, const int* in_sizes, int n_in,
                              void* d_out, int out_size, void* d_ws, size_t ws_size,
                              hipStream_t stream) {
    const float* x  = (const float*)d_in[0];
    const float* Wq = (const float*)d_in[1];
    const float* Wk = (const float*)d_in[2];
    const float* Wv = (const float*)d_in[3];
    const float* Wo = (const float*)d_in[4];
    float* out = (float*)d_out;

    // bf16 workspace (~67 MB)
    ushort* xh    = (ushort*)d_ws;                    // [MS, DD]
    ushort* QKV   = xh + (size_t)MS * DD;             // [MS, QKVS]
    ushort* VTb   = QKV + (size_t)MS * QKVS;          // [BB*DKV, SS]
    ushort* WqkvT = VTb + (size_t)MS * DKV;           // [QKVS, DD]
    ushort* WoT   = WqkvT + (size_t)QKVS * DD;        // [DD, DD]
    ushort* Ch    = xh;                               // ctx bf16 aliases xh

    dim3 blk(256);
    int nx8 = MS * DD / 8;
    cast_bf16<<<(nx8 + 255) / 256, 256, 0, stream>>>(x, xh, nx8);

    transpose_cast<<<dim3(DD / 32, DD / 32), blk, 0, stream>>>(Wq, WqkvT, DD, DD);
    transpose_cast<<<dim3(DKV / 32, DD / 32), blk, 0, stream>>>(Wk, WqkvT + (size_t)DD * DD, DD, DKV);
    transpose_cast<<<dim3(DKV / 32, DD / 32), blk, 0, stream>>>(Wv, WqkvT + (size_t)(DD + DKV) * DD, DD, DKV);

    // fused QKV GEMM: M=4096, N=3072 -> 16 x 12 = 192 blocks (BM=256)
    gemm8<256, true><<<dim3(QKVS / 256, MS / 256), dim3(512), 0, stream>>>(xh, WqkvT, QKV, MS, QKVS, DD);

    int nq = MS * HH * 64;
    rope_bf16<<<(nq + 255) / 256, 256, 0, stream>>>(QKV, HH, 0, nq);
    int nk = MS * GG * 64;
    rope_bf16<<<(nk + 255) / 256, 256, 0, stream>>>(QKV, GG, 2048, nk);

    transpose_v<<<dim3(DKV / 32, SS / 32, BB), blk, 0, stream>>>(QKV, VTb);

    attn_mfma<<<dim3(256), dim3(512), 0, stream>>>(QKV, VTb, Ch);

    transpose_cast<<<dim3(DD / 32, DD / 32), blk, 0, stream>>>(Wo, WoT, DD, DD);
    // Wo GEMM: M=4096, N=2048 -> BM=128: 32 x 8 = 256 blocks (1/CU exactly)
    gemm8<128, false><<<dim3(DD / 256, MS / 128), dim3(512), 0, stream>>>(Ch, WoT, out, MS, DD, DD);
}

// Round 11
// 210.384 us; speedup vs baseline: 28.5328x; 1.0297x over previous
//
#include <hip/hip_runtime.h>
#include <hip/hip_bf16.h>
#include <math.h>

// Problem constants
#define BB 2
#define SS 2048
#define DD 2048
#define HH 16
#define GG 4
#define HDIM 128
#define DKV (GG * HDIM)      // 512
#define MS (BB * SS)         // 4096 rows
#define QKVS 3072            // fused QKV row stride (2048 Q + 512 K + 512 V)

typedef __attribute__((ext_vector_type(8))) short bf16x8;
typedef __attribute__((ext_vector_type(4))) float f32x4;
typedef __attribute__((ext_vector_type(4))) unsigned int u32x4;

__device__ __forceinline__ ushort f2bf(float x) {
    __hip_bfloat16 b = __float2bfloat16(x);
    return *(ushort*)&b;
}
__device__ __forceinline__ float bf2f(ushort u) {
    __hip_bfloat16 b;
    *(ushort*)&b = u;
    return __bfloat162float(b);
}

#define GLOAD_LDS(src, dst)                                                        \
    __builtin_amdgcn_global_load_lds(                                              \
        (const __attribute__((address_space(1))) unsigned int*)(src),              \
        (__attribute__((address_space(3))) unsigned int*)(dst), 16, 0, 0)

#define WAITV(n) asm volatile("s_waitcnt vmcnt(" #n ")" ::: "memory")

// ---------------- fp32 -> bf16 cast, 8 elems/thread ----------------
__global__ void cast_bf16(const float* __restrict__ X, ushort* __restrict__ O, int total8) {
    int idx = blockIdx.x * blockDim.x + threadIdx.x;
    if (idx >= total8) return;
    const float4* p = (const float4*)X + (size_t)idx * 2;
    float4 a = p[0], b = p[1];
    float v[8] = {a.x, a.y, a.z, a.w, b.x, b.y, b.z, b.w};
    ushort r[8];
#pragma unroll
    for (int j = 0; j < 8; ++j) r[j] = f2bf(v[j]);
    *((u32x4*)O + idx) = *(u32x4*)r;
}

// ---------------- transpose + cast: WT[n*K + k] = bf16(W[k*N + n]) ----------------
__global__ __launch_bounds__(256) void transpose_cast(const float* __restrict__ W,
                                                      ushort* __restrict__ WT,
                                                      int K, int N) {
    __shared__ ushort tile[32][33];
    const int tx = threadIdx.x & 31, ty = threadIdx.x >> 5;  // 32 x 8
    const int n0 = blockIdx.x * 32, k0 = blockIdx.y * 32;
#pragma unroll
    for (int i = 0; i < 4; ++i)
        tile[ty + i * 8][tx] = f2bf(W[(size_t)(k0 + ty + i * 8) * N + n0 + tx]);
    __syncthreads();
#pragma unroll
    for (int i = 0; i < 4; ++i)
        WT[(size_t)(n0 + ty + i * 8) * K + k0 + tx] = tile[tx][ty + i * 8];
}

// ---- per-batch V transpose from fused QKV, with PV-slot column permutation ----
// VT'[b*DKV + dkv][tau(kv)] = QKV[b*SS+kv][2560+dkv]
// tau: kv = 32a+16m+4w+r  ->  pos = 32a+8w+4m+r
__global__ __launch_bounds__(256) void transpose_v(const ushort* __restrict__ QKV,
                                                   ushort* __restrict__ VT) {
    __shared__ ushort tile[32][33];
    const int tx = threadIdx.x & 31, ty = threadIdx.x >> 5;  // 32 x 8
    const int d0 = blockIdx.x * 32;  // dkv
    const int k0 = blockIdx.y * 32;  // kv (32-aligned)
    const int b = blockIdx.z;
#pragma unroll
    for (int i = 0; i < 4; ++i)
        tile[ty + i * 8][tx] =
            QKV[(size_t)(b * SS + k0 + ty + i * 8) * QKVS + 2560 + d0 + tx];
    __syncthreads();
    const int posl = ((tx & 12) << 1) | ((tx & 16) >> 2) | (tx & 3);
#pragma unroll
    for (int i = 0; i < 4; ++i)
        VT[((size_t)b * DKV + d0 + ty + i * 8) * SS + k0 + posl] = tile[tx][ty + i * 8];
}

// ---------------- bf16 MFMA GEMM v3: BM=128, ring-3, 2 blocks/CU ---------------
// C[M,N] = A[M,K] x BT[N,K]^T.  BN templated (256 or 128).  512 threads.
// Ring-3 LDS: STAGE(kt+2) issued AFTER the tile barrier (its slot was last read
// at kt-1, all waves past barrier(kt)); counted WAITV (never 0 mid-loop).
template <int BN, bool OUT_BF16>
__global__ __launch_bounds__(512) void gemm8(const ushort* __restrict__ A,
                                             const ushort* __restrict__ BT,
                                             void* __restrict__ Cout,
                                             int M, int N, int K) {
    constexpr int ABUF = 128 * 32;        // ushorts per A K-tile
    constexpr int BBUF = BN * 32;         // ushorts per B K-tile
    constexpr int NWC = BN / 64;          // N-waves (4 or 2)
    constexpr int NWM = 8 / NWC;          // M-waves (2 or 4)
    constexpr int ROWS = 128 / NWM;       // rows per wave (64 or 32)
    constexpr int MFR = ROWS / 16;        // A fragments per wave (4 or 2)
    __shared__ ushort As[3 * ABUF];
    __shared__ ushort Bs[3 * BBUF];

    const int t = threadIdx.x;
    const int w = t >> 6, l = t & 63;
    const int lm = l & 15, lw = l >> 4;
    const int wr = w / NWC, wc = w % NWC;
    // XCD swizzle (grid size % 8 == 0)
    const int nx = gridDim.x;
    const int bid = blockIdx.y * nx + blockIdx.x;
    const int cpx = (nx * gridDim.y) >> 3;
    const int swb = (bid & 7) * cpx + (bid >> 3);
    const int bm = (swb / nx) * 128, bn = (swb % nx) * BN;

    const int NT = K >> 5;
    const int swzc = (lw ^ ((lm >> 1) & 3)) * 8;  // swizzled read column (ushorts)

    // staging sources (inverse-swizzled chunk within each 64B row)
    const int ar0 = t >> 2, ac0 = (t & 3) ^ ((ar0 >> 1) & 3);
    const ushort* a0 = A + (size_t)(bm + ar0) * K + ac0 * 8;
    const int br0 = t >> 2, bc0 = (t & 3) ^ ((br0 >> 1) & 3);
    const ushort* b0 = BT + (size_t)(bn + br0) * K + bc0 * 8;
    const int br1 = (t + 512) >> 2, bc1 = ((t + 512) & 3) ^ ((br1 >> 1) & 3);
    const ushort* b1 = BT + (size_t)(bn + br1) * K + bc1 * 8;  // BN==256 only

    auto STAGE = [&](int slot) {
        GLOAD_LDS(a0, &As[slot * ABUF + t * 8]);
        a0 += 32;
        GLOAD_LDS(b0, &Bs[slot * BBUF + t * 8]);
        b0 += 32;
        if constexpr (BN == 256) {
            GLOAD_LDS(b1, &Bs[slot * BBUF + (t + 512) * 8]);
            b1 += 32;
        }
    };

    f32x4 acc[MFR][4];
#pragma unroll
    for (int m = 0; m < MFR; ++m)
#pragma unroll
        for (int n = 0; n < 4; ++n) acc[m][n] = (f32x4){0.f, 0.f, 0.f, 0.f};

    STAGE(0);
    STAGE(1);
    int cs = 0, ps = 2;  // compute slot (kt%3), prefetch slot ((kt+2)%3)

#pragma unroll 1
    for (int kt = 0; kt < NT; ++kt) {
        if (kt + 1 < NT) {
            if constexpr (BN == 256) WAITV(3); else WAITV(2);
        } else {
            WAITV(0);
        }
        __builtin_amdgcn_s_barrier();
        if (kt + 2 < NT) STAGE(ps);

        const ushort* Ab = &As[cs * ABUF];
        const ushort* Bb = &Bs[cs * BBUF];
        bf16x8 bfr[4], af[MFR];
#pragma unroll
        for (int n = 0; n < 4; ++n)
            bfr[n] = *(const bf16x8*)&Bb[(wc * 64 + n * 16 + lm) * 32 + swzc];
#pragma unroll
        for (int i = 0; i < MFR; ++i)
            af[i] = *(const bf16x8*)&Ab[(wr * ROWS + i * 16 + lm) * 32 + swzc];
        __builtin_amdgcn_s_setprio(1);
#pragma unroll
        for (int i = 0; i < MFR; ++i)
#pragma unroll
            for (int n = 0; n < 4; ++n)
                acc[i][n] = __builtin_amdgcn_mfma_f32_16x16x32_bf16(af[i], bfr[n], acc[i][n], 0, 0, 0);
        __builtin_amdgcn_s_setprio(0);

        cs = (cs == 2) ? 0 : cs + 1;
        ps = (ps == 2) ? 0 : ps + 1;
    }

    // epilogue: C/D layout col=lm, row=lw*4+reg (verified)
#pragma unroll
    for (int m = 0; m < MFR; ++m)
#pragma unroll
        for (int n = 0; n < 4; ++n)
#pragma unroll
            for (int r = 0; r < 4; ++r) {
                int row = bm + wr * ROWS + m * 16 + lw * 4 + r;
                int col = bn + wc * 64 + n * 16 + lm;
                if (OUT_BF16)
                    ((ushort*)Cout)[(size_t)row * N + col] = f2bf(acc[m][n][r]);
                else
                    ((float*)Cout)[(size_t)row * N + col] = acc[m][n][r];
            }
}

// ------- RoPE in-place on bf16, fused Q+K in one launch (heads 0..19) -------
// hh 0..15 -> Q at col hh*128; hh 16..19 -> K at col 2048+(hh-16)*128.
__global__ void rope_bf16(ushort* __restrict__ X, int total) {
    int idx = blockIdx.x * blockDim.x + threadIdx.x;
    if (idx >= total) return;
    int i = idx & 63;
    int hh = (idx >> 6) % 20;
    int row = idx / (64 * 20);
    int s = row & (SS - 1);
    int colOff = (hh < 16) ? hh * HDIM : 2048 + (hh - 16) * HDIM;
    float inv = exp2f((float)i * -0.2076205059304601f);  // 10000^(-2i/128)
    float ang = (float)s * inv;
    float c, sn;
    __sincosf(ang, &sn, &c);
    size_t base = (size_t)row * QKVS + colOff + i;
    float x1 = bf2f(X[base]), x2 = bf2f(X[base + 64]);
    X[base] = f2bf(x1 * c - x2 * sn);
    X[base + 64] = f2bf(x2 * c + x1 * sn);
}

// ---------------- MFMA flash attention v9 (round-9 verified) ----------------
#define SCL 0.08838834764831845f          // 1/sqrt(128)
#define CEXP 0.1275296340545927f          // SCL * log2(e)
#define THRRAW 90.50966799187809f         // 8 / SCL

__global__ __launch_bounds__(512) void attn_mfma(const ushort* __restrict__ QKV,
                                                 const ushort* __restrict__ VT,
                                                 ushort* __restrict__ Ctx) {
    __shared__ ushort Ks[2][64 * 128];  // 32 KB
    __shared__ ushort Vs[2][128 * 64];  // 32 KB
    const int t = threadIdx.x;          // 0..511
    const int w = t >> 6;               // wave 0..7
    const int l = t & 63;
    const int lm = l & 15, lw = l >> 4;
    const int bid = blockIdx.x;
    const int g = bid & 3;
    const int b = (bid >> 2) & 1;
    const int within = bid >> 3;
    const int xq = within & 7;
    const int h = g * 4 + (within >> 3);
    const int swz = (lm & 7) << 3;

    const ushort* kbase = QKV + (size_t)(b * SS) * QKVS + 2048 + g * HDIM;
    const ushort* vbase = VT + ((size_t)b * DKV + g * HDIM) * SS;

    const short one_bf = (short)0x3F80;
    const bf16x8 ones = {one_bf, one_bf, one_bf, one_bf, one_bf, one_bf, one_bf, one_bf};

    const int kr0 = t >> 4, ko0 = t & 15;
    const int kr1 = (t + 512) >> 4, ko1 = (t + 512) & 15;
    const int vr0 = t >> 3, vo0 = t & 7;
    const int vr1 = (t + 512) >> 3, vo1 = (t + 512) & 7;
    ushort* kd0a = &Ks[0][t * 8];
    ushort* kd0b = &Ks[1][t * 8];
    ushort* kd1a = &Ks[0][(t + 512) * 8];
    ushort* kd1b = &Ks[1][(t + 512) * 8];
    ushort* vd0a = &Vs[0][t * 8];
    ushort* vd0b = &Vs[1][t * 8];
    ushort* vd1a = &Vs[0][(t + 512) * 8];
    ushort* vd1b = &Vs[1][(t + 512) * 8];

#pragma unroll 1
    for (int phase = 0; phase < 2; ++phase) {
        const int qt = (phase == 0) ? xq : (15 - xq);
        const int q0 = qt * 128;
        const int qw = q0 + w * 16;
        const int q = qw + lm;
        const int ntiles = 2 * qt + 2;
        const int lt = (qw + 15) >> 6;

        const ushort* ks0 = kbase + (size_t)kr0 * QKVS + ((ko0 ^ (kr0 & 7)) * 8);
        const ushort* ks1 = kbase + (size_t)kr1 * QKVS + ((ko1 ^ (kr1 & 7)) * 8);
        const ushort* vs0 = vbase + (size_t)vr0 * SS + ((vo0 ^ (vr0 & 7)) * 8);
        const ushort* vs1 = vbase + (size_t)vr1 * SS + ((vo1 ^ (vr1 & 7)) * 8);

        bf16x8 qa[4];
        {
            const ushort* qp = QKV + (size_t)(b * SS + qw + lm) * QKVS + h * HDIM + lw * 8;
#pragma unroll
            for (int kk = 0; kk < 4; ++kk)
                qa[kk] = *(const bf16x8*)(qp + kk * 32);
        }

        f32x4 acc[8];
#pragma unroll
        for (int d = 0; d < 8; ++d) acc[d] = (f32x4){0.f, 0.f, 0.f, 0.f};
        f32x4 accl = (f32x4){0.f, 0.f, 0.f, 0.f};
        float m = -INFINITY;

        GLOAD_LDS(ks0, kd0a);
        GLOAD_LDS(ks1, kd1a);
        ks0 += 64 * QKVS;
        ks1 += 64 * QKVS;
        GLOAD_LDS(vs0, vd0a);
        GLOAD_LDS(vs1, vd1a);
        vs0 += 64;
        vs1 += 64;
        asm volatile("s_waitcnt vmcnt(0)" ::: "memory");
        __builtin_amdgcn_s_barrier();

#pragma unroll 1
        for (int tile = 0; tile < ntiles; ++tile) {
            const int cur = tile & 1;
            const int kv0 = tile * 64;
            const bool more = (tile + 1 < ntiles);
            if (more) {
                GLOAD_LDS(ks0, cur ? kd0a : kd0b);
                GLOAD_LDS(ks1, cur ? kd1a : kd1b);
                ks0 += 64 * QKVS;
                ks1 += 64 * QKVS;
                GLOAD_LDS(vs0, cur ? vd0a : vd0b);
                GLOAD_LDS(vs1, cur ? vd1a : vd1b);
                vs0 += 64;
                vs1 += 64;
            }

            if (tile <= lt) {
                f32x4 sfT[4];
#pragma unroll
                for (int kvb = 0; kvb < 4; ++kvb) sfT[kvb] = (f32x4){0.f, 0.f, 0.f, 0.f};
                __builtin_amdgcn_s_setprio(1);
#pragma unroll
                for (int kvb = 0; kvb < 4; ++kvb)
#pragma unroll
                    for (int kk = 0; kk < 4; ++kk) {
                        bf16x8 kb = *(const bf16x8*)&Ks[cur][(kvb * 16 + lm) * 128 + ((kk * 32 + lw * 8) ^ swz)];
                        sfT[kvb] = __builtin_amdgcn_mfma_f32_16x16x32_bf16(kb, qa[kk], sfT[kvb], 0, 0, 0);
                    }
                __builtin_amdgcn_s_setprio(0);

                if (tile == lt) {
#pragma unroll
                    for (int kvb = 0; kvb < 4; ++kvb)
#pragma unroll
                        for (int r = 0; r < 4; ++r) {
                            int kv = kv0 + kvb * 16 + lw * 4 + r;
                            if (kv > q) sfT[kvb][r] = -INFINITY;
                        }
                }

                float rm = fmaxf(fmaxf(sfT[0][0], sfT[0][1]), fmaxf(sfT[0][2], sfT[0][3]));
#pragma unroll
                for (int kvb = 1; kvb < 4; ++kvb) {
                    rm = fmaxf(rm, fmaxf(fmaxf(sfT[kvb][0], sfT[kvb][1]),
                                         fmaxf(sfT[kvb][2], sfT[kvb][3])));
                }
                rm = fmaxf(rm, __shfl_xor(rm, 16));
                rm = fmaxf(rm, __shfl_xor(rm, 32));

                bool stable = (rm - m <= THRRAW);
                if (!__all((int)stable)) {
                    float mn = fmaxf(m, rm);
                    float alpha_l = exp2f((m - mn) * CEXP);
                    m = mn;
                    float ar[4];
#pragma unroll
                    for (int r = 0; r < 4; ++r)
                        ar[r] = __shfl(alpha_l, (l & 48) | (lw * 4 + r));
#pragma unroll
                    for (int d = 0; d < 8; ++d) {
                        acc[d][0] *= ar[0];
                        acc[d][1] *= ar[1];
                        acc[d][2] *= ar[2];
                        acc[d][3] *= ar[3];
                    }
                    accl[0] *= ar[0];
                    accl[1] *= ar[1];
                    accl[2] *= ar[2];
                    accl[3] *= ar[3];
                }

                bf16x8 pa[2];
                float mC = m * CEXP;
#pragma unroll
                for (int kvb = 0; kvb < 4; ++kvb)
#pragma unroll
                    for (int r = 0; r < 4; ++r) {
                        float pv = exp2f(fmaf(sfT[kvb][r], CEXP, -mC));
                        pa[kvb >> 1][(kvb & 1) * 4 + r] = (short)f2bf(pv);
                    }

                __builtin_amdgcn_s_setprio(1);
#pragma unroll
                for (int kks = 0; kks < 2; ++kks) {
                    accl = __builtin_amdgcn_mfma_f32_16x16x32_bf16(pa[kks], ones, accl, 0, 0, 0);
#pragma unroll
                    for (int dcol = 0; dcol < 8; ++dcol) {
                        bf16x8 vb = *(const bf16x8*)&Vs[cur][(dcol * 16 + lm) * 64 + ((kks * 32 + lw * 8) ^ swz)];
                        acc[dcol] = __builtin_amdgcn_mfma_f32_16x16x32_bf16(pa[kks], vb, acc[dcol], 0, 0, 0);
                    }
                }
                __builtin_amdgcn_s_setprio(0);
            }

            if (more) {
                asm volatile("s_waitcnt vmcnt(0)" ::: "memory");
                __builtin_amdgcn_s_barrier();
            }
        }

        float rinv[4];
#pragma unroll
        for (int r = 0; r < 4; ++r) rinv[r] = 1.f / accl[r];
        ushort* cp = Ctx + (size_t)(b * SS + qw) * DD + h * HDIM;
#pragma unroll
        for (int d = 0; d < 8; ++d)
#pragma unroll
            for (int r = 0; r < 4; ++r)
                cp[(size_t)(lw * 4 + r) * DD + d * 16 + lm] = f2bf(acc[d][r] * rinv[r]);
        __builtin_amdgcn_s_barrier();
    }
}

extern "C" void kernel_launch(void* const* d_in, const int* in_sizes, int n_in,
                              void* d_out, int out_size, void* d_ws, size_t ws_size,
                              hipStream_t stream) {
    const float* x  = (const float*)d_in[0];
    const float* Wq = (const float*)d_in[1];
    const float* Wk = (const float*)d_in[2];
    const float* Wv = (const float*)d_in[3];
    const float* Wo = (const float*)d_in[4];
    float* out = (float*)d_out;

    // bf16 workspace (~67 MB)
    ushort* xh    = (ushort*)d_ws;                    // [MS, DD]
    ushort* QKV   = xh + (size_t)MS * DD;             // [MS, QKVS]
    ushort* VTb   = QKV + (size_t)MS * QKVS;          // [BB*DKV, SS]
    ushort* WqkvT = VTb + (size_t)MS * DKV;           // [QKVS, DD]
    ushort* WoT   = WqkvT + (size_t)QKVS * DD;        // [DD, DD]
    ushort* Ch    = xh;                               // ctx bf16 aliases xh

    dim3 blk(256);
    int nx8 = MS * DD / 8;
    cast_bf16<<<(nx8 + 255) / 256, 256, 0, stream>>>(x, xh, nx8);

    transpose_cast<<<dim3(DD / 32, DD / 32), blk, 0, stream>>>(Wq, WqkvT, DD, DD);
    transpose_cast<<<dim3(DKV / 32, DD / 32), blk, 0, stream>>>(Wk, WqkvT + (size_t)DD * DD, DD, DKV);
    transpose_cast<<<dim3(DKV / 32, DD / 32), blk, 0, stream>>>(Wv, WqkvT + (size_t)(DD + DKV) * DD, DD, DKV);

    // fused QKV GEMM: BM=128, BN=256 -> 12 x 32 = 384 blocks (2-resident/CU)
    gemm8<256, true><<<dim3(QKVS / 256, MS / 128), dim3(512), 0, stream>>>(xh, WqkvT, QKV, MS, QKVS, DD);

    // fused RoPE over Q (heads 0..15) and K (heads 16..19)
    int nrope = MS * 20 * 64;
    rope_bf16<<<(nrope + 255) / 256, 256, 0, stream>>>(QKV, nrope);

    transpose_v<<<dim3(DKV / 32, SS / 32, BB), blk, 0, stream>>>(QKV, VTb);

    attn_mfma<<<dim3(256), dim3(512), 0, stream>>>(QKV, VTb, Ch);

    transpose_cast<<<dim3(DD / 32, DD / 32), blk, 0, stream>>>(Wo, WoT, DD, DD);
    // Wo GEMM: BM=128, BN=128 -> 16 x 32 = 512 blocks (exactly 2/CU)
    gemm8<128, false><<<dim3(DD / 128, MS / 128), dim3(512), 0, stream>>>(Ch, WoT, out, MS, DD, DD);
}

// Round 12
// 210.060 us; speedup vs baseline: 28.5769x; 1.0015x over previous
//
#include <hip/hip_runtime.h>
#include <hip/hip_bf16.h>
#include <math.h>

// Problem constants
#define BB 2
#define SS 2048
#define DD 2048
#define HH 16
#define GG 4
#define HDIM 128
#define DKV (GG * HDIM)      // 512
#define MS (BB * SS)         // 4096 rows
#define QKVS 3072            // fused QKV row stride (2048 Q + 512 K + 512 V)

typedef __attribute__((ext_vector_type(8))) short bf16x8;
typedef __attribute__((ext_vector_type(4))) float f32x4;
typedef __attribute__((ext_vector_type(4))) unsigned int u32x4;

__device__ __forceinline__ ushort f2bf(float x) {
    __hip_bfloat16 b = __float2bfloat16(x);
    return *(ushort*)&b;
}
__device__ __forceinline__ float bf2f(ushort u) {
    __hip_bfloat16 b;
    *(ushort*)&b = u;
    return __bfloat162float(b);
}

#define GLOAD_LDS(src, dst)                                                        \
    __builtin_amdgcn_global_load_lds(                                              \
        (const __attribute__((address_space(1))) unsigned int*)(src),              \
        (__attribute__((address_space(3))) unsigned int*)(dst), 16, 0, 0)

#define WAITV(n) asm volatile("s_waitcnt vmcnt(" #n ")" ::: "memory")

// ---------------- fp32 -> bf16 cast, 8 elems/thread ----------------
__global__ void cast_bf16(const float* __restrict__ X, ushort* __restrict__ O, int total8) {
    int idx = blockIdx.x * blockDim.x + threadIdx.x;
    if (idx >= total8) return;
    const float4* p = (const float4*)X + (size_t)idx * 2;
    float4 a = p[0], b = p[1];
    float v[8] = {a.x, a.y, a.z, a.w, b.x, b.y, b.z, b.w};
    ushort r[8];
#pragma unroll
    for (int j = 0; j < 8; ++j) r[j] = f2bf(v[j]);
    *((u32x4*)O + idx) = *(u32x4*)r;
}

// ---------------- transpose + cast: WT[n*K + k] = bf16(W[k*N + n]) ----------------
__global__ __launch_bounds__(256) void transpose_cast(const float* __restrict__ W,
                                                      ushort* __restrict__ WT,
                                                      int K, int N) {
    __shared__ ushort tile[32][33];
    const int tx = threadIdx.x & 31, ty = threadIdx.x >> 5;  // 32 x 8
    const int n0 = blockIdx.x * 32, k0 = blockIdx.y * 32;
#pragma unroll
    for (int i = 0; i < 4; ++i)
        tile[ty + i * 8][tx] = f2bf(W[(size_t)(k0 + ty + i * 8) * N + n0 + tx]);
    __syncthreads();
#pragma unroll
    for (int i = 0; i < 4; ++i)
        WT[(size_t)(n0 + ty + i * 8) * K + k0 + tx] = tile[tx][ty + i * 8];
}

// ---- per-batch V transpose from fused QKV, with PV-slot column permutation ----
// VT'[b*DKV + dkv][tau(kv)] = QKV[b*SS+kv][2560+dkv]
// tau: kv = 32a+16m+4w+r  ->  pos = 32a+8w+4m+r
__global__ __launch_bounds__(256) void transpose_v(const ushort* __restrict__ QKV,
                                                   ushort* __restrict__ VT) {
    __shared__ ushort tile[32][33];
    const int tx = threadIdx.x & 31, ty = threadIdx.x >> 5;  // 32 x 8
    const int d0 = blockIdx.x * 32;  // dkv
    const int k0 = blockIdx.y * 32;  // kv (32-aligned)
    const int b = blockIdx.z;
#pragma unroll
    for (int i = 0; i < 4; ++i)
        tile[ty + i * 8][tx] =
            QKV[(size_t)(b * SS + k0 + ty + i * 8) * QKVS + 2560 + d0 + tx];
    __syncthreads();
    const int posl = ((tx & 12) << 1) | ((tx & 16) >> 2) | (tx & 3);
#pragma unroll
    for (int i = 0; i < 4; ++i)
        VT[((size_t)b * DKV + d0 + ty + i * 8) * SS + k0 + posl] = tile[tx][ty + i * 8];
}

// ---------------- bf16 MFMA GEMM v3: BM=128, ring-3, 2 blocks/CU ---------------
template <int BN, bool OUT_BF16>
__global__ __launch_bounds__(512) void gemm8(const ushort* __restrict__ A,
                                             const ushort* __restrict__ BT,
                                             void* __restrict__ Cout,
                                             int M, int N, int K) {
    constexpr int ABUF = 128 * 32;
    constexpr int BBUF = BN * 32;
    constexpr int NWC = BN / 64;
    constexpr int NWM = 8 / NWC;
    constexpr int ROWS = 128 / NWM;
    constexpr int MFR = ROWS / 16;
    __shared__ ushort As[3 * ABUF];
    __shared__ ushort Bs[3 * BBUF];

    const int t = threadIdx.x;
    const int w = t >> 6, l = t & 63;
    const int lm = l & 15, lw = l >> 4;
    const int wr = w / NWC, wc = w % NWC;
    const int nx = gridDim.x;
    const int bid = blockIdx.y * nx + blockIdx.x;
    const int cpx = (nx * gridDim.y) >> 3;
    const int swb = (bid & 7) * cpx + (bid >> 3);
    const int bm = (swb / nx) * 128, bn = (swb % nx) * BN;

    const int NT = K >> 5;
    const int swzc = (lw ^ ((lm >> 1) & 3)) * 8;

    const int ar0 = t >> 2, ac0 = (t & 3) ^ ((ar0 >> 1) & 3);
    const ushort* a0 = A + (size_t)(bm + ar0) * K + ac0 * 8;
    const int br0 = t >> 2, bc0 = (t & 3) ^ ((br0 >> 1) & 3);
    const ushort* b0 = BT + (size_t)(bn + br0) * K + bc0 * 8;
    const int br1 = (t + 512) >> 2, bc1 = ((t + 512) & 3) ^ ((br1 >> 1) & 3);
    const ushort* b1 = BT + (size_t)(bn + br1) * K + bc1 * 8;  // BN==256 only

    auto STAGE = [&](int slot) {
        GLOAD_LDS(a0, &As[slot * ABUF + t * 8]);
        a0 += 32;
        GLOAD_LDS(b0, &Bs[slot * BBUF + t * 8]);
        b0 += 32;
        if constexpr (BN == 256) {
            GLOAD_LDS(b1, &Bs[slot * BBUF + (t + 512) * 8]);
            b1 += 32;
        }
    };

    f32x4 acc[MFR][4];
#pragma unroll
    for (int m = 0; m < MFR; ++m)
#pragma unroll
        for (int n = 0; n < 4; ++n) acc[m][n] = (f32x4){0.f, 0.f, 0.f, 0.f};

    STAGE(0);
    STAGE(1);
    int cs = 0, ps = 2;

#pragma unroll 1
    for (int kt = 0; kt < NT; ++kt) {
        if (kt + 1 < NT) {
            if constexpr (BN == 256) WAITV(3); else WAITV(2);
        } else {
            WAITV(0);
        }
        __builtin_amdgcn_s_barrier();
        if (kt + 2 < NT) STAGE(ps);

        const ushort* Ab = &As[cs * ABUF];
        const ushort* Bb = &Bs[cs * BBUF];
        bf16x8 bfr[4], af[MFR];
#pragma unroll
        for (int n = 0; n < 4; ++n)
            bfr[n] = *(const bf16x8*)&Bb[(wc * 64 + n * 16 + lm) * 32 + swzc];
#pragma unroll
        for (int i = 0; i < MFR; ++i)
            af[i] = *(const bf16x8*)&Ab[(wr * ROWS + i * 16 + lm) * 32 + swzc];
        __builtin_amdgcn_s_setprio(1);
#pragma unroll
        for (int i = 0; i < MFR; ++i)
#pragma unroll
            for (int n = 0; n < 4; ++n)
                acc[i][n] = __builtin_amdgcn_mfma_f32_16x16x32_bf16(af[i], bfr[n], acc[i][n], 0, 0, 0);
        __builtin_amdgcn_s_setprio(0);

        cs = (cs == 2) ? 0 : cs + 1;
        ps = (ps == 2) ? 0 : ps + 1;
    }

#pragma unroll
    for (int m = 0; m < MFR; ++m)
#pragma unroll
        for (int n = 0; n < 4; ++n)
#pragma unroll
            for (int r = 0; r < 4; ++r) {
                int row = bm + wr * ROWS + m * 16 + lw * 4 + r;
                int col = bn + wc * 64 + n * 16 + lm;
                if (OUT_BF16)
                    ((ushort*)Cout)[(size_t)row * N + col] = f2bf(acc[m][n][r]);
                else
                    ((float*)Cout)[(size_t)row * N + col] = acc[m][n][r];
            }
}

// ------- RoPE in-place on bf16, fused Q+K in one launch (heads 0..19) -------
__global__ void rope_bf16(ushort* __restrict__ X, int total) {
    int idx = blockIdx.x * blockDim.x + threadIdx.x;
    if (idx >= total) return;
    int i = idx & 63;
    int hh = (idx >> 6) % 20;
    int row = idx / (64 * 20);
    int s = row & (SS - 1);
    int colOff = (hh < 16) ? hh * HDIM : 2048 + (hh - 16) * HDIM;
    float inv = exp2f((float)i * -0.2076205059304601f);  // 10000^(-2i/128)
    float ang = (float)s * inv;
    float c, sn;
    __sincosf(ang, &sn, &c);
    size_t base = (size_t)row * QKVS + colOff + i;
    float x1 = bf2f(X[base]), x2 = bf2f(X[base + 64]);
    X[base] = f2bf(x1 * c - x2 * sn);
    X[base + 64] = f2bf(x2 * c + x1 * sn);
}

// ---------------- MFMA flash attention v10: 512 blocks x 4 waves -------------
// Q-tile 64, paired {x, 31-x} (33 staged KV-tiles/block). 64 KB LDS ->
// 2 independent blocks/CU (cross-block overlap hides barrier/vmcnt drains).
// Swapped QK^T + tau-permuted V (round-9 verified math). All 4 waves share
// the same diagonal tile (lt == qt) -> no wave-divergent tile skip.
#define SCL 0.08838834764831845f          // 1/sqrt(128)
#define CEXP 0.1275296340545927f          // SCL * log2(e)
#define THRRAW 90.50966799187809f         // 8 / SCL

__global__ __launch_bounds__(256) void attn_mfma(const ushort* __restrict__ QKV,
                                                 const ushort* __restrict__ VT,
                                                 ushort* __restrict__ Ctx) {
    __shared__ ushort Ks[2][64 * 128];  // 32 KB
    __shared__ ushort Vs[2][128 * 64];  // 32 KB
    const int t = threadIdx.x;          // 0..255
    const int w = t >> 6;               // wave 0..3
    const int l = t & 63;
    const int lm = l & 15, lw = l >> 4;
    // XCD decode: bid&7 = (g + 4b) -> one (b,g) per XCD
    const int bid = blockIdx.x;
    const int g = bid & 3;
    const int b = (bid >> 2) & 1;
    const int within = bid >> 3;        // 0..63
    const int xq = within & 15;         // pair index
    const int h = g * 4 + (within >> 4);
    const int swz = (lm & 7) << 3;

    const ushort* kbase = QKV + (size_t)(b * SS) * QKVS + 2048 + g * HDIM;
    const ushort* vbase = VT + ((size_t)b * DKV + g * HDIM) * SS;

    const short one_bf = (short)0x3F80;
    const bf16x8 ones = {one_bf, one_bf, one_bf, one_bf, one_bf, one_bf, one_bf, one_bf};

    ushort* ksb = &Ks[0][0];
    ushort* vsb = &Vs[0][0];

#pragma unroll 1
    for (int phase = 0; phase < 2; ++phase) {
        const int qt = (phase == 0) ? xq : (31 - xq);
        const int q0 = qt * 64;
        const int qw = q0 + w * 16;
        const int q = qw + lm;          // this lane's q-row
        const int ntiles = qt + 1;

        // per-thread incremental source pointers (4 K chunks + 4 V chunks)
        const ushort* ks[4];
        const ushort* vs[4];
#pragma unroll
        for (int it = 0; it < 4; ++it) {
            int c = t + it * 256;
            int kr = c >> 4, ko = c & 15;
            ks[it] = kbase + (size_t)kr * QKVS + ((ko ^ (kr & 7)) * 8);
            int vr = c >> 3, vo = c & 7;
            vs[it] = vbase + (size_t)vr * SS + ((vo ^ (vr & 7)) * 8);
        }

        bf16x8 qa[4];
        {
            const ushort* qp = QKV + (size_t)(b * SS + qw + lm) * QKVS + h * HDIM + lw * 8;
#pragma unroll
            for (int kk = 0; kk < 4; ++kk)
                qa[kk] = *(const bf16x8*)(qp + kk * 32);
        }

        f32x4 acc[8];
#pragma unroll
        for (int d = 0; d < 8; ++d) acc[d] = (f32x4){0.f, 0.f, 0.f, 0.f};
        f32x4 accl = (f32x4){0.f, 0.f, 0.f, 0.f};
        float m = -INFINITY;

        // prologue: stage tile 0 into buffer 0
#pragma unroll
        for (int it = 0; it < 4; ++it) {
            GLOAD_LDS(ks[it], ksb + (t + it * 256) * 8);
            ks[it] += 64 * QKVS;
            GLOAD_LDS(vs[it], vsb + (t + it * 256) * 8);
            vs[it] += 64;
        }
        asm volatile("s_waitcnt vmcnt(0)" ::: "memory");
        __builtin_amdgcn_s_barrier();

#pragma unroll 1
        for (int tile = 0; tile < ntiles; ++tile) {
            const int cur = tile & 1;
            const int kv0 = tile * 64;
            const bool more = (tile + 1 < ntiles);
            if (more) {  // issue next tile into other buffer
                ushort* kd = ksb + (cur ^ 1) * (64 * 128);
                ushort* vd = vsb + (cur ^ 1) * (128 * 64);
#pragma unroll
                for (int it = 0; it < 4; ++it) {
                    GLOAD_LDS(ks[it], kd + (t + it * 256) * 8);
                    ks[it] += 64 * QKVS;
                    GLOAD_LDS(vs[it], vd + (t + it * 256) * 8);
                    vs[it] += 64;
                }
            }

            // ---- S^T = mfma(K, Q): lane holds S[q=lm][kv=kv0+16kvb+4lw+r] ----
            f32x4 sfT[4];
#pragma unroll
            for (int kvb = 0; kvb < 4; ++kvb) sfT[kvb] = (f32x4){0.f, 0.f, 0.f, 0.f};
            __builtin_amdgcn_s_setprio(1);
#pragma unroll
            for (int kvb = 0; kvb < 4; ++kvb)
#pragma unroll
                for (int kk = 0; kk < 4; ++kk) {
                    bf16x8 kb = *(const bf16x8*)&Ks[cur][(kvb * 16 + lm) * 128 + ((kk * 32 + lw * 8) ^ swz)];
                    sfT[kvb] = __builtin_amdgcn_mfma_f32_16x16x32_bf16(kb, qa[kk], sfT[kvb], 0, 0, 0);
                }
            __builtin_amdgcn_s_setprio(0);

            // ---- mask (diagonal tile only; lt == qt for all waves) ----
            if (tile == ntiles - 1) {
#pragma unroll
                for (int kvb = 0; kvb < 4; ++kvb)
#pragma unroll
                    for (int r = 0; r < 4; ++r) {
                        int kv = kv0 + kvb * 16 + lw * 4 + r;
                        if (kv > q) sfT[kvb][r] = -INFINITY;
                    }
            }

            // ---- in-lane row max + cross-lw reduce (2 shfl) ----
            float rm = fmaxf(fmaxf(sfT[0][0], sfT[0][1]), fmaxf(sfT[0][2], sfT[0][3]));
#pragma unroll
            for (int kvb = 1; kvb < 4; ++kvb)
                rm = fmaxf(rm, fmaxf(fmaxf(sfT[kvb][0], sfT[kvb][1]),
                                     fmaxf(sfT[kvb][2], sfT[kvb][3])));
            rm = fmaxf(rm, __shfl_xor(rm, 16));
            rm = fmaxf(rm, __shfl_xor(rm, 32));

            // ---- defer-max rescale ----
            bool stable = (rm - m <= THRRAW);
            if (!__all((int)stable)) {
                float mn = fmaxf(m, rm);
                float alpha_l = exp2f((m - mn) * CEXP);
                m = mn;
                float ar[4];
#pragma unroll
                for (int r = 0; r < 4; ++r)
                    ar[r] = __shfl(alpha_l, (l & 48) | (lw * 4 + r));
#pragma unroll
                for (int d = 0; d < 8; ++d) {
                    acc[d][0] *= ar[0];
                    acc[d][1] *= ar[1];
                    acc[d][2] *= ar[2];
                    acc[d][3] *= ar[3];
                }
                accl[0] *= ar[0];
                accl[1] *= ar[1];
                accl[2] *= ar[2];
                accl[3] *= ar[3];
            }

            // ---- P = exp2((s-m)*CEXP), packed straight into A-fragments ----
            bf16x8 pa[2];
            float mC = m * CEXP;
#pragma unroll
            for (int kvb = 0; kvb < 4; ++kvb)
#pragma unroll
                for (int r = 0; r < 4; ++r) {
                    float pv = exp2f(fmaf(sfT[kvb][r], CEXP, -mC));
                    pa[kvb >> 1][(kvb & 1) * 4 + r] = (short)f2bf(pv);
                }

            // ---- PV + l via ones-MFMA (V columns tau-permuted) ----
            __builtin_amdgcn_s_setprio(1);
#pragma unroll
            for (int kks = 0; kks < 2; ++kks) {
                accl = __builtin_amdgcn_mfma_f32_16x16x32_bf16(pa[kks], ones, accl, 0, 0, 0);
#pragma unroll
                for (int dcol = 0; dcol < 8; ++dcol) {
                    bf16x8 vb = *(const bf16x8*)&Vs[cur][(dcol * 16 + lm) * 64 + ((kks * 32 + lw * 8) ^ swz)];
                    acc[dcol] = __builtin_amdgcn_mfma_f32_16x16x32_bf16(pa[kks], vb, acc[dcol], 0, 0, 0);
                }
            }
            __builtin_amdgcn_s_setprio(0);

            if (more) {
                asm volatile("s_waitcnt vmcnt(0)" ::: "memory");
                __builtin_amdgcn_s_barrier();
            }
        }

        // ---- epilogue: O[q=qw+lw*4+r][d=dcol*16+lm] = acc/l ----
        float rinv[4];
#pragma unroll
        for (int r = 0; r < 4; ++r) rinv[r] = 1.f / accl[r];
        ushort* cp = Ctx + (size_t)(b * SS + qw) * DD + h * HDIM;
#pragma unroll
        for (int d = 0; d < 8; ++d)
#pragma unroll
            for (int r = 0; r < 4; ++r)
                cp[(size_t)(lw * 4 + r) * DD + d * 16 + lm] = f2bf(acc[d][r] * rinv[r]);
        __builtin_amdgcn_s_barrier();  // protect LDS before next phase's prologue
    }
}

extern "C" void kernel_launch(void* const* d_in, const int* in_sizes, int n_in,
                              void* d_out, int out_size, void* d_ws, size_t ws_size,
                              hipStream_t stream) {
    const float* x  = (const float*)d_in[0];
    const float* Wq = (const float*)d_in[1];
    const float* Wk = (const float*)d_in[2];
    const float* Wv = (const float*)d_in[3];
    const float* Wo = (const float*)d_in[4];
    float* out = (float*)d_out;

    // bf16 workspace (~67 MB)
    ushort* xh    = (ushort*)d_ws;                    // [MS, DD]
    ushort* QKV   = xh + (size_t)MS * DD;             // [MS, QKVS]
    ushort* VTb   = QKV + (size_t)MS * QKVS;          // [BB*DKV, SS]
    ushort* WqkvT = VTb + (size_t)MS * DKV;           // [QKVS, DD]
    ushort* WoT   = WqkvT + (size_t)QKVS * DD;        // [DD, DD]
    ushort* Ch    = xh;                               // ctx bf16 aliases xh

    dim3 blk(256);
    int nx8 = MS * DD / 8;
    cast_bf16<<<(nx8 + 255) / 256, 256, 0, stream>>>(x, xh, nx8);

    transpose_cast<<<dim3(DD / 32, DD / 32), blk, 0, stream>>>(Wq, WqkvT, DD, DD);
    transpose_cast<<<dim3(DKV / 32, DD / 32), blk, 0, stream>>>(Wk, WqkvT + (size_t)DD * DD, DD, DKV);
    transpose_cast<<<dim3(DKV / 32, DD / 32), blk, 0, stream>>>(Wv, WqkvT + (size_t)(DD + DKV) * DD, DD, DKV);

    // fused QKV GEMM: BM=128, BN=256 -> 12 x 32 = 384 blocks (2-resident/CU)
    gemm8<256, true><<<dim3(QKVS / 256, MS / 128), dim3(512), 0, stream>>>(xh, WqkvT, QKV, MS, QKVS, DD);

    // fused RoPE over Q (heads 0..15) and K (heads 16..19)
    int nrope = MS * 20 * 64;
    rope_bf16<<<(nrope + 255) / 256, 256, 0, stream>>>(QKV, nrope);

    transpose_v<<<dim3(DKV / 32, SS / 32, BB), blk, 0, stream>>>(QKV, VTb);

    // attention: 512 blocks x 256 threads (2 blocks/CU)
    attn_mfma<<<dim3(512), dim3(256), 0, stream>>>(QKV, VTb, Ch);

    transpose_cast<<<dim3(DD / 32, DD / 32), blk, 0, stream>>>(Wo, WoT, DD, DD);
    // Wo GEMM: BM=128, BN=128 -> 16 x 32 = 512 blocks (exactly 2/CU)
    gemm8<128, false><<<dim3(DD / 128, MS / 128), dim3(512), 0, stream>>>(Ch, WoT, out, MS, DD, DD);
}